// Round 24
// baseline (1192.622 us; speedup 1.0000x reference)
//
#include <hip/hip_runtime.h>
#include <hip/hip_cooperative_groups.h>
#include <math.h>

namespace cg = cooperative_groups;

// ---- problem constants ----
constexpr int BB   = 32;
constexpr int L    = 336;
constexpr int CIN  = 7;
constexpr int MARK = 4;
constexpr int D    = 512;
constexpr int DFF  = 2048;
constexpr int S    = 446;
constexpr int DBOT = 128;
constexpr int L1 = 84, L2 = 21, L3 = 5;
constexpr int LC = 110;
constexpr int NLAYER = 3;
constexpr int PRED_N = 672;
constexpr int MP   = 14336;
constexpr int NMAX = 12;
constexpr int MCONV1 = BB * L1;   // 2688
constexpr int MCONV2P = 768;
constexpr int MCAT  = 3584;

using short8  = __attribute__((ext_vector_type(8))) short;
using float4v = __attribute__((ext_vector_type(4))) float;

// ---------------------------------------------------------------------------
// COMPILE-TIME pyramid structure
// ---------------------------------------------------------------------------
struct SetsData {
    int nbr[S][NMAX];
    int idx[4][S];
    int cnt[4];
};

constexpr SetsData compute_sets() {
    SetsData sd{};
    constexpr int sizes[4]  = {336, 84, 21, 5};
    constexpr int starts[4] = {0, 336, 420, 441};
    for (int i = 0; i < S; ++i) {
        int li = 0, pi = i;
        if (i < 336)      { li = 0; pi = i; }
        else if (i < 420) { li = 1; pi = i - 336; }
        else if (i < 441) { li = 2; pi = i - 420; }
        else              { li = 3; pi = i - 441; }
        int cnt = 0;
        for (int d = -2; d <= 2; ++d) {
            int q = pi + d;
            if (q >= 0 && q < sizes[li]) sd.nbr[i][cnt++] = starts[li] + q;
        }
        if (li > 0) {
            int lo = pi * 4;
            int hi = (pi == sizes[li] - 1) ? sizes[li - 1] : (pi + 1) * 4;
            for (int c = lo; c < hi; ++c) sd.nbr[i][cnt++] = starts[li - 1] + c;
        }
        if (li < 3) {
            int q = pi >> 2;
            if (q > sizes[li + 1] - 1) q = sizes[li + 1] - 1;
            sd.nbr[i][cnt++] = starts[li + 1] + q;
        }
        for (int j = cnt; j < NMAX; ++j) sd.nbr[i][j] = -1;
    }
    sd.cnt[3] = 4;
    sd.idx[3][0] = 335; sd.idx[3][1] = 419; sd.idx[3][2] = 440; sd.idx[3][3] = 445;
    for (int lvl = 3; lvl >= 1; --lvl) {
        bool mk[S] = {};
        for (int k = 0; k < sd.cnt[lvl]; ++k) {
            int i = sd.idx[lvl][k];
            for (int t = 0; t < NMAX; ++t) {
                int v = sd.nbr[i][t];
                if (v >= 0) mk[v] = true;
            }
        }
        int nc = 0;
        for (int i = 0; i < S; ++i)
            if (mk[i]) sd.idx[lvl - 1][nc++] = i;
        sd.cnt[lvl - 1] = nc;
    }
    return sd;
}

constexpr SetsData HS = compute_sets();
__constant__ SetsData d_sets = compute_sets();

// split-K partial buffer size (elements) — superset for BOTH paths (r22 set)
constexpr size_t psk_elems() {
    size_t mx = 4 * (size_t)BB * L * DBOT;
    {
        size_t v = 4 * (size_t)MCONV1 * DBOT; if (v > mx) mx = v;
        v = 4 * (size_t)MCONV2P * DBOT;       if (v > mx) mx = v;
    }
    for (int l = 0; l < NLAYER; ++l) {
        size_t Mc = (size_t)HS.cnt[l + 1] * 32;
        size_t Mpad = ((Mc + 127) / 128) * 128;
        { size_t v = 4 * Mpad * 512;  if (v > mx) mx = v; }
        if (Mc <= 512) { size_t v = 4 * Mpad * 2048; if (v > mx) mx = v; }
        size_t ks = (Mc <= 512) ? 8 : 4;
        size_t v = ks * Mpad * 512; if (v > mx) mx = v;
    }
    return mx;
}

__device__ inline short f2bf(float f) {
    union { float f; unsigned u; } v; v.f = f;
    unsigned r = v.u + 0x7fffu + ((v.u >> 16) & 1u);
    return (short)(r >> 16);
}
__device__ inline float bf2f(short h) {
    union { unsigned u; float f; } v; v.u = ((unsigned)(unsigned short)h) << 16;
    return v.f;
}

__device__ inline void gload_lds16(const void* g, void* l) {
    __builtin_amdgcn_global_load_lds(
        (const __attribute__((address_space(1))) void*)g,
        (__attribute__((address_space(3))) void*)l, 16, 0, 0);
}

__device__ inline float blk_reduce(float v, float* ws4, int tid) {
#pragma unroll
    for (int o = 32; o; o >>= 1) v += __shfl_xor(v, o);
    if ((tid & 63) == 0) ws4[tid >> 6] = v;
    __syncthreads();
    return ws4[0] + ws4[1] + ws4[2] + ws4[3];
}

constexpr int PE_N  = L * D;
constexpr int WE_N  = D * 32;
constexpr int XIM_N = BB * L * 32;
constexpr int MISC_N = PE_N + WE_N + XIM_N;
constexpr int PREP_BLKS = 3072 + 6144 + 640 + (MISC_N + 255) / 256;

// ===========================================================================
// PATH A: round-22 standalone kernels (verbatim known-good fallback)
// ===========================================================================

template<int EPI>
__launch_bounds__(256, 4)
__global__ void mfma_gemm(const short* __restrict__ A, const short* __restrict__ Bt,
                          const float* __restrict__ bias, const float* __restrict__ bias2,
                          void* __restrict__ Cout, int Kd, int Nd,
                          int alvl, int clvl, int cnt,
                          const float* __restrict__ peT, short* __restrict__ Cout2) {
    __shared__ short As[2][128 * 32];
    __shared__ short Bs[2][128 * 32];
    int tid = threadIdx.x;
    int nwg  = gridDim.x * gridDim.y;
    int orig = blockIdx.y * gridDim.x + blockIdx.x;
    int qq = nwg >> 3, rr = nwg & 7;
    int xcd = orig & 7, idx = orig >> 3;
    int wgid = (xcd < rr ? xcd * (qq + 1) : rr * (qq + 1) + (xcd - rr) * qq) + idx;
    int m0 = (wgid / gridDim.x) * 128, n0 = (wgid % gridDim.x) * 128;

    int lane = tid & 63, wid = tid >> 6;
    int wm = wid >> 1, wn = wid & 1;
    int lr = lane & 15, lk = lane >> 4;

    size_t abase[2], bbase[2];
#pragma unroll
    for (int r = 0; r < 2; ++r) {
        int u = r * 256 + tid;
        int row = ((u >> 3) << 1) | ((u >> 2) & 1);
        int kg  = (u & 3) ^ ((u >> 3) & 3);
        int rm = m0 + row, ga;
        if (alvl >= 0) { int j = rm >> 5; if (j > cnt - 1) j = cnt - 1; ga = (rm & 31) * S + d_sets.idx[alvl][j]; }
        else ga = rm;
        abase[r] = (size_t)ga * Kd + kg * 8;
        bbase[r] = (size_t)(n0 + row) * Kd + kg * 8;
    }
    auto stage = [&](int buf, int k0) {
#pragma unroll
        for (int r = 0; r < 2; ++r) {
            short* la = As[buf] + (size_t)(r * 256 + wid * 64) * 8;
            short* lb = Bs[buf] + (size_t)(r * 256 + wid * 64) * 8;
            gload_lds16(A + abase[r] + k0, la);
            gload_lds16(Bt + bbase[r] + k0, lb);
        }
    };
    auto rd_off = [&](int row_) {
        int rh = row_ >> 1;
        int s  = lk ^ (rh & 3);
        return (size_t)(rh * 8 + (row_ & 1) * 4 + s) * 8;
    };

    float4v acc[4][4];
#pragma unroll
    for (int i = 0; i < 4; ++i)
#pragma unroll
        for (int j = 0; j < 4; ++j) acc[i][j] = 0;

    const int nt = Kd >> 5;
    stage(0, 0);
    for (int t = 0; t < nt; ++t) {
        int cur = t & 1;
        if (t + 1 < nt) {
            stage(cur ^ 1, (t + 1) * 32);
            asm volatile("s_waitcnt vmcnt(4)" ::: "memory");
        } else {
            asm volatile("s_waitcnt vmcnt(0)" ::: "memory");
        }
        __builtin_amdgcn_s_barrier();
        short8 af[4], bfv[4];
#pragma unroll
        for (int mi = 0; mi < 4; ++mi)
            af[mi] = *(const short8*)(As[cur] + rd_off(wm * 64 + mi * 16 + lr));
#pragma unroll
        for (int ni = 0; ni < 4; ++ni)
            bfv[ni] = *(const short8*)(Bs[cur] + rd_off(wn * 64 + ni * 16 + lr));
        __builtin_amdgcn_s_setprio(1);
#pragma unroll
        for (int mi = 0; mi < 4; ++mi)
#pragma unroll
            for (int ni = 0; ni < 4; ++ni)
                acc[mi][ni] = __builtin_amdgcn_mfma_f32_16x16x32_bf16(
                    af[mi], bfv[ni], acc[mi][ni], 0, 0, 0);
        __builtin_amdgcn_s_setprio(0);
        __builtin_amdgcn_s_barrier();
    }

#pragma unroll
    for (int mi = 0; mi < 4; ++mi) {
        int gmc = m0 + wm * 64 + mi * 16 + lk * 4;
#pragma unroll
        for (int ni = 0; ni < 4; ++ni) {
            int gn = n0 + wn * 64 + ni * 16 + lr;
            float bsv = (EPI == 1 || EPI == 3 || EPI == 4) ? bias[gn] : 0.0f;
            float sc = (EPI == 5) ? bias[gn]  : 0.0f;
            float sh = (EPI == 5) ? bias2[gn] : 0.0f;
#pragma unroll
            for (int e = 0; e < 4; ++e) {
                int rm = gmc + e, grow;
                if (clvl >= 0) { int j = rm >> 5; if (j > cnt - 1) j = cnt - 1; grow = (rm & 31) * S + d_sets.idx[clvl][j]; }
                else grow = rm;
                float v = acc[mi][ni][e] + bsv;
                if (EPI == 3) v = 0.5f * v * (1.0f + erff(v * 0.70710678118654752f));
                if (EPI == 5) { v = v * sc + sh; v = v > 0.0f ? v : (expf(v) - 1.0f); }
                if (EPI == 6) {
                    v += peT[(size_t)(grow % L) * D + gn];
                    Cout2[(size_t)grow * Nd + gn] = f2bf(v);
                } else if (EPI <= 1) {
                    ((float*)Cout)[(size_t)grow * Nd + gn] = v;
                } else {
                    ((short*)Cout)[(size_t)grow * Nd + gn] = f2bf(v);
                }
            }
        }
    }
}

__launch_bounds__(256, 4)
__global__ void mfma_gemm_up(const short* __restrict__ cs1, const short* __restrict__ cs2,
                             const short* __restrict__ cs3, const short* __restrict__ Bt,
                             const float* __restrict__ bias, float* __restrict__ Cout) {
    __shared__ short As[2][128 * 32];
    __shared__ short Bs[2][128 * 32];
    int tid = threadIdx.x;
    int nwg  = gridDim.x * gridDim.y;
    int orig = blockIdx.y * gridDim.x + blockIdx.x;
    int qq = nwg >> 3, rr = nwg & 7;
    int xcd = orig & 7, idx = orig >> 3;
    int wgid = (xcd < rr ? xcd * (qq + 1) : rr * (qq + 1) + (xcd - rr) * qq) + idx;
    int m0 = (wgid / gridDim.x) * 128, n0 = (wgid % gridDim.x) * 128;
    const int Kd = DBOT, Nd = D;

    int lane = tid & 63, wid = tid >> 6;
    int wm = wid >> 1, wn = wid & 1;
    int lr = lane & 15, lk = lane >> 4;

    const short* aad[2];
    size_t bbase[2];
#pragma unroll
    for (int r = 0; r < 2; ++r) {
        int u = r * 256 + tid;
        int row = ((u >> 3) << 1) | ((u >> 2) & 1);
        int kg  = (u & 3) ^ ((u >> 3) & 3);
        int rm = m0 + row;
        const short* base;
        if (rm < BB * LC) {
            int b = rm / LC, t = rm % LC;
            if (t < L1)           base = cs1 + (size_t)(b * L1 + t) * DBOT;
            else if (t < L1 + L2) base = cs2 + (size_t)(b * L2 + (t - L1)) * DBOT;
            else                  base = cs3 + (size_t)(b * L3 + (t - L1 - L2)) * DBOT;
        } else {
            base = cs1;
        }
        aad[r] = base + kg * 8;
        bbase[r] = (size_t)(n0 + row) * Kd + kg * 8;
    }
    auto stage = [&](int buf, int k0) {
#pragma unroll
        for (int r = 0; r < 2; ++r) {
            short* la = As[buf] + (size_t)(r * 256 + wid * 64) * 8;
            short* lb = Bs[buf] + (size_t)(r * 256 + wid * 64) * 8;
            gload_lds16(aad[r] + k0, la);
            gload_lds16(Bt + bbase[r] + k0, lb);
        }
    };
    auto rd_off = [&](int row_) {
        int rh = row_ >> 1;
        int s  = lk ^ (rh & 3);
        return (size_t)(rh * 8 + (row_ & 1) * 4 + s) * 8;
    };

    float4v acc[4][4];
#pragma unroll
    for (int i = 0; i < 4; ++i)
#pragma unroll
        for (int j = 0; j < 4; ++j) acc[i][j] = 0;

    const int nt = Kd >> 5;
    stage(0, 0);
    for (int t = 0; t < nt; ++t) {
        int cur = t & 1;
        if (t + 1 < nt) {
            stage(cur ^ 1, (t + 1) * 32);
            asm volatile("s_waitcnt vmcnt(4)" ::: "memory");
        } else {
            asm volatile("s_waitcnt vmcnt(0)" ::: "memory");
        }
        __builtin_amdgcn_s_barrier();
        short8 af[4], bfv[4];
#pragma unroll
        for (int mi = 0; mi < 4; ++mi)
            af[mi] = *(const short8*)(As[cur] + rd_off(wm * 64 + mi * 16 + lr));
#pragma unroll
        for (int ni = 0; ni < 4; ++ni)
            bfv[ni] = *(const short8*)(Bs[cur] + rd_off(wn * 64 + ni * 16 + lr));
        __builtin_amdgcn_s_setprio(1);
#pragma unroll
        for (int mi = 0; mi < 4; ++mi)
#pragma unroll
            for (int ni = 0; ni < 4; ++ni)
                acc[mi][ni] = __builtin_amdgcn_mfma_f32_16x16x32_bf16(
                    af[mi], bfv[ni], acc[mi][ni], 0, 0, 0);
        __builtin_amdgcn_s_setprio(0);
        __builtin_amdgcn_s_barrier();
    }

#pragma unroll
    for (int mi = 0; mi < 4; ++mi) {
        int gmc = m0 + wm * 64 + mi * 16 + lk * 4;
#pragma unroll
        for (int ni = 0; ni < 4; ++ni) {
            int gn = n0 + wn * 64 + ni * 16 + lr;
            float bsv = bias[gn];
#pragma unroll
            for (int e = 0; e < 4; ++e)
                Cout[(size_t)(gmc + e) * Nd + gn] = acc[mi][ni][e] + bsv;
        }
    }
}

__launch_bounds__(256, 4)
__global__ void mfma_gemm_sk(const short* __restrict__ A, const short* __restrict__ Bt,
                             float* __restrict__ part, int Kd, int Nd,
                             int alvl, int cnt) {
    __shared__ short As[2][128 * 32];
    __shared__ short Bs[2][128 * 32];
    int tid = threadIdx.x;
    int nwg  = gridDim.x * gridDim.y;
    int orig = blockIdx.y * gridDim.x + blockIdx.x;
    int qq = nwg >> 3, rr = nwg & 7;
    int xcd = orig & 7, idx = orig >> 3;
    int wgid = (xcd < rr ? xcd * (qq + 1) : rr * (qq + 1) + (xcd - rr) * qq) + idx;
    int m0 = (wgid / gridDim.x) * 128, n0 = (wgid % gridDim.x) * 128;
    int Mpad = gridDim.y * 128;
    int kz = blockIdx.z;
    int kb = Kd / gridDim.z;
    int kbase = kz * kb;

    int lane = tid & 63, wid = tid >> 6;
    int wm = wid >> 1, wn = wid & 1;
    int lr = lane & 15, lk = lane >> 4;

    size_t abase[2], bbase[2];
#pragma unroll
    for (int r = 0; r < 2; ++r) {
        int u = r * 256 + tid;
        int row = ((u >> 3) << 1) | ((u >> 2) & 1);
        int kg  = (u & 3) ^ ((u >> 3) & 3);
        int rm = m0 + row, ga;
        if (alvl >= 0) { int j = rm >> 5; if (j > cnt - 1) j = cnt - 1; ga = (rm & 31) * S + d_sets.idx[alvl][j]; }
        else ga = rm;
        abase[r] = (size_t)ga * Kd + kbase + kg * 8;
        bbase[r] = (size_t)(n0 + row) * Kd + kbase + kg * 8;
    }
    auto stage = [&](int buf, int k0) {
#pragma unroll
        for (int r = 0; r < 2; ++r) {
            short* la = As[buf] + (size_t)(r * 256 + wid * 64) * 8;
            short* lb = Bs[buf] + (size_t)(r * 256 + wid * 64) * 8;
            gload_lds16(A + abase[r] + k0, la);
            gload_lds16(Bt + bbase[r] + k0, lb);
        }
    };
    auto rd_off = [&](int row_) {
        int rh = row_ >> 1;
        int s  = lk ^ (rh & 3);
        return (size_t)(rh * 8 + (row_ & 1) * 4 + s) * 8;
    };

    float4v acc[4][4];
#pragma unroll
    for (int i = 0; i < 4; ++i)
#pragma unroll
        for (int j = 0; j < 4; ++j) acc[i][j] = 0;

    const int nt = kb >> 5;
    stage(0, 0);
    for (int t = 0; t < nt; ++t) {
        int cur = t & 1;
        if (t + 1 < nt) {
            stage(cur ^ 1, (t + 1) * 32);
            asm volatile("s_waitcnt vmcnt(4)" ::: "memory");
        } else {
            asm volatile("s_waitcnt vmcnt(0)" ::: "memory");
        }
        __builtin_amdgcn_s_barrier();
        short8 af[4], bfv[4];
#pragma unroll
        for (int mi = 0; mi < 4; ++mi)
            af[mi] = *(const short8*)(As[cur] + rd_off(wm * 64 + mi * 16 + lr));
#pragma unroll
        for (int ni = 0; ni < 4; ++ni)
            bfv[ni] = *(const short8*)(Bs[cur] + rd_off(wn * 64 + ni * 16 + lr));
        __builtin_amdgcn_s_setprio(1);
#pragma unroll
        for (int mi = 0; mi < 4; ++mi)
#pragma unroll
            for (int ni = 0; ni < 4; ++ni)
                acc[mi][ni] = __builtin_amdgcn_mfma_f32_16x16x32_bf16(
                    af[mi], bfv[ni], acc[mi][ni], 0, 0, 0);
        __builtin_amdgcn_s_setprio(0);
        __builtin_amdgcn_s_barrier();
    }

#pragma unroll
    for (int mi = 0; mi < 4; ++mi) {
        int gmc = m0 + wm * 64 + mi * 16 + lk * 4;
#pragma unroll
        for (int ni = 0; ni < 4; ++ni) {
            int gn = n0 + wn * 64 + ni * 16 + lr;
#pragma unroll
            for (int e = 0; e < 4; ++e)
                part[((size_t)kz * Mpad + gmc + e) * Nd + gn] = acc[mi][ni][e];
        }
    }
}

template<int EPI>
__launch_bounds__(256)
__global__ void reduce_sk(const float* __restrict__ part, const float* __restrict__ bias,
                          const float* __restrict__ bias2, short* __restrict__ Cout,
                          int Mpad, int Nd, int KS) {
    int idx = blockIdx.x * 256 + threadIdx.x;
    if (idx >= Mpad * Nd) return;
    float s = 0.0f;
    for (int k = 0; k < KS; ++k)
        s += part[(size_t)k * Mpad * Nd + idx];
    int n = idx % Nd;
    if (EPI == 3 || EPI == 4) s += bias[n];
    if (EPI == 3) s = 0.5f * s * (1.0f + erff(s * 0.70710678118654752f));
    if (EPI == 5) { s = s * bias[n] + bias2[n]; s = s > 0.0f ? s : (expf(s) - 1.0f); }
    Cout[idx] = f2bf(s);
}

__device__ inline void wtrans_tile_s(const float* __restrict__ W, short* __restrict__ Wt,
                                     int Kd, int Nd, int n0, int k0, int tid) {
    __shared__ float tile[32][33];
    int tx = tid & 31, ty = tid >> 5;
#pragma unroll
    for (int r = 0; r < 32; r += 8)
        tile[ty + r][tx] = W[(size_t)(k0 + ty + r) * Nd + n0 + tx];
    __syncthreads();
#pragma unroll
    for (int r = 0; r < 32; r += 8)
        Wt[(size_t)(n0 + ty + r) * Kd + k0 + tx] = f2bf(tile[tx][ty + r]);
}

__launch_bounds__(256)
__global__ void prep_all(const float* __restrict__ wq, const float* __restrict__ wk,
                         const float* __restrict__ wv, const float* __restrict__ wo,
                         short* __restrict__ wqkvT, short* __restrict__ woT,
                         const float* __restrict__ w1, const float* __restrict__ w2,
                         short* __restrict__ w1T, short* __restrict__ w2T,
                         const float* __restrict__ down_w, short* __restrict__ downT,
                         const float* __restrict__ up_w, short* __restrict__ upT,
                         const float* __restrict__ cw, const float* __restrict__ cb,
                         const float* __restrict__ bg, const float* __restrict__ bb,
                         short* __restrict__ cscmT, float* __restrict__ sc,
                         float* __restrict__ sh,
                         const float* __restrict__ x_enc, const float* __restrict__ x_mark,
                         const float* __restrict__ cew, const float* __restrict__ tw,
                         const float* __restrict__ tb, float* __restrict__ pe,
                         short* __restrict__ wE, short* __restrict__ xim) {
    int blk = blockIdx.x;
    int tid = threadIdx.x;
    if (blk < 3072) {
        int z = blk >> 8, rem = blk & 255;
        int l = z >> 2, part = z & 3;
        const float* src = (part == 0 ? wq : part == 1 ? wk : part == 2 ? wv : wo)
                           + (size_t)l * D * D;
        short* dst = (part < 3) ? wqkvT + (size_t)l * 3 * D * D + (size_t)part * D * D
                                : woT + (size_t)l * D * D;
        wtrans_tile_s(src, dst, D, D, (rem & 15) * 32, (rem >> 4) * 32, tid);
        return;
    }
    blk -= 3072;
    if (blk < 6144) {
        int z = blk >> 10, rem = blk & 1023;
        int l = z >> 1, part = z & 1;
        int bx = rem & 63, by = rem >> 6;
        int nt = part ? by : bx;
        int kt = part ? bx : by;
        if (part == 0)
            wtrans_tile_s(w1 + (size_t)l * D * DFF, w1T + (size_t)l * DFF * D,
                          D, DFF, nt * 32, kt * 32, tid);
        else
            wtrans_tile_s(w2 + (size_t)l * DFF * D, w2T + (size_t)l * D * DFF,
                          DFF, D, nt * 32, kt * 32, tid);
        return;
    }
    blk -= 6144;
    if (blk < 640) {
        if (blk < 64) {
            wtrans_tile_s(down_w, downT, D, DBOT, (blk & 3) * 32, (blk >> 2) * 32, tid);
        } else if (blk < 128) {
            int b2 = blk - 64;
            wtrans_tile_s(up_w, upT, DBOT, D, (b2 & 15) * 32, (b2 >> 4) * 32, tid);
        } else {
            int idx = (blk - 128) * 256 + tid;
            if (idx < 2 * DBOT * 512) {
                int l = idx >> 16;
                int rem = idx & 65535;
                int oc = rem >> 9, j = rem & 511;
                int r = j >> 7, c = j & 127;
                cscmT[idx] = f2bf(cw[(((size_t)l * DBOT + oc) * DBOT + c) * 4 + r]);
            }
            if (idx < 3 * DBOT) {
                sc[idx] = bg[idx];
                sh[idx] = cb[idx] * bg[idx] + bb[idx];
            }
        }
        return;
    }
    blk -= 640;
    {
        int idx = blk * 256 + tid;
        if (idx < PE_N) {
            int d = idx % D, t = idx / D;
            int e = d & ~1;
            float div = expf(-(float)e * (logf(10000.0f) / (float)D));
            float arg = (float)t * div;
            pe[idx] = (d & 1) ? cosf(arg) : sinf(arg);
            return;
        }
        int i2 = idx - PE_N;
        if (i2 < WE_N) {
            int k = i2 & 31, d = i2 >> 5;
            float v = 0.0f;
            if (k < 21) {
                int w = k / 7, i = k % 7;
                v = cew[(size_t)d * (CIN * 3) + i * 3 + w];
            } else if (k < 25) {
                v = tw[(size_t)(k - 21) * D + d];
            } else if (k == 25) {
                v = tb[d];
            }
            wE[i2] = f2bf(v);
            return;
        }
        int i3 = i2 - WE_N;
        if (i3 < XIM_N) {
            int k = i3 & 31, m = i3 >> 5;
            int t = m % L, b = m / L;
            float v = 0.0f;
            if (k < 21) {
                int w = k / 7, i = k % 7;
                int s = t + w - 1;
                if (s < 0) s = L - 1;
                if (s >= L) s = 0;
                v = x_enc[((size_t)b * L + s) * CIN + i];
            } else if (k < 25) {
                v = x_mark[(size_t)m * MARK + (k - 21)];
            } else if (k == 25) {
                v = 1.0f;
            }
            xim[i3] = f2bf(v);
        }
    }
}

__launch_bounds__(128)
__global__ void cscm_conv_bf16(const short* __restrict__ in, int inRowsPerB,
                               short* __restrict__ outp, const float* __restrict__ w,
                               const float* __restrict__ cb, const float* __restrict__ bng,
                               const float* __restrict__ bnb, int Lout) {
    int bid = blockIdx.x;
    int to = bid % Lout, b = bid / Lout;
    __shared__ float insh[4 * DBOT];
    int tid = threadIdx.x;
#pragma unroll
    for (int r = 0; r < 4; ++r)
        insh[r * DBOT + tid] = bf2f(in[((size_t)(b * inRowsPerB + to * 4 + r)) * DBOT + tid]);
    __syncthreads();
    float acc = cb[tid];
    const float* wr = w + (size_t)tid * (DBOT * 4);
    for (int c = 0; c < DBOT; ++c) {
#pragma unroll
        for (int r = 0; r < 4; ++r)
            acc += insh[r * DBOT + c] * wr[c * 4 + r];
    }
    acc = acc * bng[tid] + bnb[tid];
    outp[((size_t)(b * Lout + to)) * DBOT + tid] = f2bf(acc > 0.0f ? acc : (expf(acc) - 1.0f));
}

__launch_bounds__(256)
__global__ void attn_sparse_kernel(const short* __restrict__ QKV, short* __restrict__ Ob,
                                   int lvl, int cnt) {
    int wid  = blockIdx.x * 4 + (threadIdx.x >> 6);
    if (wid >= cnt * 32) return;
    int lane = threadIdx.x & 63;
    int b = wid & 31, j = wid >> 5;
    int i = d_sets.idx[lvl][j];
    const short8 qv = *(const short8*)(QKV + (size_t)(b * S + i) * 1536 + lane * 8);
    float qf[8];
#pragma unroll
    for (int e = 0; e < 8; ++e) qf[e] = bf2f(qv[e]);
    int nb[NMAX];
#pragma unroll
    for (int jj = 0; jj < NMAX; ++jj) nb[jj] = d_sets.nbr[i][jj];
    float sc[NMAX];
#pragma unroll
    for (int jj = 0; jj < NMAX; ++jj) {
        float s = -1e30f;
        if (nb[jj] >= 0) {
            const short8 kv = *(const short8*)(QKV + (size_t)(b * S + nb[jj]) * 1536 + 512 + lane * 8);
            s = 0.0f;
#pragma unroll
            for (int e = 0; e < 8; ++e) s += qf[e] * bf2f(kv[e]);
            s += __shfl_xor(s, 1); s += __shfl_xor(s, 2); s += __shfl_xor(s, 4);
            s *= 0.125f;
        }
        sc[jj] = s;
    }
    float mx = sc[0];
#pragma unroll
    for (int jj = 1; jj < NMAX; ++jj) mx = fmaxf(mx, sc[jj]);
    float sum = 0.0f;
    float accv[8] = {};
#pragma unroll
    for (int jj = 0; jj < NMAX; ++jj) {
        float p = expf(sc[jj] - mx);
        sum += p;
        if (nb[jj] >= 0) {
            const short8 vv = *(const short8*)(QKV + (size_t)(b * S + nb[jj]) * 1536 + 1024 + lane * 8);
#pragma unroll
            for (int e = 0; e < 8; ++e) accv[e] += p * bf2f(vv[e]);
        }
    }
    float inv = 1.0f / sum;
    short8 ov;
#pragma unroll
    for (int e = 0; e < 8; ++e) ov[e] = f2bf(accv[e] * inv);
    *(short8*)(Ob + (size_t)wid * D + lane * 8) = ov;
}

__launch_bounds__(256)
__global__ void concat_ln_idx(const short* __restrict__ emb_bf, const float* __restrict__ coarse,
                              const float* __restrict__ g, const float* __restrict__ bta,
                              float* __restrict__ seq, short* __restrict__ seq_bf) {
    int row = blockIdx.x;
    int b = row & 31, j = row >> 5;
    int s = d_sets.idx[0][j];
    int orig = b * S + s;
    __shared__ float wsA[4];
    __shared__ float wsB[4];
    int tid = threadIdx.x;
    float x0, x1;
    if (s < L) {
        const short* src = emb_bf + ((size_t)b * L + s) * D;
        x0 = bf2f(src[tid]); x1 = bf2f(src[tid + 256]);
    } else {
        const float* src = coarse + ((size_t)b * LC + (s - L)) * D;
        x0 = src[tid]; x1 = src[tid + 256];
    }
    float mu = blk_reduce(x0 + x1, wsA, tid) * (1.0f / D);
    float d0 = x0 - mu, d1 = x1 - mu;
    float var = blk_reduce(d0 * d0 + d1 * d1, wsB, tid) * (1.0f / D);
    float rstd = rsqrtf(var + 1e-5f);
    float v0 = d0 * rstd * g[tid]       + bta[tid];
    float v1 = d1 * rstd * g[tid + 256] + bta[tid + 256];
    float* dst = seq + (size_t)orig * D;
    dst[tid] = v0; dst[tid + 256] = v1;
    short* dbf = seq_bf + (size_t)orig * D;
    dbf[tid] = f2bf(v0); dbf[tid + 256] = f2bf(v1);
}

__launch_bounds__(256)
__global__ void add_ln_sk(float* __restrict__ seq, const float* __restrict__ part,
                          const float* __restrict__ bias, const float* __restrict__ g,
                          const float* __restrict__ bta, short* __restrict__ seq_bf,
                          int lvl, int Mpad, int KS) {
    int row = blockIdx.x;
    int b = row & 31, j = row >> 5;
    int orig = b * S + d_sets.idx[lvl][j];
    __shared__ float wsA[4];
    __shared__ float wsB[4];
    int tid = threadIdx.x;
    float a0 = 0.0f, a1 = 0.0f;
    for (int k = 0; k < KS; ++k) {
        const float* pr = part + ((size_t)k * Mpad + row) * D;
        a0 += pr[tid];
        a1 += pr[tid + 256];
    }
    if (bias) { a0 += bias[tid]; a1 += bias[tid + 256]; }
    float* srow = seq + (size_t)orig * D;
    float x0 = srow[tid] + a0;
    float x1 = srow[tid + 256] + a1;
    float mu = blk_reduce(x0 + x1, wsA, tid) * (1.0f / D);
    float d0 = x0 - mu, d1 = x1 - mu;
    float var = blk_reduce(d0 * d0 + d1 * d1, wsB, tid) * (1.0f / D);
    float rstd = rsqrtf(var + 1e-5f);
    float v0 = d0 * rstd * g[tid]       + bta[tid];
    float v1 = d1 * rstd * g[tid + 256] + bta[tid + 256];
    srow[tid] = v0; srow[tid + 256] = v1;
    short* dbf = seq_bf + (size_t)orig * D;
    dbf[tid] = f2bf(v0); dbf[tid + 256] = f2bf(v1);
}

__launch_bounds__(256)
__global__ void pred_kernel(const float* __restrict__ seq, const float* __restrict__ w,
                            float* __restrict__ part) {
    __shared__ float es[32][257];
    __shared__ float wsm[256][8];
    int tid = threadIdx.x;
    int n0 = blockIdx.x * 8;
    int ks = blockIdx.y;
    int k0 = ks * 256;
    const int pos[4] = {335, 419, 440, 445};
    int seg = ks >> 1;
    int dbase = (ks & 1) * 256;
#pragma unroll 8
    for (int r = 0; r < 32; ++r)
        es[r][tid] = seq[((size_t)r * S + pos[seg]) * D + dbase + tid];
#pragma unroll
    for (int e = 0; e < 8; ++e)
        wsm[tid][e] = w[(size_t)(k0 + tid) * PRED_N + n0 + e];
    __syncthreads();
    int b = tid >> 3, nn = tid & 7;
    float acc = 0.0f;
#pragma unroll 8
    for (int kk = 0; kk < 256; ++kk)
        acc += es[b][kk] * wsm[kk][nn];
    part[(size_t)ks * (BB * PRED_N) + (size_t)b * PRED_N + n0 + nn] = acc;
}

__launch_bounds__(256)
__global__ void pred_reduce_kernel(const float* __restrict__ part, float* __restrict__ out) {
    int idx = blockIdx.x * 256 + threadIdx.x;
    if (idx >= BB * PRED_N) return;
    float s = 0.0f;
#pragma unroll
    for (int k = 0; k < 8; ++k) s += part[(size_t)k * (BB * PRED_N) + idx];
    out[idx] = s;
}

// ===========================================================================
// PATH B: cooperative megakernel (round-23 body, launched with queried grid)
// ===========================================================================

struct P {
    const float *x_enc, *x_mark, *cew, *tw, *tb;
    const float *down_w, *down_b, *cscm_w, *cscm_b, *bn_g, *bn_b;
    const float *up_w, *up_b, *cln_g, *cln_b;
    const float *wq, *wk, *wv, *wo, *ln1_g, *ln1_b;
    const float *w1, *b1, *w2, *b2, *ln2_g, *ln2_b, *pred_w;
    float* out;
    short *emb_bf, *xim, *wE, *xd_bf, *cs1, *cs2, *cs3;
    short *seq_bf, *QKV, *Ob;
    short *wqkvT, *woT, *w1T, *w2T, *downT, *upT, *cscmT;
    float *pe, *coarse, *seq, *part, *partsk, *csc_sc, *csc_sh;
};

__device__ inline void wtrans_tile_p(const float* __restrict__ W, short* __restrict__ Wt,
                                     int Kd, int Nd, int n0, int k0, int tid,
                                     float (*tile)[33]) {
    int tx = tid & 31, ty = tid >> 5;
#pragma unroll
    for (int r = 0; r < 32; r += 8)
        tile[ty + r][tx] = W[(size_t)(k0 + ty + r) * Nd + n0 + tx];
    __syncthreads();
#pragma unroll
    for (int r = 0; r < 32; r += 8)
        Wt[(size_t)(n0 + ty + r) * Kd + k0 + tx] = f2bf(tile[tx][ty + r]);
}

__device__ inline void prep_vb(const P& p, int blk, int tid, float (*tile)[33]) {
    if (blk < 3072) {
        int z = blk >> 8, rem = blk & 255;
        int l = z >> 2, part = z & 3;
        const float* src = (part == 0 ? p.wq : part == 1 ? p.wk : part == 2 ? p.wv : p.wo)
                           + (size_t)l * D * D;
        short* dst = (part < 3) ? p.wqkvT + (size_t)l * 3 * D * D + (size_t)part * D * D
                                : p.woT + (size_t)l * D * D;
        wtrans_tile_p(src, dst, D, D, (rem & 15) * 32, (rem >> 4) * 32, tid, tile);
    } else if (blk < 3072 + 6144) {
        int b2 = blk - 3072;
        int z = b2 >> 10, rem = b2 & 1023;
        int l = z >> 1, part = z & 1;
        int bx = rem & 63, by = rem >> 6;
        int nt = part ? by : bx;
        int kt = part ? bx : by;
        if (part == 0)
            wtrans_tile_p(p.w1 + (size_t)l * D * DFF, p.w1T + (size_t)l * DFF * D,
                          D, DFF, nt * 32, kt * 32, tid, tile);
        else
            wtrans_tile_p(p.w2 + (size_t)l * DFF * D, p.w2T + (size_t)l * D * DFF,
                          DFF, D, nt * 32, kt * 32, tid, tile);
    } else if (blk < 3072 + 6144 + 640) {
        int b3 = blk - (3072 + 6144);
        if (b3 < 64) {
            wtrans_tile_p(p.down_w, p.downT, D, DBOT, (b3 & 3) * 32, (b3 >> 2) * 32, tid, tile);
        } else if (b3 < 128) {
            int b4 = b3 - 64;
            wtrans_tile_p(p.up_w, p.upT, DBOT, D, (b4 & 15) * 32, (b4 >> 4) * 32, tid, tile);
        } else {
            int idx = (b3 - 128) * 256 + tid;
            if (idx < 2 * DBOT * 512) {
                int l = idx >> 16;
                int rem = idx & 65535;
                int oc = rem >> 9, j = rem & 511;
                int r = j >> 7, c = j & 127;
                p.cscmT[idx] = f2bf(p.cscm_w[(((size_t)l * DBOT + oc) * DBOT + c) * 4 + r]);
            }
            if (idx < 3 * DBOT) {
                p.csc_sc[idx] = p.bn_g[idx];
                p.csc_sh[idx] = p.cscm_b[idx] * p.bn_g[idx] + p.bn_b[idx];
            }
        }
    } else {
        int idx = (blk - (3072 + 6144 + 640)) * 256 + tid;
        if (idx < PE_N) {
            int d = idx % D, t = idx / D;
            int e = d & ~1;
            float div = expf(-(float)e * (logf(10000.0f) / (float)D));
            float arg = (float)t * div;
            p.pe[idx] = (d & 1) ? cosf(arg) : sinf(arg);
        } else if (idx - PE_N < WE_N) {
            int i2 = idx - PE_N;
            int k = i2 & 31, d = i2 >> 5;
            float v = 0.0f;
            if (k < 21) {
                int w = k / 7, i = k % 7;
                v = p.cew[(size_t)d * (CIN * 3) + i * 3 + w];
            } else if (k < 25) {
                v = p.tw[(size_t)(k - 21) * D + d];
            } else if (k == 25) {
                v = p.tb[d];
            }
            p.wE[i2] = f2bf(v);
        } else if (idx - PE_N - WE_N < XIM_N) {
            int i3 = idx - PE_N - WE_N;
            int k = i3 & 31, m = i3 >> 5;
            int t = m % L, b = m / L;
            float v = 0.0f;
            if (k < 21) {
                int w = k / 7, i = k % 7;
                int s = t + w - 1;
                if (s < 0) s = L - 1;
                if (s >= L) s = 0;
                v = p.x_enc[((size_t)b * L + s) * CIN + i];
            } else if (k < 25) {
                v = p.x_mark[(size_t)m * MARK + (k - 21)];
            } else if (k == 25) {
                v = 1.0f;
            }
            p.xim[i3] = f2bf(v);
        }
    }
}

__device__ __forceinline__ void gemm_tile(
    const P& p, const short* __restrict__ A, const short* __restrict__ Bt,
    short* As, short* Bs,
    int Kd, int Nd, int m0, int n0, int kbase, int kb,
    int amode, int alvl, int acnt, int clvl, int ccnt, int epi,
    const float* __restrict__ bias, const float* __restrict__ bias2,
    float* __restrict__ outF, short* __restrict__ outB, size_t outOff, int tid)
{
    int lane = tid & 63, wid = tid >> 6;
    int wm = wid >> 1, wn = wid & 1;
    int lr = lane & 15, lk = lane >> 4;

    const short* aad[2];
    size_t bbase[2];
#pragma unroll
    for (int r = 0; r < 2; ++r) {
        int u = r * 256 + tid;
        int row = ((u >> 3) << 1) | ((u >> 2) & 1);
        int kg  = (u & 3) ^ ((u >> 3) & 3);
        int rm = m0 + row;
        const short* ab;
        if (amode == 1) {
            int j = rm >> 5; if (j > acnt - 1) j = acnt - 1;
            ab = A + (size_t)((rm & 31) * S + d_sets.idx[alvl][j]) * Kd;
        } else if (amode == 2) {
            if (rm < BB * LC) {
                int b = rm / LC, t = rm % LC;
                if (t < L1)           ab = p.cs1 + (size_t)(b * L1 + t) * DBOT;
                else if (t < L1 + L2) ab = p.cs2 + (size_t)(b * L2 + (t - L1)) * DBOT;
                else                  ab = p.cs3 + (size_t)(b * L3 + (t - L1 - L2)) * DBOT;
            } else ab = p.cs1;
        } else {
            ab = A + (size_t)rm * Kd;
        }
        aad[r] = ab + kbase + kg * 8;
        bbase[r] = (size_t)(n0 + row) * Kd + kbase + kg * 8;
    }
    auto rd_off = [&](int row_) {
        int rh = row_ >> 1;
        int sx = lk ^ (rh & 3);
        return (size_t)(rh * 8 + (row_ & 1) * 4 + sx) * 8;
    };

    float4v acc[4][4];
#pragma unroll
    for (int i = 0; i < 4; ++i)
#pragma unroll
        for (int j = 0; j < 4; ++j) acc[i][j] = 0;

    const int nt = kb >> 5;
#pragma unroll
    for (int r = 0; r < 2; ++r) {
        gload_lds16(aad[r], As + (size_t)(r * 256 + wid * 64) * 8);
        gload_lds16(Bt + bbase[r], Bs + (size_t)(r * 256 + wid * 64) * 8);
    }
    for (int t = 0; t < nt; ++t) {
        int cur = t & 1;
        if (t + 1 < nt) {
            int k0 = (t + 1) * 32;
            int nb = (cur ^ 1) * 4096;
#pragma unroll
            for (int r = 0; r < 2; ++r) {
                gload_lds16(aad[r] + k0, As + nb + (size_t)(r * 256 + wid * 64) * 8);
                gload_lds16(Bt + bbase[r] + k0, Bs + nb + (size_t)(r * 256 + wid * 64) * 8);
            }
            asm volatile("s_waitcnt vmcnt(4)" ::: "memory");
        } else {
            asm volatile("s_waitcnt vmcnt(0)" ::: "memory");
        }
        __builtin_amdgcn_s_barrier();
        short8 af[4], bfv[4];
#pragma unroll
        for (int mi = 0; mi < 4; ++mi)
            af[mi] = *(const short8*)(As + cur * 4096 + rd_off(wm * 64 + mi * 16 + lr));
#pragma unroll
        for (int ni = 0; ni < 4; ++ni)
            bfv[ni] = *(const short8*)(Bs + cur * 4096 + rd_off(wn * 64 + ni * 16 + lr));
        __builtin_amdgcn_s_setprio(1);
#pragma unroll
        for (int mi = 0; mi < 4; ++mi)
#pragma unroll
            for (int ni = 0; ni < 4; ++ni)
                acc[mi][ni] = __builtin_amdgcn_mfma_f32_16x16x32_bf16(
                    af[mi], bfv[ni], acc[mi][ni], 0, 0, 0);
        __builtin_amdgcn_s_setprio(0);
        __builtin_amdgcn_s_barrier();
    }

#pragma unroll
    for (int mi = 0; mi < 4; ++mi) {
        int gmc = m0 + wm * 64 + mi * 16 + lk * 4;
#pragma unroll
        for (int ni = 0; ni < 4; ++ni) {
            int gn = n0 + wn * 64 + ni * 16 + lr;
            float bsv = (epi == 1 || epi == 3 || epi == 4) ? bias[gn] : 0.0f;
            float sc = (epi == 5) ? bias[gn]  : 0.0f;
            float sh = (epi == 5) ? bias2[gn] : 0.0f;
#pragma unroll
            for (int e = 0; e < 4; ++e) {
                int rm = gmc + e, grow;
                if (clvl >= 0) { int j = rm >> 5; if (j > ccnt - 1) j = ccnt - 1; grow = (rm & 31) * S + d_sets.idx[clvl][j]; }
                else grow = rm;
                float v = acc[mi][ni][e] + bsv;
                if (epi == 3) v = 0.5f * v * (1.0f + erff(v * 0.70710678118654752f));
                if (epi == 5) { v = v * sc + sh; v = v > 0.0f ? v : (expf(v) - 1.0f); }
                if (epi == 6) {
                    v += p.pe[(size_t)(grow % L) * D + gn];
                    outB[(size_t)grow * Nd + gn] = f2bf(v);
                } else if (epi == 1) {
                    outF[(size_t)grow * Nd + gn] = v;
                } else if (epi == 7) {
                    outF[outOff + (size_t)grow * Nd + gn] = v;
                } else {
                    outB[(size_t)grow * Nd + gn] = f2bf(v);
                }
            }
        }
    }
}

__device__ inline void concat_ln_row(const P& p, int row, int tid, float* wsA, float* wsB) {
    int b = row & 31, j = row >> 5;
    int s = d_sets.idx[0][j];
    int orig = b * S + s;
    float x0, x1;
    if (s < L) {
        const short* src = p.emb_bf + ((size_t)b * L + s) * D;
        x0 = bf2f(src[tid]); x1 = bf2f(src[tid + 256]);
    } else {
        const float* src = p.coarse + ((size_t)b * LC + (s - L)) * D;
        x0 = src[tid]; x1 = src[tid + 256];
    }
    float mu = blk_reduce(x0 + x1, wsA, tid) * (1.0f / D);
    float d0 = x0 - mu, d1 = x1 - mu;
    float var = blk_reduce(d0 * d0 + d1 * d1, wsB, tid) * (1.0f / D);
    float rstd = rsqrtf(var + 1e-5f);
    float v0 = d0 * rstd * p.cln_g[tid]       + p.cln_b[tid];
    float v1 = d1 * rstd * p.cln_g[tid + 256] + p.cln_b[tid + 256];
    float* dst = p.seq + (size_t)orig * D;
    dst[tid] = v0; dst[tid + 256] = v1;
    short* dbf = p.seq_bf + (size_t)orig * D;
    dbf[tid] = f2bf(v0); dbf[tid + 256] = f2bf(v1);
}

__device__ inline void add_ln_row(const P& p, int row, int tid, const float* bias,
                                  const float* g, const float* bta,
                                  int lvl, int Mpad, int KS, float* wsA, float* wsB) {
    int b = row & 31, j = row >> 5;
    int orig = b * S + d_sets.idx[lvl][j];
    float a0 = 0.0f, a1 = 0.0f;
    for (int k = 0; k < KS; ++k) {
        const float* pr = p.partsk + ((size_t)k * Mpad + row) * D;
        a0 += pr[tid];
        a1 += pr[tid + 256];
    }
    if (bias) { a0 += bias[tid]; a1 += bias[tid + 256]; }
    float* srow = p.seq + (size_t)orig * D;
    float x0 = srow[tid] + a0;
    float x1 = srow[tid + 256] + a1;
    float mu = blk_reduce(x0 + x1, wsA, tid) * (1.0f / D);
    float d0 = x0 - mu, d1 = x1 - mu;
    float var = blk_reduce(d0 * d0 + d1 * d1, wsB, tid) * (1.0f / D);
    float rstd = rsqrtf(var + 1e-5f);
    float v0 = d0 * rstd * g[tid]       + bta[tid];
    float v1 = d1 * rstd * g[tid + 256] + bta[tid + 256];
    srow[tid] = v0; srow[tid + 256] = v1;
    short* dbf = p.seq_bf + (size_t)orig * D;
    dbf[tid] = f2bf(v0); dbf[tid + 256] = f2bf(v1);
}

__device__ inline void attn_vb(const P& p, int vb, int tid, int lvl, int cnt) {
    int wid = vb * 4 + (tid >> 6);
    if (wid >= cnt * 32) return;
    int lane = tid & 63;
    int b = wid & 31, j = wid >> 5;
    int i = d_sets.idx[lvl][j];
    const short8 qv = *(const short8*)(p.QKV + (size_t)(b * S + i) * 1536 + lane * 8);
    float qf[8];
#pragma unroll
    for (int e = 0; e < 8; ++e) qf[e] = bf2f(qv[e]);
    int nb[NMAX];
#pragma unroll
    for (int jj = 0; jj < NMAX; ++jj) nb[jj] = d_sets.nbr[i][jj];
    float sc[NMAX];
#pragma unroll
    for (int jj = 0; jj < NMAX; ++jj) {
        float s = -1e30f;
        if (nb[jj] >= 0) {
            const short8 kv = *(const short8*)(p.QKV + (size_t)(b * S + nb[jj]) * 1536 + 512 + lane * 8);
            s = 0.0f;
#pragma unroll
            for (int e = 0; e < 8; ++e) s += qf[e] * bf2f(kv[e]);
            s += __shfl_xor(s, 1); s += __shfl_xor(s, 2); s += __shfl_xor(s, 4);
            s *= 0.125f;
        }
        sc[jj] = s;
    }
    float mx = sc[0];
#pragma unroll
    for (int jj = 1; jj < NMAX; ++jj) mx = fmaxf(mx, sc[jj]);
    float sum = 0.0f;
    float accv[8] = {};
#pragma unroll
    for (int jj = 0; jj < NMAX; ++jj) {
        float pr = expf(sc[jj] - mx);
        sum += pr;
        if (nb[jj] >= 0) {
            const short8 vv = *(const short8*)(p.QKV + (size_t)(b * S + nb[jj]) * 1536 + 1024 + lane * 8);
#pragma unroll
            for (int e = 0; e < 8; ++e) accv[e] += pr * bf2f(vv[e]);
        }
    }
    float inv = 1.0f / sum;
    short8 ov;
#pragma unroll
    for (int e = 0; e < 8; ++e) ov[e] = f2bf(accv[e] * inv);
    *(short8*)(p.Ob + (size_t)wid * D + lane * 8) = ov;
}

__device__ inline void conv3_vb(const P& p, int vb, int tid, char* lds_pool) {
    float* insh = (float*)lds_pool;
    int half = tid >> 7, t2 = tid & 127;
    int bid = vb * 2 + half;
    int to = bid % L3, b = bid / L3;
    float* my = insh + half * 512;
#pragma unroll
    for (int r = 0; r < 4; ++r)
        my[r * DBOT + t2] = bf2f(p.cs2[((size_t)(b * L2 + to * 4 + r)) * DBOT + t2]);
    __syncthreads();
    const float* w = p.cscm_w + 2 * DBOT * DBOT * 4;
    float acc = p.cscm_b[2 * DBOT + t2];
    const float* wr = w + (size_t)t2 * (DBOT * 4);
    for (int c = 0; c < DBOT; ++c) {
#pragma unroll
        for (int r = 0; r < 4; ++r)
            acc += my[r * DBOT + c] * wr[c * 4 + r];
    }
    acc = acc * p.bn_g[2 * DBOT + t2] + p.bn_b[2 * DBOT + t2];
    p.cs3[((size_t)(b * L3 + to)) * DBOT + t2] = f2bf(acc > 0.0f ? acc : (expf(acc) - 1.0f));
    __syncthreads();
}

__device__ inline void pred_vb(const P& p, int vb, int tid, char* lds_pool) {
    float (*es)[257] = (float(*)[257])lds_pool;
    float (*wsm)[8]  = (float(*)[8])(lds_pool + 32 * 257 * 4);
    int n0 = (vb % 84) * 8;
    int ks = vb / 84;
    int k0 = ks * 256;
    const int pos[4] = {335, 419, 440, 445};
    int seg = ks >> 1;
    int dbase = (ks & 1) * 256;
#pragma unroll 8
    for (int r = 0; r < 32; ++r)
        es[r][tid] = p.seq[((size_t)r * S + pos[seg]) * D + dbase + tid];
#pragma unroll
    for (int e = 0; e < 8; ++e)
        wsm[tid][e] = p.pred_w[(size_t)(k0 + tid) * PRED_N + n0 + e];
    __syncthreads();
    int b = tid >> 3, nn = tid & 7;
    float acc = 0.0f;
#pragma unroll 8
    for (int kk = 0; kk < 256; ++kk)
        acc += es[b][kk] * wsm[kk][nn];
    p.part[(size_t)ks * (BB * PRED_N) + (size_t)b * PRED_N + n0 + nn] = acc;
    __syncthreads();
}

__launch_bounds__(256, 2)
__global__ void fused_fwd(P p) {
    __shared__ __align__(16) char lds_pool[41088];
    __shared__ float wsA[4], wsB[4];
    short* As = (short*)lds_pool;
    short* Bs = (short*)(lds_pool + 16384);
    cg::grid_group grid = cg::this_grid();
    int tid = threadIdx.x;
    int nbk = gridDim.x;

    {
        float (*tile)[33] = (float(*)[33])lds_pool;
        for (int vb = blockIdx.x; vb < PREP_BLKS; vb += nbk) {
            prep_vb(p, vb, tid, tile);
            __syncthreads();
        }
    }
    grid.sync();
    for (int vb = blockIdx.x; vb < 4 * 84; vb += nbk) {
        int bx = vb & 3, by = vb >> 2;
        gemm_tile(p, p.xim, p.wE, As, Bs, 32, D, by * 128, bx * 128, 0, 32,
                  0, 0, 0, -1, 0, 6, nullptr, nullptr, nullptr, p.emb_bf, 0, tid);
    }
    grid.sync();
    for (int vb = blockIdx.x; vb < 84; vb += nbk)
        gemm_tile(p, p.emb_bf, p.downT, As, Bs, 512, DBOT, vb * 128, 0, 0, 512,
                  0, 0, 0, -1, 0, 4, p.down_b, nullptr, nullptr, p.xd_bf, 0, tid);
    grid.sync();
    for (int vb = blockIdx.x; vb < 21; vb += nbk)
        gemm_tile(p, p.xd_bf, p.cscmT, As, Bs, 512, DBOT, vb * 128, 0, 0, 512,
                  0, 0, 0, -1, 0, 5, p.csc_sc, p.csc_sh, nullptr, p.cs1, 0, tid);
    grid.sync();
    for (int vb = blockIdx.x; vb < 6; vb += nbk)
        gemm_tile(p, p.cs1, p.cscmT + (size_t)DBOT * 512, As, Bs, 512, DBOT, vb * 128, 0, 0, 512,
                  0, 0, 0, -1, 0, 5, p.csc_sc + DBOT, p.csc_sh + DBOT, nullptr, p.cs2, 0, tid);
    grid.sync();
    for (int vb = blockIdx.x; vb < 80; vb += nbk)
        conv3_vb(p, vb, tid, lds_pool);
    grid.sync();
    for (int vb = blockIdx.x; vb < 4 * 28; vb += nbk) {
        int bx = vb & 3, by = vb >> 2;
        gemm_tile(p, p.cs1, p.upT, As, Bs, DBOT, D, by * 128, bx * 128, 0, DBOT,
                  2, 0, 0, -1, 0, 1, p.up_b, nullptr, p.coarse, nullptr, 0, tid);
    }
    grid.sync();
    {
        int c0 = d_sets.cnt[0] * 32;
        for (int vb = blockIdx.x; vb < c0; vb += nbk)
            concat_ln_row(p, vb, tid, wsA, wsB);
    }
    grid.sync();

    for (int l = 0; l < NLAYER; ++l) {
        int inCnt = d_sets.cnt[l], outCnt = d_sets.cnt[l + 1];
        int Mc = outCnt * 32;
        int mtIn = (inCnt * 32 + 127) >> 7;
        int Mpad = ((Mc + 127) >> 7) << 7;
        int mtOut = Mpad >> 7;
        int KS2 = (Mc <= 512) ? 8 : 4;
        int kb2 = DFF / KS2;

        for (int vb = blockIdx.x; vb < 12 * mtIn; vb += nbk) {
            int bx = vb % 12, by = vb / 12;
            gemm_tile(p, p.seq_bf, p.wqkvT + (size_t)l * 3 * D * D, As, Bs,
                      512, 3 * D, by * 128, bx * 128, 0, 512,
                      1, l, inCnt, l, inCnt, 2, nullptr, nullptr, nullptr, p.QKV, 0, tid);
        }
        grid.sync();
        for (int vb = blockIdx.x; vb < outCnt * 8; vb += nbk)
            attn_vb(p, vb, tid, l + 1, outCnt);
        grid.sync();
        for (int vb = blockIdx.x; vb < 4 * mtOut * 4; vb += nbk) {
            int bx = vb & 3;
            int rest = vb >> 2;
            int by = rest % mtOut, kz = rest / mtOut;
            gemm_tile(p, p.Ob, p.woT + (size_t)l * D * D, As, Bs,
                      512, D, by * 128, bx * 128, kz * 128, 128,
                      0, 0, 0, -1, 0, 7, nullptr, nullptr, p.partsk, nullptr,
                      (size_t)kz * Mpad * D, tid);
        }
        grid.sync();
        for (int vb = blockIdx.x; vb < Mc; vb += nbk)
            add_ln_row(p, vb, tid, nullptr, p.ln1_g + (size_t)l * D, p.ln1_b + (size_t)l * D,
                       l + 1, Mpad, 4, wsA, wsB);
        grid.sync();
        for (int vb = blockIdx.x; vb < 16 * mtOut; vb += nbk) {
            int bx = vb % 16, by = vb / 16;
            gemm_tile(p, p.seq_bf, p.w1T + (size_t)l * DFF * D, As, Bs,
                      512, DFF, by * 128, bx * 128, 0, 512,
                      1, l + 1, outCnt, -1, 0, 3, p.b1 + (size_t)l * DFF, nullptr,
                      nullptr, p.QKV, 0, tid);
        }
        grid.sync();
        for (int vb = blockIdx.x; vb < 4 * mtOut * KS2; vb += nbk) {
            int bx = vb & 3;
            int rest = vb >> 2;
            int by = rest % mtOut, kz = rest / mtOut;
            gemm_tile(p, p.QKV, p.w2T + (size_t)l * D * DFF, As, Bs,
                      DFF, D, by * 128, bx * 128, kz * kb2, kb2,
                      0, 0, 0, -1, 0, 7, nullptr, nullptr, p.partsk, nullptr,
                      (size_t)kz * Mpad * D, tid);
        }
        grid.sync();
        for (int vb = blockIdx.x; vb < Mc; vb += nbk)
            add_ln_row(p, vb, tid, p.b2 + (size_t)l * D, p.ln2_g + (size_t)l * D,
                       p.ln2_b + (size_t)l * D, l + 1, Mpad, KS2, wsA, wsB);
        grid.sync();
    }

    for (int vb = blockIdx.x; vb < 672; vb += nbk)
        pred_vb(p, vb, tid, lds_pool);
    grid.sync();
    for (int i = blockIdx.x * 256 + tid; i < BB * PRED_N; i += nbk * 256) {
        float s = 0.0f;
#pragma unroll
        for (int k = 0; k < 8; ++k) s += p.part[(size_t)k * (BB * PRED_N) + i];
        p.out[i] = s;
    }
}

// ---------------------------------------------------------------------------
extern "C" void kernel_launch(void* const* d_in, const int* in_sizes, int n_in,
                              void* d_out, int out_size, void* d_ws, size_t ws_size,
                              hipStream_t stream) {
    const float* x_enc      = (const float*)d_in[0];
    const float* x_mark_enc = (const float*)d_in[1];
    const float* conv_embed_w = (const float*)d_in[4];
    const float* time_w  = (const float*)d_in[5];
    const float* time_b  = (const float*)d_in[6];
    const float* down_w  = (const float*)d_in[7];
    const float* down_b  = (const float*)d_in[8];
    const float* cscm_w  = (const float*)d_in[9];
    const float* cscm_b  = (const float*)d_in[10];
    const float* bn_g    = (const float*)d_in[11];
    const float* bn_b    = (const float*)d_in[12];
    const float* up_w    = (const float*)d_in[13];
    const float* up_b    = (const float*)d_in[14];
    const float* cln_g   = (const float*)d_in[15];
    const float* cln_b   = (const float*)d_in[16];
    const float* wq      = (const float*)d_in[17];
    const float* wk      = (const float*)d_in[18];
    const float* wv      = (const float*)d_in[19];
    const float* wo      = (const float*)d_in[20];
    const float* ln1_g   = (const float*)d_in[21];
    const float* ln1_b   = (const float*)d_in[22];
    const float* ffn_w1  = (const float*)d_in[23];
    const float* ffn_b1  = (const float*)d_in[24];
    const float* ffn_w2  = (const float*)d_in[25];
    const float* ffn_b2  = (const float*)d_in[26];
    const float* ln2_g   = (const float*)d_in[27];
    const float* ln2_b   = (const float*)d_in[28];
    const float* pred_w  = (const float*)d_in[29];
    float* out = (float*)d_out;

    // ---- workspace layout (shared by both paths) ----
    char* w8 = (char*)d_ws;
    size_t off = 0;
    auto alloc = [&](size_t bytes) {
        void* pp = w8 + off;
        off = (off + bytes + 255) & ~(size_t)255;
        return pp;
    };
    short* emb_bf = (short*)alloc((size_t)BB * L * D * 2);
    float* pe     = (float*)alloc((size_t)L * D * 4);
    short* xim    = (short*)alloc((size_t)BB * L * 32 * 2);
    short* wE     = (short*)alloc((size_t)D * 32 * 2);
    short* xd_bf  = (short*)alloc((size_t)BB * L * DBOT * 2);
    short* cs1_bf = (short*)alloc((size_t)MCONV2P * 512 * 2);
    short* cs2_bf = (short*)alloc((size_t)MCONV2P * DBOT * 2);
    short* cs3_bf = (short*)alloc((size_t)BB * L3 * DBOT * 2);
    float* coarse = (float*)alloc((size_t)MCAT * D * 4);
    float* seq    = (float*)alloc((size_t)BB * S * D * 4);
    float* part   = (float*)alloc((size_t)8 * BB * PRED_N * 4);
    float* partsk = (float*)alloc(psk_elems() * 4);
    short* seq_bf = (short*)alloc((size_t)MP * D * 2);
    short* QKV    = (short*)alloc((size_t)MP * 3 * D * 2);
    short* Ob     = (short*)alloc((size_t)MP * D * 2);
    short* hidden = QKV;
    short* wqkvT  = (short*)alloc((size_t)NLAYER * 3 * D * D * 2);
    short* woT    = (short*)alloc((size_t)NLAYER * D * D * 2);
    short* w1T    = (short*)alloc((size_t)NLAYER * DFF * D * 2);
    short* w2T    = (short*)alloc((size_t)NLAYER * D * DFF * 2);
    short* downT  = (short*)alloc((size_t)DBOT * D * 2);
    short* upT    = (short*)alloc((size_t)D * DBOT * 2);
    short* cscmT  = (short*)alloc((size_t)2 * DBOT * 512 * 2);
    float* csc_sc = (float*)alloc((size_t)3 * DBOT * 4);
    float* csc_sh = (float*)alloc((size_t)3 * DBOT * 4);
    (void)ws_size; (void)in_sizes; (void)n_in; (void)out_size;

    const int rowsL = BB * L;
    dim3 blk(256);

    // ---- attempt cooperative megakernel (grid sized by occupancy query) ----
    P prm;
    prm.x_enc = x_enc; prm.x_mark = x_mark_enc; prm.cew = conv_embed_w;
    prm.tw = time_w; prm.tb = time_b;
    prm.down_w = down_w; prm.down_b = down_b; prm.cscm_w = cscm_w; prm.cscm_b = cscm_b;
    prm.bn_g = bn_g; prm.bn_b = bn_b; prm.up_w = up_w; prm.up_b = up_b;
    prm.cln_g = cln_g; prm.cln_b = cln_b;
    prm.wq = wq; prm.wk = wk; prm.wv = wv; prm.wo = wo;
    prm.ln1_g = ln1_g; prm.ln1_b = ln1_b;
    prm.w1 = ffn_w1; prm.b1 = ffn_b1; prm.w2 = ffn_w2; prm.b2 = ffn_b2;
    prm.ln2_g = ln2_g; prm.ln2_b = ln2_b; prm.pred_w = pred_w; prm.out = out;
    prm.emb_bf = emb_bf; prm.xim = xim; prm.wE = wE; prm.xd_bf = xd_bf;
    prm.cs1 = cs1_bf; prm.cs2 = cs2_bf; prm.cs3 = cs3_bf;
    prm.seq_bf = seq_bf; prm.QKV = QKV; prm.Ob = Ob;
    prm.wqkvT = wqkvT; prm.woT = woT; prm.w1T = w1T; prm.w2T = w2T;
    prm.downT = downT; prm.upT = upT; prm.cscmT = cscmT;
    prm.pe = pe; prm.coarse = coarse; prm.seq = seq; prm.part = part;
    prm.partsk = partsk; prm.csc_sc = csc_sc; prm.csc_sh = csc_sh;

    bool coop_done = false;
    int maxBlk = 0;
    if (hipOccupancyMaxActiveBlocksPerMultiprocessor(
            &maxBlk, reinterpret_cast<const void*>(&fused_fwd), 256, 0) == hipSuccess
        && maxBlk > 0) {
        if (maxBlk > 3) maxBlk = 3;
        int grid = maxBlk * 256;   // 256 CUs on MI355X
        void* args[] = { &prm };
        if (hipLaunchCooperativeKernel(reinterpret_cast<const void*>(&fused_fwd),
                                       dim3(grid), dim3(256), args, 0, stream)
            == hipSuccess)
            coop_done = true;
    }
    if (coop_done) return;

    // ---- fallback: round-22 multi-kernel pipeline (known good) ----
    prep_all<<<dim3(PREP_BLKS), blk, 0, stream>>>(
        wq, wk, wv, wo, wqkvT, woT,
        ffn_w1, ffn_w2, w1T, w2T,
        down_w, downT, up_w, upT,
        cscm_w, cscm_b, bn_g, bn_b, cscmT, csc_sc, csc_sh,
        x_enc, x_mark_enc, conv_embed_w, time_w, time_b, pe, wE, xim);
    mfma_gemm<6><<<dim3(D / 128, rowsL / 128), blk, 0, stream>>>(
        xim, wE, nullptr, nullptr, nullptr, 32, D, -1, -1, 0, pe, emb_bf);
    mfma_gemm_sk<<<dim3(1, rowsL / 128, 4), blk, 0, stream>>>(
        emb_bf, downT, partsk, D, DBOT, -1, 0);
    reduce_sk<4><<<dim3((rowsL * DBOT + 255) / 256), blk, 0, stream>>>(
        partsk, down_b, nullptr, xd_bf, rowsL, DBOT, 4);
    mfma_gemm_sk<<<dim3(1, MCONV1 / 128, 4), blk, 0, stream>>>(
        xd_bf, cscmT, partsk, 512, DBOT, -1, 0);
    reduce_sk<5><<<dim3((MCONV1 * DBOT + 255) / 256), blk, 0, stream>>>(
        partsk, csc_sc, csc_sh, cs1_bf, MCONV1, DBOT, 4);
    mfma_gemm_sk<<<dim3(1, MCONV2P / 128, 4), blk, 0, stream>>>(
        cs1_bf, cscmT + (size_t)DBOT * 512, partsk, 512, DBOT, -1, 0);
    reduce_sk<5><<<dim3((MCONV2P * DBOT + 255) / 256), blk, 0, stream>>>(
        partsk, csc_sc + DBOT, csc_sh + DBOT, cs2_bf, MCONV2P, DBOT, 4);
    cscm_conv_bf16<<<dim3(BB * L3), dim3(DBOT), 0, stream>>>(
        cs2_bf, L2, cs3_bf, cscm_w + 2 * DBOT * DBOT * 4,
        cscm_b + 2 * DBOT, bn_g + 2 * DBOT, bn_b + 2 * DBOT, L3);
    mfma_gemm_up<<<dim3(D / 128, MCAT / 128), blk, 0, stream>>>(
        cs1_bf, cs2_bf, cs3_bf, upT, up_b, coarse);
    concat_ln_idx<<<dim3(HS.cnt[0] * 32), blk, 0, stream>>>(
        emb_bf, coarse, cln_g, cln_b, seq, seq_bf);

    for (int l = 0; l < NLAYER; ++l) {
        const int inLvl = l, outLvl = l + 1;
        const int inCnt  = HS.cnt[l];
        const int outCnt = HS.cnt[l + 1];
        const int Mc   = outCnt * 32;
        const int Mpad = ((Mc + 127) / 128) * 128;
        mfma_gemm<2><<<dim3(3 * D / 128, (inCnt * 32 + 127) / 128), blk, 0, stream>>>(
            seq_bf, wqkvT + (size_t)l * 3 * D * D, nullptr, nullptr, QKV, D, 3 * D,
            inLvl, inLvl, inCnt, nullptr, nullptr);
        attn_sparse_kernel<<<dim3(outCnt * 8), blk, 0, stream>>>(
            QKV, Ob, outLvl, outCnt);
        mfma_gemm_sk<<<dim3(D / 128, Mpad / 128, 4), blk, 0, stream>>>(
            Ob, woT + (size_t)l * D * D, partsk, D, D, -1, 0);
        add_ln_sk<<<dim3(Mc), blk, 0, stream>>>(
            seq, partsk, nullptr, ln1_g + (size_t)l * D, ln1_b + (size_t)l * D,
            seq_bf, outLvl, Mpad, 4);
        if (Mc <= 512) {
            mfma_gemm_sk<<<dim3(DFF / 128, Mpad / 128, 4), blk, 0, stream>>>(
                seq_bf, w1T + (size_t)l * DFF * D, partsk, D, DFF, outLvl, outCnt);
            reduce_sk<3><<<dim3((Mpad * DFF + 255) / 256), blk, 0, stream>>>(
                partsk, ffn_b1 + (size_t)l * DFF, nullptr, hidden, Mpad, DFF, 4);
        } else {
            mfma_gemm<3><<<dim3(DFF / 128, Mpad / 128), blk, 0, stream>>>(
                seq_bf, w1T + (size_t)l * DFF * D, ffn_b1 + (size_t)l * DFF, nullptr,
                hidden, D, DFF, outLvl, -1, outCnt, nullptr, nullptr);
        }
        {
            int KS = (Mc <= 512) ? 8 : 4;
            mfma_gemm_sk<<<dim3(D / 128, Mpad / 128, KS), blk, 0, stream>>>(
                hidden, w2T + (size_t)l * D * DFF, partsk, DFF, D, -1, 0);
            add_ln_sk<<<dim3(Mc), blk, 0, stream>>>(
                seq, partsk, ffn_b2 + (size_t)l * D, ln2_g + (size_t)l * D,
                ln2_b + (size_t)l * D, seq_bf, outLvl, Mpad, KS);
        }
    }

    pred_kernel<<<dim3(PRED_N / 8, 8), blk, 0, stream>>>(seq, pred_w, part);
    pred_reduce_kernel<<<dim3((BB * PRED_N + 255) / 256), blk, 0, stream>>>(part, out);
}

// Round 25
// 348.686 us; speedup vs baseline: 3.4203x; 3.4203x over previous
//
#include <hip/hip_runtime.h>
#include <math.h>

// ---- problem constants ----
constexpr int BB   = 32;    // batch
constexpr int L    = 336;   // seq_len
constexpr int CIN  = 7;
constexpr int MARK = 4;
constexpr int D    = 512;   // d_model
constexpr int DFF  = 2048;
constexpr int S    = 446;   // 336+84+21+5
constexpr int DBOT = 128;
constexpr int L1 = 84, L2 = 21, L3 = 5;
constexpr int LC = 110;     // 84+21+5
constexpr int NLAYER = 3;
constexpr int PRED_N = 672; // 96*7
constexpr int MP   = 14336; // BB*S padded
constexpr int NMAX = 12;    // max sparse neighbors (real max 10)
constexpr int MCONV1 = BB * L1;          // 2688 = 21*128 (exact)
constexpr int MCONV2P = 768;             // BB*L2=672 padded to 6*128
constexpr int MCAT  = 3584;              // BB*LC=3520 padded to 28*128

using short8  = __attribute__((ext_vector_type(8))) short;
using float4v = __attribute__((ext_vector_type(4))) float;

// ---------------------------------------------------------------------------
// COMPILE-TIME pyramid structure: neighbor lists + active sets.
// ---------------------------------------------------------------------------
struct SetsData {
    int nbr[S][NMAX];
    int idx[4][S];
    int cnt[4];
};

constexpr SetsData compute_sets() {
    SetsData sd{};
    constexpr int sizes[4]  = {336, 84, 21, 5};
    constexpr int starts[4] = {0, 336, 420, 441};
    for (int i = 0; i < S; ++i) {
        int li = 0, pi = i;
        if (i < 336)      { li = 0; pi = i; }
        else if (i < 420) { li = 1; pi = i - 336; }
        else if (i < 441) { li = 2; pi = i - 420; }
        else              { li = 3; pi = i - 441; }
        int cnt = 0;
        for (int d = -2; d <= 2; ++d) {
            int q = pi + d;
            if (q >= 0 && q < sizes[li]) sd.nbr[i][cnt++] = starts[li] + q;
        }
        if (li > 0) {
            int lo = pi * 4;
            int hi = (pi == sizes[li] - 1) ? sizes[li - 1] : (pi + 1) * 4;
            for (int c = lo; c < hi; ++c) sd.nbr[i][cnt++] = starts[li - 1] + c;
        }
        if (li < 3) {
            int q = pi >> 2;
            if (q > sizes[li + 1] - 1) q = sizes[li + 1] - 1;
            sd.nbr[i][cnt++] = starts[li + 1] + q;
        }
        for (int j = cnt; j < NMAX; ++j) sd.nbr[i][j] = -1;
    }
    sd.cnt[3] = 4;
    sd.idx[3][0] = 335; sd.idx[3][1] = 419; sd.idx[3][2] = 440; sd.idx[3][3] = 445;
    for (int lvl = 3; lvl >= 1; --lvl) {
        bool mk[S] = {};
        for (int k = 0; k < sd.cnt[lvl]; ++k) {
            int i = sd.idx[lvl][k];
            for (int t = 0; t < NMAX; ++t) {
                int v = sd.nbr[i][t];
                if (v >= 0) mk[v] = true;
            }
        }
        int nc = 0;
        for (int i = 0; i < S; ++i)
            if (mk[i]) sd.idx[lvl - 1][nc++] = i;
        sd.cnt[lvl - 1] = nc;
    }
    return sd;
}

constexpr SetsData HS = compute_sets();         // host: grid sizing
__constant__ SetsData d_sets = compute_sets();  // device: row maps + nbr

// exact split-K partial buffer size (elements), from compile-time counts
// (r22 thresholds: wo always split-K; ffn1 split-K for Mc<=512)
constexpr size_t psk_elems() {
    size_t mx = 4 * (size_t)BB * L * DBOT;      // down-proj split-K (5.5M)
    {
        size_t v = 4 * (size_t)MCONV1 * DBOT; if (v > mx) mx = v;   // conv1
        v = 4 * (size_t)MCONV2P * DBOT;       if (v > mx) mx = v;   // conv2
    }
    for (int l = 0; l < NLAYER; ++l) {
        size_t Mc = (size_t)HS.cnt[l + 1] * 32;
        size_t Mpad = ((Mc + 127) / 128) * 128;
        { size_t v = 4 * Mpad * 512;  if (v > mx) mx = v; }                  // wo (always)
        if (Mc <= 512) { size_t v = 4 * Mpad * 2048; if (v > mx) mx = v; }   // ffn1
        size_t ks = (Mc <= 512) ? 8 : 4;
        size_t v = ks * Mpad * 512; if (v > mx) mx = v;                      // ffn2
    }
    return mx;
}

__device__ inline short f2bf(float f) {
    union { float f; unsigned u; } v; v.f = f;
    unsigned r = v.u + 0x7fffu + ((v.u >> 16) & 1u);
    return (short)(r >> 16);
}
__device__ inline float bf2f(short h) {
    union { unsigned u; float f; } v; v.u = ((unsigned)(unsigned short)h) << 16;
    return v.f;
}

// async global->LDS, 16B per lane, wave-uniform LDS base + lane*16
__device__ inline void gload_lds16(const void* g, void* l) {
    __builtin_amdgcn_global_load_lds(
        (const __attribute__((address_space(1))) void*)g,
        (__attribute__((address_space(3))) void*)l, 16, 0, 0);
}

// Staging map: conflict-free + coalesced (verified r11: 0 bank conflicts).
// Sparse rows: alvl/clvl >= 0 select d_sets.idx[lvl] (pos-major compact:
// compact m -> b=m&31, j=m>>5 clamped to cnt-1, orig row b*S+idx[j]).

// ---------------------------------------------------------------------------
// 128x128 bf16 MFMA GEMM, BK=32, double-buffered, counted vmcnt(4) pipeline.
// EPI: 0 f32; 1 f32+bias; 2 bf16; 3 bf16+bias+gelu; 4 bf16+bias;
//      5 bf16, v = acc*bias[gn]+bias2[gn] then ELU;
//      6 v = acc + peT[(row%L)*D+gn] -> bf16 Cout2 only (embed)
// ---------------------------------------------------------------------------
template<int EPI>
__launch_bounds__(256, 4)
__global__ void mfma_gemm(const short* __restrict__ A, const short* __restrict__ Bt,
                          const float* __restrict__ bias, const float* __restrict__ bias2,
                          void* __restrict__ Cout, int Kd, int Nd,
                          int alvl, int clvl, int cnt,
                          const float* __restrict__ peT, short* __restrict__ Cout2) {
    __shared__ short As[2][128 * 32];
    __shared__ short Bs[2][128 * 32];
    int tid = threadIdx.x;
    int nwg  = gridDim.x * gridDim.y;
    int orig = blockIdx.y * gridDim.x + blockIdx.x;
    int qq = nwg >> 3, rr = nwg & 7;
    int xcd = orig & 7, idx = orig >> 3;
    int wgid = (xcd < rr ? xcd * (qq + 1) : rr * (qq + 1) + (xcd - rr) * qq) + idx;
    int m0 = (wgid / gridDim.x) * 128, n0 = (wgid % gridDim.x) * 128;

    int lane = tid & 63, wid = tid >> 6;
    int wm = wid >> 1, wn = wid & 1;
    int lr = lane & 15, lk = lane >> 4;

    size_t abase[2], bbase[2];
#pragma unroll
    for (int r = 0; r < 2; ++r) {
        int u = r * 256 + tid;
        int row = ((u >> 3) << 1) | ((u >> 2) & 1);
        int kg  = (u & 3) ^ ((u >> 3) & 3);
        int rm = m0 + row, ga;
        if (alvl >= 0) { int j = rm >> 5; if (j > cnt - 1) j = cnt - 1; ga = (rm & 31) * S + d_sets.idx[alvl][j]; }
        else ga = rm;
        abase[r] = (size_t)ga * Kd + kg * 8;
        bbase[r] = (size_t)(n0 + row) * Kd + kg * 8;
    }
    auto stage = [&](int buf, int k0) {
#pragma unroll
        for (int r = 0; r < 2; ++r) {
            short* la = As[buf] + (size_t)(r * 256 + wid * 64) * 8;
            short* lb = Bs[buf] + (size_t)(r * 256 + wid * 64) * 8;
            gload_lds16(A + abase[r] + k0, la);
            gload_lds16(Bt + bbase[r] + k0, lb);
        }
    };
    auto rd_off = [&](int row_) {
        int rh = row_ >> 1;
        int s  = lk ^ (rh & 3);
        return (size_t)(rh * 8 + (row_ & 1) * 4 + s) * 8;
    };

    float4v acc[4][4];
#pragma unroll
    for (int i = 0; i < 4; ++i)
#pragma unroll
        for (int j = 0; j < 4; ++j) acc[i][j] = 0;

    const int nt = Kd >> 5;
    stage(0, 0);
    for (int t = 0; t < nt; ++t) {
        int cur = t & 1;
        if (t + 1 < nt) {
            stage(cur ^ 1, (t + 1) * 32);
            asm volatile("s_waitcnt vmcnt(4)" ::: "memory");
        } else {
            asm volatile("s_waitcnt vmcnt(0)" ::: "memory");
        }
        __builtin_amdgcn_s_barrier();
        short8 af[4], bfv[4];
#pragma unroll
        for (int mi = 0; mi < 4; ++mi)
            af[mi] = *(const short8*)(As[cur] + rd_off(wm * 64 + mi * 16 + lr));
#pragma unroll
        for (int ni = 0; ni < 4; ++ni)
            bfv[ni] = *(const short8*)(Bs[cur] + rd_off(wn * 64 + ni * 16 + lr));
        __builtin_amdgcn_s_setprio(1);
#pragma unroll
        for (int mi = 0; mi < 4; ++mi)
#pragma unroll
            for (int ni = 0; ni < 4; ++ni)
                acc[mi][ni] = __builtin_amdgcn_mfma_f32_16x16x32_bf16(
                    af[mi], bfv[ni], acc[mi][ni], 0, 0, 0);
        __builtin_amdgcn_s_setprio(0);
        __builtin_amdgcn_s_barrier();
    }

#pragma unroll
    for (int mi = 0; mi < 4; ++mi) {
        int gmc = m0 + wm * 64 + mi * 16 + lk * 4;
#pragma unroll
        for (int ni = 0; ni < 4; ++ni) {
            int gn = n0 + wn * 64 + ni * 16 + lr;
            float bsv = (EPI == 1 || EPI == 3 || EPI == 4) ? bias[gn] : 0.0f;
            float sc = (EPI == 5) ? bias[gn]  : 0.0f;
            float sh = (EPI == 5) ? bias2[gn] : 0.0f;
#pragma unroll
            for (int e = 0; e < 4; ++e) {
                int rm = gmc + e, grow;
                if (clvl >= 0) { int j = rm >> 5; if (j > cnt - 1) j = cnt - 1; grow = (rm & 31) * S + d_sets.idx[clvl][j]; }
                else grow = rm;
                float v = acc[mi][ni][e] + bsv;
                if (EPI == 3) v = 0.5f * v * (1.0f + erff(v * 0.70710678118654752f));
                if (EPI == 5) { v = v * sc + sh; v = v > 0.0f ? v : (expf(v) - 1.0f); }
                if (EPI == 6) {
                    v += peT[(size_t)(grow % L) * D + gn];
                    Cout2[(size_t)grow * Nd + gn] = f2bf(v);
                } else if (EPI <= 1) {
                    ((float*)Cout)[(size_t)grow * Nd + gn] = v;
                } else {
                    ((short*)Cout)[(size_t)grow * Nd + gn] = f2bf(v);
                }
            }
        }
    }
}

// ---------------------------------------------------------------------------
// up-projection GEMM with INLINE concat gather (r21)
// ---------------------------------------------------------------------------
__launch_bounds__(256, 4)
__global__ void mfma_gemm_up(const short* __restrict__ cs1, const short* __restrict__ cs2,
                             const short* __restrict__ cs3, const short* __restrict__ Bt,
                             const float* __restrict__ bias, float* __restrict__ Cout) {
    __shared__ short As[2][128 * 32];
    __shared__ short Bs[2][128 * 32];
    int tid = threadIdx.x;
    int nwg  = gridDim.x * gridDim.y;
    int orig = blockIdx.y * gridDim.x + blockIdx.x;
    int qq = nwg >> 3, rr = nwg & 7;
    int xcd = orig & 7, idx = orig >> 3;
    int wgid = (xcd < rr ? xcd * (qq + 1) : rr * (qq + 1) + (xcd - rr) * qq) + idx;
    int m0 = (wgid / gridDim.x) * 128, n0 = (wgid % gridDim.x) * 128;
    const int Kd = DBOT, Nd = D;

    int lane = tid & 63, wid = tid >> 6;
    int wm = wid >> 1, wn = wid & 1;
    int lr = lane & 15, lk = lane >> 4;

    const short* aad[2];
    size_t bbase[2];
#pragma unroll
    for (int r = 0; r < 2; ++r) {
        int u = r * 256 + tid;
        int row = ((u >> 3) << 1) | ((u >> 2) & 1);
        int kg  = (u & 3) ^ ((u >> 3) & 3);
        int rm = m0 + row;
        const short* base;
        if (rm < BB * LC) {
            int b = rm / LC, t = rm % LC;
            if (t < L1)           base = cs1 + (size_t)(b * L1 + t) * DBOT;
            else if (t < L1 + L2) base = cs2 + (size_t)(b * L2 + (t - L1)) * DBOT;
            else                  base = cs3 + (size_t)(b * L3 + (t - L1 - L2)) * DBOT;
        } else {
            base = cs1;   // pad row: garbage computed, never read
        }
        aad[r] = base + kg * 8;
        bbase[r] = (size_t)(n0 + row) * Kd + kg * 8;
    }
    auto stage = [&](int buf, int k0) {
#pragma unroll
        for (int r = 0; r < 2; ++r) {
            short* la = As[buf] + (size_t)(r * 256 + wid * 64) * 8;
            short* lb = Bs[buf] + (size_t)(r * 256 + wid * 64) * 8;
            gload_lds16(aad[r] + k0, la);
            gload_lds16(Bt + bbase[r] + k0, lb);
        }
    };
    auto rd_off = [&](int row_) {
        int rh = row_ >> 1;
        int s  = lk ^ (rh & 3);
        return (size_t)(rh * 8 + (row_ & 1) * 4 + s) * 8;
    };

    float4v acc[4][4];
#pragma unroll
    for (int i = 0; i < 4; ++i)
#pragma unroll
        for (int j = 0; j < 4; ++j) acc[i][j] = 0;

    const int nt = Kd >> 5;   // 4
    stage(0, 0);
    for (int t = 0; t < nt; ++t) {
        int cur = t & 1;
        if (t + 1 < nt) {
            stage(cur ^ 1, (t + 1) * 32);
            asm volatile("s_waitcnt vmcnt(4)" ::: "memory");
        } else {
            asm volatile("s_waitcnt vmcnt(0)" ::: "memory");
        }
        __builtin_amdgcn_s_barrier();
        short8 af[4], bfv[4];
#pragma unroll
        for (int mi = 0; mi < 4; ++mi)
            af[mi] = *(const short8*)(As[cur] + rd_off(wm * 64 + mi * 16 + lr));
#pragma unroll
        for (int ni = 0; ni < 4; ++ni)
            bfv[ni] = *(const short8*)(Bs[cur] + rd_off(wn * 64 + ni * 16 + lr));
        __builtin_amdgcn_s_setprio(1);
#pragma unroll
        for (int mi = 0; mi < 4; ++mi)
#pragma unroll
            for (int ni = 0; ni < 4; ++ni)
                acc[mi][ni] = __builtin_amdgcn_mfma_f32_16x16x32_bf16(
                    af[mi], bfv[ni], acc[mi][ni], 0, 0, 0);
        __builtin_amdgcn_s_setprio(0);
        __builtin_amdgcn_s_barrier();
    }

#pragma unroll
    for (int mi = 0; mi < 4; ++mi) {
        int gmc = m0 + wm * 64 + mi * 16 + lk * 4;
#pragma unroll
        for (int ni = 0; ni < 4; ++ni) {
            int gn = n0 + wn * 64 + ni * 16 + lr;
            float bsv = bias[gn];
#pragma unroll
            for (int e = 0; e < 4; ++e)
                Cout[(size_t)(gmc + e) * Nd + gn] = acc[mi][ni][e] + bsv;
        }
    }
}

// ---------------------------------------------------------------------------
// SPLIT-K variant: gridDim.z = KS slices; writes f32 partial part[kz][Mpad][Nd].
// ---------------------------------------------------------------------------
__launch_bounds__(256, 4)
__global__ void mfma_gemm_sk(const short* __restrict__ A, const short* __restrict__ Bt,
                             float* __restrict__ part, int Kd, int Nd,
                             int alvl, int cnt) {
    __shared__ short As[2][128 * 32];
    __shared__ short Bs[2][128 * 32];
    int tid = threadIdx.x;
    int nwg  = gridDim.x * gridDim.y;
    int orig = blockIdx.y * gridDim.x + blockIdx.x;
    int qq = nwg >> 3, rr = nwg & 7;
    int xcd = orig & 7, idx = orig >> 3;
    int wgid = (xcd < rr ? xcd * (qq + 1) : rr * (qq + 1) + (xcd - rr) * qq) + idx;
    int m0 = (wgid / gridDim.x) * 128, n0 = (wgid % gridDim.x) * 128;
    int Mpad = gridDim.y * 128;
    int kz = blockIdx.z;
    int kb = Kd / gridDim.z;          // slice length (multiple of 32)
    int kbase = kz * kb;

    int lane = tid & 63, wid = tid >> 6;
    int wm = wid >> 1, wn = wid & 1;
    int lr = lane & 15, lk = lane >> 4;

    size_t abase[2], bbase[2];
#pragma unroll
    for (int r = 0; r < 2; ++r) {
        int u = r * 256 + tid;
        int row = ((u >> 3) << 1) | ((u >> 2) & 1);
        int kg  = (u & 3) ^ ((u >> 3) & 3);
        int rm = m0 + row, ga;
        if (alvl >= 0) { int j = rm >> 5; if (j > cnt - 1) j = cnt - 1; ga = (rm & 31) * S + d_sets.idx[alvl][j]; }
        else ga = rm;
        abase[r] = (size_t)ga * Kd + kbase + kg * 8;
        bbase[r] = (size_t)(n0 + row) * Kd + kbase + kg * 8;
    }
    auto stage = [&](int buf, int k0) {
#pragma unroll
        for (int r = 0; r < 2; ++r) {
            short* la = As[buf] + (size_t)(r * 256 + wid * 64) * 8;
            short* lb = Bs[buf] + (size_t)(r * 256 + wid * 64) * 8;
            gload_lds16(A + abase[r] + k0, la);
            gload_lds16(Bt + bbase[r] + k0, lb);
        }
    };
    auto rd_off = [&](int row_) {
        int rh = row_ >> 1;
        int s  = lk ^ (rh & 3);
        return (size_t)(rh * 8 + (row_ & 1) * 4 + s) * 8;
    };

    float4v acc[4][4];
#pragma unroll
    for (int i = 0; i < 4; ++i)
#pragma unroll
        for (int j = 0; j < 4; ++j) acc[i][j] = 0;

    const int nt = kb >> 5;
    stage(0, 0);
    for (int t = 0; t < nt; ++t) {
        int cur = t & 1;
        if (t + 1 < nt) {
            stage(cur ^ 1, (t + 1) * 32);
            asm volatile("s_waitcnt vmcnt(4)" ::: "memory");
        } else {
            asm volatile("s_waitcnt vmcnt(0)" ::: "memory");
        }
        __builtin_amdgcn_s_barrier();
        short8 af[4], bfv[4];
#pragma unroll
        for (int mi = 0; mi < 4; ++mi)
            af[mi] = *(const short8*)(As[cur] + rd_off(wm * 64 + mi * 16 + lr));
#pragma unroll
        for (int ni = 0; ni < 4; ++ni)
            bfv[ni] = *(const short8*)(Bs[cur] + rd_off(wn * 64 + ni * 16 + lr));
        __builtin_amdgcn_s_setprio(1);
#pragma unroll
        for (int mi = 0; mi < 4; ++mi)
#pragma unroll
            for (int ni = 0; ni < 4; ++ni)
                acc[mi][ni] = __builtin_amdgcn_mfma_f32_16x16x32_bf16(
                    af[mi], bfv[ni], acc[mi][ni], 0, 0, 0);
        __builtin_amdgcn_s_setprio(0);
        __builtin_amdgcn_s_barrier();
    }

#pragma unroll
    for (int mi = 0; mi < 4; ++mi) {
        int gmc = m0 + wm * 64 + mi * 16 + lk * 4;
#pragma unroll
        for (int ni = 0; ni < 4; ++ni) {
            int gn = n0 + wn * 64 + ni * 16 + lr;
#pragma unroll
            for (int e = 0; e < 4; ++e)
                part[((size_t)kz * Mpad + gmc + e) * Nd + gn] = acc[mi][ni][e];
        }
    }
}

// sum KS partials + epilogue -> bf16 compact output
// EPI: 3 +bias+gelu; 4 +bias; 5 *bias+bias2 then ELU (conv BN fold)
template<int EPI>
__launch_bounds__(256)
__global__ void reduce_sk(const float* __restrict__ part, const float* __restrict__ bias,
                          const float* __restrict__ bias2, short* __restrict__ Cout,
                          int Mpad, int Nd, int KS) {
    int idx = blockIdx.x * 256 + threadIdx.x;
    if (idx >= Mpad * Nd) return;
    float s = 0.0f;
    for (int k = 0; k < KS; ++k)
        s += part[(size_t)k * Mpad * Nd + idx];
    int n = idx % Nd;
    if (EPI == 3 || EPI == 4) s += bias[n];
    if (EPI == 3) s = 0.5f * s * (1.0f + erff(s * 0.70710678118654752f));
    if (EPI == 5) { s = s * bias[n] + bias2[n]; s = s > 0.0f ? s : (expf(s) - 1.0f); }
    Cout[idx] = f2bf(s);
}

// ---------------------------------------------------------------------------
// weight transpose tile helper
// ---------------------------------------------------------------------------
__device__ inline void wtrans_tile(const float* __restrict__ W, short* __restrict__ Wt,
                                   int Kd, int Nd, int n0, int k0, int tid) {
    __shared__ float tile[32][33];
    int tx = tid & 31, ty = tid >> 5; // ty 0..7
#pragma unroll
    for (int r = 0; r < 32; r += 8)
        tile[ty + r][tx] = W[(size_t)(k0 + ty + r) * Nd + n0 + tx];
    __syncthreads();
#pragma unroll
    for (int r = 0; r < 32; r += 8)
        Wt[(size_t)(n0 + ty + r) * Kd + k0 + tx] = f2bf(tile[tx][ty + r]);
}

// ---------------------------------------------------------------------------
// ONE fused prep kernel: all weight transposes + small prep + pe/wE/xim.
// ---------------------------------------------------------------------------
constexpr int PE_N  = L * D;           // 172032
constexpr int WE_N  = D * 32;          // 16384
constexpr int XIM_N = BB * L * 32;     // 344064
constexpr int MISC_N = PE_N + WE_N + XIM_N;
constexpr int PREP_BLKS = 3072 + 6144 + 640 + (MISC_N + 255) / 256;

__launch_bounds__(256)
__global__ void prep_all(const float* __restrict__ wq, const float* __restrict__ wk,
                         const float* __restrict__ wv, const float* __restrict__ wo,
                         short* __restrict__ wqkvT, short* __restrict__ woT,
                         const float* __restrict__ w1, const float* __restrict__ w2,
                         short* __restrict__ w1T, short* __restrict__ w2T,
                         const float* __restrict__ down_w, short* __restrict__ downT,
                         const float* __restrict__ up_w, short* __restrict__ upT,
                         const float* __restrict__ cw, const float* __restrict__ cb,
                         const float* __restrict__ bg, const float* __restrict__ bb,
                         short* __restrict__ cscmT, float* __restrict__ sc,
                         float* __restrict__ sh,
                         const float* __restrict__ x_enc, const float* __restrict__ x_mark,
                         const float* __restrict__ cew, const float* __restrict__ tw,
                         const float* __restrict__ tb, float* __restrict__ pe,
                         short* __restrict__ wE, short* __restrict__ xim) {
    int blk = blockIdx.x;
    int tid = threadIdx.x;
    if (blk < 3072) {
        int z = blk >> 8, rem = blk & 255;
        int l = z >> 2, part = z & 3;
        const float* src = (part == 0 ? wq : part == 1 ? wk : part == 2 ? wv : wo)
                           + (size_t)l * D * D;
        short* dst = (part < 3) ? wqkvT + (size_t)l * 3 * D * D + (size_t)part * D * D
                                : woT + (size_t)l * D * D;
        wtrans_tile(src, dst, D, D, (rem & 15) * 32, (rem >> 4) * 32, tid);
        return;
    }
    blk -= 3072;
    if (blk < 6144) {
        int z = blk >> 10, rem = blk & 1023;
        int l = z >> 1, part = z & 1;
        int bx = rem & 63, by = rem >> 6;
        int nt = part ? by : bx;
        int kt = part ? bx : by;
        if (part == 0)
            wtrans_tile(w1 + (size_t)l * D * DFF, w1T + (size_t)l * DFF * D,
                        D, DFF, nt * 32, kt * 32, tid);
        else
            wtrans_tile(w2 + (size_t)l * DFF * D, w2T + (size_t)l * D * DFF,
                        DFF, D, nt * 32, kt * 32, tid);
        return;
    }
    blk -= 6144;
    if (blk < 640) {
        if (blk < 64) {
            wtrans_tile(down_w, downT, D, DBOT, (blk & 3) * 32, (blk >> 2) * 32, tid);
        } else if (blk < 128) {
            int b2 = blk - 64;
            wtrans_tile(up_w, upT, DBOT, D, (b2 & 15) * 32, (b2 >> 4) * 32, tid);
        } else {
            int idx = (blk - 128) * 256 + tid;
            if (idx < 2 * DBOT * 512) {
                int l = idx >> 16;
                int rem = idx & 65535;
                int oc = rem >> 9, j = rem & 511;
                int r = j >> 7, c = j & 127;
                cscmT[idx] = f2bf(cw[(((size_t)l * DBOT + oc) * DBOT + c) * 4 + r]);
            }
            if (idx < 3 * DBOT) {
                sc[idx] = bg[idx];
                sh[idx] = cb[idx] * bg[idx] + bb[idx];
            }
        }
        return;
    }
    blk -= 640;
    {
        int idx = blk * 256 + tid;
        if (idx < PE_N) {
            int d = idx % D, t = idx / D;
            int e = d & ~1;
            float div = expf(-(float)e * (logf(10000.0f) / (float)D));
            float arg = (float)t * div;
            pe[idx] = (d & 1) ? cosf(arg) : sinf(arg);
            return;
        }
        int i2 = idx - PE_N;
        if (i2 < WE_N) {
            int k = i2 & 31, d = i2 >> 5;
            float v = 0.0f;
            if (k < 21) {
                int w = k / 7, i = k % 7;
                v = cew[(size_t)d * (CIN * 3) + i * 3 + w];
            } else if (k < 25) {
                v = tw[(size_t)(k - 21) * D + d];
            } else if (k == 25) {
                v = tb[d];
            }
            wE[i2] = f2bf(v);
            return;
        }
        int i3 = i2 - WE_N;
        if (i3 < XIM_N) {
            int k = i3 & 31, m = i3 >> 5;
            int t = m % L, b = m / L;
            float v = 0.0f;
            if (k < 21) {
                int w = k / 7, i = k % 7;
                int s = t + w - 1;
                if (s < 0) s = L - 1;
                if (s >= L) s = 0;
                v = x_enc[((size_t)b * L + s) * CIN + i];
            } else if (k < 25) {
                v = x_mark[(size_t)m * MARK + (k - 21)];
            } else if (k == 25) {
                v = 1.0f;
            }
            xim[i3] = f2bf(v);
        }
    }
}

// ---------------------------------------------------------------------------
// CSCM conv level 3 (tiny)
// ---------------------------------------------------------------------------
__launch_bounds__(128)
__global__ void cscm_conv_bf16(const short* __restrict__ in, int inRowsPerB,
                               short* __restrict__ outp, const float* __restrict__ w,
                               const float* __restrict__ cb, const float* __restrict__ bng,
                               const float* __restrict__ bnb, int Lout) {
    int bid = blockIdx.x;
    int to = bid % Lout, b = bid / Lout;
    __shared__ float insh[4 * DBOT];
    int tid = threadIdx.x;
#pragma unroll
    for (int r = 0; r < 4; ++r)
        insh[r * DBOT + tid] = bf2f(in[((size_t)(b * inRowsPerB + to * 4 + r)) * DBOT + tid]);
    __syncthreads();
    float acc = cb[tid];
    const float* wr = w + (size_t)tid * (DBOT * 4);
    for (int c = 0; c < DBOT; ++c) {
#pragma unroll
        for (int r = 0; r < 4; ++r)
            acc += insh[r * DBOT + c] * wr[c * 4 + r];
    }
    acc = acc * bng[tid] + bnb[tid];
    outp[((size_t)(b * Lout + to)) * DBOT + tid] = f2bf(acc > 0.0f ? acc : (expf(acc) - 1.0f));
}

// ---------------------------------------------------------------------------
// sparse attention over active level (compact Ob)
// ---------------------------------------------------------------------------
__launch_bounds__(256)
__global__ void attn_sparse_kernel(const short* __restrict__ QKV, short* __restrict__ Ob,
                                   int lvl, int cnt) {
    int wid  = blockIdx.x * 4 + (threadIdx.x >> 6);
    if (wid >= cnt * 32) return;
    int lane = threadIdx.x & 63;
    int b = wid & 31, j = wid >> 5;
    int i = d_sets.idx[lvl][j];
    const short8 qv = *(const short8*)(QKV + (size_t)(b * S + i) * 1536 + lane * 8);
    float qf[8];
#pragma unroll
    for (int e = 0; e < 8; ++e) qf[e] = bf2f(qv[e]);
    int nb[NMAX];
#pragma unroll
    for (int jj = 0; jj < NMAX; ++jj) nb[jj] = d_sets.nbr[i][jj];
    float sc[NMAX];
#pragma unroll
    for (int jj = 0; jj < NMAX; ++jj) {
        float s = -1e30f;
        if (nb[jj] >= 0) {
            const short8 kv = *(const short8*)(QKV + (size_t)(b * S + nb[jj]) * 1536 + 512 + lane * 8);
            s = 0.0f;
#pragma unroll
            for (int e = 0; e < 8; ++e) s += qf[e] * bf2f(kv[e]);
            s += __shfl_xor(s, 1); s += __shfl_xor(s, 2); s += __shfl_xor(s, 4);
            s *= 0.125f;
        }
        sc[jj] = s;
    }
    float mx = sc[0];
#pragma unroll
    for (int jj = 1; jj < NMAX; ++jj) mx = fmaxf(mx, sc[jj]);
    float sum = 0.0f;
    float accv[8] = {};
#pragma unroll
    for (int jj = 0; jj < NMAX; ++jj) {
        float p = expf(sc[jj] - mx);
        sum += p;
        if (nb[jj] >= 0) {
            const short8 vv = *(const short8*)(QKV + (size_t)(b * S + nb[jj]) * 1536 + 1024 + lane * 8);
#pragma unroll
            for (int e = 0; e < 8; ++e) accv[e] += p * bf2f(vv[e]);
        }
    }
    float inv = 1.0f / sum;
    short8 ov;
#pragma unroll
    for (int e = 0; e < 8; ++e) ov[e] = f2bf(accv[e] * inv);
    *(short8*)(Ob + (size_t)wid * D + lane * 8) = ov;
}

// ---------------------------------------------------------------------------
// wave-shuffle block reduction over 4 waves (256 thr)
// ---------------------------------------------------------------------------
__device__ inline float blk_reduce(float v, float* ws4, int tid) {
#pragma unroll
    for (int o = 32; o; o >>= 1) v += __shfl_xor(v, o);
    if ((tid & 63) == 0) ws4[tid >> 6] = v;
    __syncthreads();
    return ws4[0] + ws4[1] + ws4[2] + ws4[3];
}

// ---------------------------------------------------------------------------
// concat(emb_bf, coarse) + LayerNorm at A_0 rows only
// ---------------------------------------------------------------------------
__launch_bounds__(256)
__global__ void concat_ln_idx(const short* __restrict__ emb_bf, const float* __restrict__ coarse,
                              const float* __restrict__ g, const float* __restrict__ bta,
                              float* __restrict__ seq, short* __restrict__ seq_bf) {
    int row = blockIdx.x;
    int b = row & 31, j = row >> 5;
    int s = d_sets.idx[0][j];
    int orig = b * S + s;
    __shared__ float wsA[4];
    __shared__ float wsB[4];
    int tid = threadIdx.x;
    float x0, x1;
    if (s < L) {
        const short* src = emb_bf + ((size_t)b * L + s) * D;
        x0 = bf2f(src[tid]); x1 = bf2f(src[tid + 256]);
    } else {
        const float* src = coarse + ((size_t)b * LC + (s - L)) * D;
        x0 = src[tid]; x1 = src[tid + 256];
    }
    float mu = blk_reduce(x0 + x1, wsA, tid) * (1.0f / D);
    float d0 = x0 - mu, d1 = x1 - mu;
    float var = blk_reduce(d0 * d0 + d1 * d1, wsB, tid) * (1.0f / D);
    float rstd = rsqrtf(var + 1e-5f);
    float v0 = d0 * rstd * g[tid]       + bta[tid];
    float v1 = d1 * rstd * g[tid + 256] + bta[tid + 256];
    float* dst = seq + (size_t)orig * D;
    dst[tid] = v0; dst[tid + 256] = v1;
    short* dbf = seq_bf + (size_t)orig * D;
    dbf[tid] = f2bf(v0); dbf[tid + 256] = f2bf(v1);
}

// ---------------------------------------------------------------------------
// fused split-K reduce + residual LN
// ---------------------------------------------------------------------------
__launch_bounds__(256)
__global__ void add_ln_sk(float* __restrict__ seq, const float* __restrict__ part,
                          const float* __restrict__ bias, const float* __restrict__ g,
                          const float* __restrict__ bta, short* __restrict__ seq_bf,
                          int lvl, int Mpad, int KS) {
    int row = blockIdx.x;
    int b = row & 31, j = row >> 5;
    int orig = b * S + d_sets.idx[lvl][j];
    __shared__ float wsA[4];
    __shared__ float wsB[4];
    int tid = threadIdx.x;
    float a0 = 0.0f, a1 = 0.0f;
    for (int k = 0; k < KS; ++k) {
        const float* pr = part + ((size_t)k * Mpad + row) * D;
        a0 += pr[tid];
        a1 += pr[tid + 256];
    }
    if (bias) { a0 += bias[tid]; a1 += bias[tid + 256]; }
    float* srow = seq + (size_t)orig * D;
    float x0 = srow[tid] + a0;
    float x1 = srow[tid + 256] + a1;
    float mu = blk_reduce(x0 + x1, wsA, tid) * (1.0f / D);
    float d0 = x0 - mu, d1 = x1 - mu;
    float var = blk_reduce(d0 * d0 + d1 * d1, wsB, tid) * (1.0f / D);
    float rstd = rsqrtf(var + 1e-5f);
    float v0 = d0 * rstd * g[tid]       + bta[tid];
    float v1 = d1 * rstd * g[tid + 256] + bta[tid + 256];
    srow[tid] = v0; srow[tid + 256] = v1;
    short* dbf = seq_bf + (size_t)orig * D;
    dbf[tid] = f2bf(v0); dbf[tid + 256] = f2bf(v1);
}

// ---------------------------------------------------------------------------
// prediction head: FULL K=2048 per block (fused gather + GEMM + write out).
// One block per 8 output cols; 8 sequential 256-col slabs (same summation
// order as the old split-K + reduce pair -> bitwise-identical output).
// ---------------------------------------------------------------------------
__launch_bounds__(256)
__global__ void pred_full_kernel(const float* __restrict__ seq, const float* __restrict__ w,
                                 float* __restrict__ out) {
    __shared__ float es[32][257];
    __shared__ float wsm[256][8];
    int tid = threadIdx.x;
    int n0 = blockIdx.x * 8;
    const int pos[4] = {335, 419, 440, 445};
    int b = tid >> 3, nn = tid & 7;
    float acc = 0.0f;
    for (int ks = 0; ks < 8; ++ks) {
        int k0 = ks * 256;
        int seg = ks >> 1;
        int dbase = (ks & 1) * 256;
#pragma unroll 8
        for (int r = 0; r < 32; ++r)
            es[r][tid] = seq[((size_t)r * S + pos[seg]) * D + dbase + tid];
#pragma unroll
        for (int e = 0; e < 8; ++e)
            wsm[tid][e] = w[(size_t)(k0 + tid) * PRED_N + n0 + e];
        __syncthreads();
#pragma unroll 8
        for (int kk = 0; kk < 256; ++kk)
            acc += es[b][kk] * wsm[kk][nn];
        __syncthreads();
    }
    out[(size_t)b * PRED_N + n0 + nn] = acc;
}

// ---------------------------------------------------------------------------
extern "C" void kernel_launch(void* const* d_in, const int* in_sizes, int n_in,
                              void* d_out, int out_size, void* d_ws, size_t ws_size,
                              hipStream_t stream) {
    const float* x_enc      = (const float*)d_in[0];
    const float* x_mark_enc = (const float*)d_in[1];
    const float* conv_embed_w = (const float*)d_in[4];
    const float* time_w  = (const float*)d_in[5];
    const float* time_b  = (const float*)d_in[6];
    const float* down_w  = (const float*)d_in[7];
    const float* down_b  = (const float*)d_in[8];
    const float* cscm_w  = (const float*)d_in[9];
    const float* cscm_b  = (const float*)d_in[10];
    const float* bn_g    = (const float*)d_in[11];
    const float* bn_b    = (const float*)d_in[12];
    const float* up_w    = (const float*)d_in[13];
    const float* up_b    = (const float*)d_in[14];
    const float* cln_g   = (const float*)d_in[15];
    const float* cln_b   = (const float*)d_in[16];
    const float* wq      = (const float*)d_in[17];
    const float* wk      = (const float*)d_in[18];
    const float* wv      = (const float*)d_in[19];
    const float* wo      = (const float*)d_in[20];
    const float* ln1_g   = (const float*)d_in[21];
    const float* ln1_b   = (const float*)d_in[22];
    const float* ffn_w1  = (const float*)d_in[23];
    const float* ffn_b1  = (const float*)d_in[24];
    const float* ffn_w2  = (const float*)d_in[25];
    const float* ffn_b2  = (const float*)d_in[26];
    const float* ln2_g   = (const float*)d_in[27];
    const float* ln2_b   = (const float*)d_in[28];
    const float* pred_w  = (const float*)d_in[29];
    float* out = (float*)d_out;

    // ---- workspace layout (bytes, 256-aligned) ----
    char* w8 = (char*)d_ws;
    size_t off = 0;
    auto alloc = [&](size_t bytes) {
        void* p = w8 + off;
        off = (off + bytes + 255) & ~(size_t)255;
        return p;
    };
    short* emb_bf = (short*)alloc((size_t)BB * L * D * 2);
    float* pe     = (float*)alloc((size_t)L * D * 4);
    short* xim    = (short*)alloc((size_t)BB * L * 32 * 2);
    short* wE     = (short*)alloc((size_t)D * 32 * 2);
    short* xd_bf  = (short*)alloc((size_t)BB * L * DBOT * 2);
    short* cs1_bf = (short*)alloc((size_t)MCONV2P * 512 * 2);
    short* cs2_bf = (short*)alloc((size_t)MCONV2P * DBOT * 2);
    short* cs3_bf = (short*)alloc((size_t)BB * L3 * DBOT * 2);
    float* coarse = (float*)alloc((size_t)MCAT * D * 4);
    float* seq    = (float*)alloc((size_t)BB * S * D * 4);
    float* partsk = (float*)alloc(psk_elems() * 4);   // split-K partials (exact)
    short* seq_bf = (short*)alloc((size_t)MP * D * 2);
    short* QKV    = (short*)alloc((size_t)MP * 3 * D * 2);  // + Ob contiguous
    short* Ob     = (short*)alloc((size_t)MP * D * 2);
    short* hidden = QKV;
    short* wqkvT  = (short*)alloc((size_t)NLAYER * 3 * D * D * 2);
    short* woT    = (short*)alloc((size_t)NLAYER * D * D * 2);
    short* w1T    = (short*)alloc((size_t)NLAYER * DFF * D * 2);
    short* w2T    = (short*)alloc((size_t)NLAYER * D * DFF * 2);
    short* downT  = (short*)alloc((size_t)DBOT * D * 2);
    short* upT    = (short*)alloc((size_t)D * DBOT * 2);
    short* cscmT  = (short*)alloc((size_t)2 * DBOT * 512 * 2);
    float* csc_sc = (float*)alloc((size_t)3 * DBOT * 4);
    float* csc_sh = (float*)alloc((size_t)3 * DBOT * 4);
    (void)ws_size; (void)in_sizes; (void)n_in; (void)out_size;

    const int rowsL = BB * L;   // 10752 = 84*128
    dim3 blk(256);

    // 0. ONE fused prep kernel
    prep_all<<<dim3(PREP_BLKS), blk, 0, stream>>>(
        wq, wk, wv, wo, wqkvT, woT,
        ffn_w1, ffn_w2, w1T, w2T,
        down_w, downT, up_w, upT,
        cscm_w, cscm_b, bn_g, bn_b, cscmT, csc_sc, csc_sh,
        x_enc, x_mark_enc, conv_embed_w, time_w, time_b, pe, wE, xim);
    // 1. embedding as GEMM + pe epilogue, bf16 out
    mfma_gemm<6><<<dim3(D / 128, rowsL / 128), blk, 0, stream>>>(
        xim, wE, nullptr, nullptr, nullptr, 32, D, -1, -1, 0, pe, emb_bf);
    // 2. down projection -> bf16 (split-K)
    mfma_gemm_sk<<<dim3(1, rowsL / 128, 4), blk, 0, stream>>>(
        emb_bf, downT, partsk, D, DBOT, -1, 0);
    reduce_sk<4><<<dim3((rowsL * DBOT + 255) / 256), blk, 0, stream>>>(
        partsk, down_b, nullptr, xd_bf, rowsL, DBOT, 4);
    // 3. CSCM pyramid (conv1/conv2 split-K)
    mfma_gemm_sk<<<dim3(1, MCONV1 / 128, 4), blk, 0, stream>>>(
        xd_bf, cscmT, partsk, 512, DBOT, -1, 0);
    reduce_sk<5><<<dim3((MCONV1 * DBOT + 255) / 256), blk, 0, stream>>>(
        partsk, csc_sc, csc_sh, cs1_bf, MCONV1, DBOT, 4);
    mfma_gemm_sk<<<dim3(1, MCONV2P / 128, 4), blk, 0, stream>>>(
        cs1_bf, cscmT + (size_t)DBOT * 512, partsk, 512, DBOT, -1, 0);
    reduce_sk<5><<<dim3((MCONV2P * DBOT + 255) / 256), blk, 0, stream>>>(
        partsk, csc_sc + DBOT, csc_sh + DBOT, cs2_bf, MCONV2P, DBOT, 4);
    cscm_conv_bf16<<<dim3(BB * L3), dim3(DBOT), 0, stream>>>(
        cs2_bf, L2, cs3_bf, cscm_w + 2 * DBOT * DBOT * 4,
        cscm_b + 2 * DBOT, bn_g + 2 * DBOT, bn_b + 2 * DBOT, L3);
    // 4. up projection with inline concat gather
    mfma_gemm_up<<<dim3(D / 128, MCAT / 128), blk, 0, stream>>>(
        cs1_bf, cs2_bf, cs3_bf, upT, up_b, coarse);
    // 5. concat + LN (A_0 rows only)
    concat_ln_idx<<<dim3(HS.cnt[0] * 32), blk, 0, stream>>>(
        emb_bf, coarse, cln_g, cln_b, seq, seq_bf);

    // 6. encoder layers (sparse active sets; split-K everywhere it pays)
    for (int l = 0; l < NLAYER; ++l) {
        const int inLvl = l, outLvl = l + 1;
        const int inCnt  = HS.cnt[l];
        const int outCnt = HS.cnt[l + 1];
        const int Mc   = outCnt * 32;
        const int Mpad = ((Mc + 127) / 128) * 128;
        mfma_gemm<2><<<dim3(3 * D / 128, (inCnt * 32 + 127) / 128), blk, 0, stream>>>(
            seq_bf, wqkvT + (size_t)l * 3 * D * D, nullptr, nullptr, QKV, D, 3 * D,
            inLvl, inLvl, inCnt, nullptr, nullptr);
        attn_sparse_kernel<<<dim3(outCnt * 8), blk, 0, stream>>>(
            QKV, Ob, outLvl, outCnt);
        // O-projection + LN1: ALWAYS split-K + fused reduce/LN (r22)
        mfma_gemm_sk<<<dim3(D / 128, Mpad / 128, 4), blk, 0, stream>>>(
            Ob, woT + (size_t)l * D * D, partsk, D, D, -1, 0);
        add_ln_sk<<<dim3(Mc), blk, 0, stream>>>(
            seq, partsk, nullptr, ln1_g + (size_t)l * D, ln1_b + (size_t)l * D,
            seq_bf, outLvl, Mpad, 4);
        // FFN1: split-K for Mc<=512 (r22: covers l1, l2)
        if (Mc <= 512) {
            mfma_gemm_sk<<<dim3(DFF / 128, Mpad / 128, 4), blk, 0, stream>>>(
                seq_bf, w1T + (size_t)l * DFF * D, partsk, D, DFF, outLvl, outCnt);
            reduce_sk<3><<<dim3((Mpad * DFF + 255) / 256), blk, 0, stream>>>(
                partsk, ffn_b1 + (size_t)l * DFF, nullptr, hidden, Mpad, DFF, 4);
        } else {
            mfma_gemm<3><<<dim3(DFF / 128, Mpad / 128), blk, 0, stream>>>(
                seq_bf, w1T + (size_t)l * DFF * D, ffn_b1 + (size_t)l * DFF, nullptr,
                hidden, D, DFF, outLvl, -1, outCnt, nullptr, nullptr);
        }
        // FFN2 + LN2: split-K, reduce fused into LN
        {
            int KS = (Mc <= 512) ? 8 : 4;
            mfma_gemm_sk<<<dim3(D / 128, Mpad / 128, KS), blk, 0, stream>>>(
                hidden, w2T + (size_t)l * D * DFF, partsk, DFF, D, -1, 0);
            add_ln_sk<<<dim3(Mc), blk, 0, stream>>>(
                seq, partsk, ffn_b2 + (size_t)l * D, ln2_g + (size_t)l * D,
                ln2_b + (size_t)l * D, seq_bf, outLvl, Mpad, KS);
        }
    }

    // 7. prediction head: ONE kernel, full K per block (r25 fusion)
    pred_full_kernel<<<dim3(PRED_N / 8), blk, 0, stream>>>(seq, pred_w, out);
}

// Round 26
// 330.810 us; speedup vs baseline: 3.6052x; 1.0540x over previous
//
#include <hip/hip_runtime.h>
#include <math.h>

// ---- problem constants ----
constexpr int BB   = 32;    // batch
constexpr int L    = 336;   // seq_len
constexpr int CIN  = 7;
constexpr int MARK = 4;
constexpr int D    = 512;   // d_model
constexpr int DFF  = 2048;
constexpr int S    = 446;   // 336+84+21+5
constexpr int DBOT = 128;
constexpr int L1 = 84, L2 = 21, L3 = 5;
constexpr int LC = 110;     // 84+21+5
constexpr int NLAYER = 3;
constexpr int PRED_N = 672; // 96*7
constexpr int MP   = 14336; // BB*S padded
constexpr int NMAX = 12;    // max sparse neighbors (real max 10)
constexpr int MCONV1 = BB * L1;          // 2688 = 21*128 (exact)
constexpr int MCONV2P = 768;             // BB*L2=672 padded to 6*128
constexpr int MCAT  = 3584;              // BB*LC=3520 padded to 28*128

using short8  = __attribute__((ext_vector_type(8))) short;
using float4v = __attribute__((ext_vector_type(4))) float;

// ---------------------------------------------------------------------------
// COMPILE-TIME pyramid structure: neighbor lists + active sets.
// ---------------------------------------------------------------------------
struct SetsData {
    int nbr[S][NMAX];
    int idx[4][S];
    int cnt[4];
};

constexpr SetsData compute_sets() {
    SetsData sd{};
    constexpr int sizes[4]  = {336, 84, 21, 5};
    constexpr int starts[4] = {0, 336, 420, 441};
    for (int i = 0; i < S; ++i) {
        int li = 0, pi = i;
        if (i < 336)      { li = 0; pi = i; }
        else if (i < 420) { li = 1; pi = i - 336; }
        else if (i < 441) { li = 2; pi = i - 420; }
        else              { li = 3; pi = i - 441; }
        int cnt = 0;
        for (int d = -2; d <= 2; ++d) {
            int q = pi + d;
            if (q >= 0 && q < sizes[li]) sd.nbr[i][cnt++] = starts[li] + q;
        }
        if (li > 0) {
            int lo = pi * 4;
            int hi = (pi == sizes[li] - 1) ? sizes[li - 1] : (pi + 1) * 4;
            for (int c = lo; c < hi; ++c) sd.nbr[i][cnt++] = starts[li - 1] + c;
        }
        if (li < 3) {
            int q = pi >> 2;
            if (q > sizes[li + 1] - 1) q = sizes[li + 1] - 1;
            sd.nbr[i][cnt++] = starts[li + 1] + q;
        }
        for (int j = cnt; j < NMAX; ++j) sd.nbr[i][j] = -1;
    }
    sd.cnt[3] = 4;
    sd.idx[3][0] = 335; sd.idx[3][1] = 419; sd.idx[3][2] = 440; sd.idx[3][3] = 445;
    for (int lvl = 3; lvl >= 1; --lvl) {
        bool mk[S] = {};
        for (int k = 0; k < sd.cnt[lvl]; ++k) {
            int i = sd.idx[lvl][k];
            for (int t = 0; t < NMAX; ++t) {
                int v = sd.nbr[i][t];
                if (v >= 0) mk[v] = true;
            }
        }
        int nc = 0;
        for (int i = 0; i < S; ++i)
            if (mk[i]) sd.idx[lvl - 1][nc++] = i;
        sd.cnt[lvl - 1] = nc;
    }
    return sd;
}

constexpr SetsData HS = compute_sets();         // host: grid sizing
__constant__ SetsData d_sets = compute_sets();  // device: row maps + nbr

// exact split-K partial buffer size (elements), from compile-time counts
// (r26: wo split-K KS=8 when Mc<=512 else 4; ffn1 split-K for Mc<=512)
constexpr size_t psk_elems() {
    size_t mx = 4 * (size_t)BB * L * DBOT;      // down-proj split-K (5.5M)
    {
        size_t v = 4 * (size_t)MCONV1 * DBOT; if (v > mx) mx = v;   // conv1
        v = 4 * (size_t)MCONV2P * DBOT;       if (v > mx) mx = v;   // conv2
    }
    for (int l = 0; l < NLAYER; ++l) {
        size_t Mc = (size_t)HS.cnt[l + 1] * 32;
        size_t Mpad = ((Mc + 127) / 128) * 128;
        size_t ksw = (Mc <= 512) ? 8 : 4;
        { size_t v = ksw * Mpad * 512; if (v > mx) mx = v; }                 // wo
        if (Mc <= 512) { size_t v = 4 * Mpad * 2048; if (v > mx) mx = v; }   // ffn1
        size_t ks = (Mc <= 512) ? 8 : 4;
        size_t v = ks * Mpad * 512; if (v > mx) mx = v;                      // ffn2
    }
    return mx;
}

__device__ inline short f2bf(float f) {
    union { float f; unsigned u; } v; v.f = f;
    unsigned r = v.u + 0x7fffu + ((v.u >> 16) & 1u);
    return (short)(r >> 16);
}
__device__ inline float bf2f(short h) {
    union { unsigned u; float f; } v; v.u = ((unsigned)(unsigned short)h) << 16;
    return v.f;
}

// async global->LDS, 16B per lane, wave-uniform LDS base + lane*16
__device__ inline void gload_lds16(const void* g, void* l) {
    __builtin_amdgcn_global_load_lds(
        (const __attribute__((address_space(1))) void*)g,
        (__attribute__((address_space(3))) void*)l, 16, 0, 0);
}

// Staging map: conflict-free + coalesced (verified r11: 0 bank conflicts).
// Sparse rows: alvl/clvl >= 0 select d_sets.idx[lvl] (pos-major compact:
// compact m -> b=m&31, j=m>>5 clamped to cnt-1, orig row b*S+idx[j]).

// ---------------------------------------------------------------------------
// 128x128 bf16 MFMA GEMM, BK=32, double-buffered, counted vmcnt(4) pipeline.
// EPI: 0 f32; 1 f32+bias; 2 bf16; 3 bf16+bias+gelu; 4 bf16+bias;
//      5 bf16, v = acc*bias[gn]+bias2[gn] then ELU;
//      6 v = acc + peT[(row%L)*D+gn] -> bf16 Cout2 only (embed)
// ---------------------------------------------------------------------------
template<int EPI>
__launch_bounds__(256, 4)
__global__ void mfma_gemm(const short* __restrict__ A, const short* __restrict__ Bt,
                          const float* __restrict__ bias, const float* __restrict__ bias2,
                          void* __restrict__ Cout, int Kd, int Nd,
                          int alvl, int clvl, int cnt,
                          const float* __restrict__ peT, short* __restrict__ Cout2) {
    __shared__ short As[2][128 * 32];
    __shared__ short Bs[2][128 * 32];
    int tid = threadIdx.x;
    int nwg  = gridDim.x * gridDim.y;
    int orig = blockIdx.y * gridDim.x + blockIdx.x;
    int qq = nwg >> 3, rr = nwg & 7;
    int xcd = orig & 7, idx = orig >> 3;
    int wgid = (xcd < rr ? xcd * (qq + 1) : rr * (qq + 1) + (xcd - rr) * qq) + idx;
    int m0 = (wgid / gridDim.x) * 128, n0 = (wgid % gridDim.x) * 128;

    int lane = tid & 63, wid = tid >> 6;
    int wm = wid >> 1, wn = wid & 1;
    int lr = lane & 15, lk = lane >> 4;

    size_t abase[2], bbase[2];
#pragma unroll
    for (int r = 0; r < 2; ++r) {
        int u = r * 256 + tid;
        int row = ((u >> 3) << 1) | ((u >> 2) & 1);
        int kg  = (u & 3) ^ ((u >> 3) & 3);
        int rm = m0 + row, ga;
        if (alvl >= 0) { int j = rm >> 5; if (j > cnt - 1) j = cnt - 1; ga = (rm & 31) * S + d_sets.idx[alvl][j]; }
        else ga = rm;
        abase[r] = (size_t)ga * Kd + kg * 8;
        bbase[r] = (size_t)(n0 + row) * Kd + kg * 8;
    }
    auto stage = [&](int buf, int k0) {
#pragma unroll
        for (int r = 0; r < 2; ++r) {
            short* la = As[buf] + (size_t)(r * 256 + wid * 64) * 8;
            short* lb = Bs[buf] + (size_t)(r * 256 + wid * 64) * 8;
            gload_lds16(A + abase[r] + k0, la);
            gload_lds16(Bt + bbase[r] + k0, lb);
        }
    };
    auto rd_off = [&](int row_) {
        int rh = row_ >> 1;
        int s  = lk ^ (rh & 3);
        return (size_t)(rh * 8 + (row_ & 1) * 4 + s) * 8;
    };

    float4v acc[4][4];
#pragma unroll
    for (int i = 0; i < 4; ++i)
#pragma unroll
        for (int j = 0; j < 4; ++j) acc[i][j] = 0;

    const int nt = Kd >> 5;
    stage(0, 0);
    for (int t = 0; t < nt; ++t) {
        int cur = t & 1;
        if (t + 1 < nt) {
            stage(cur ^ 1, (t + 1) * 32);
            asm volatile("s_waitcnt vmcnt(4)" ::: "memory");
        } else {
            asm volatile("s_waitcnt vmcnt(0)" ::: "memory");
        }
        __builtin_amdgcn_s_barrier();
        short8 af[4], bfv[4];
#pragma unroll
        for (int mi = 0; mi < 4; ++mi)
            af[mi] = *(const short8*)(As[cur] + rd_off(wm * 64 + mi * 16 + lr));
#pragma unroll
        for (int ni = 0; ni < 4; ++ni)
            bfv[ni] = *(const short8*)(Bs[cur] + rd_off(wn * 64 + ni * 16 + lr));
        __builtin_amdgcn_s_setprio(1);
#pragma unroll
        for (int mi = 0; mi < 4; ++mi)
#pragma unroll
            for (int ni = 0; ni < 4; ++ni)
                acc[mi][ni] = __builtin_amdgcn_mfma_f32_16x16x32_bf16(
                    af[mi], bfv[ni], acc[mi][ni], 0, 0, 0);
        __builtin_amdgcn_s_setprio(0);
        __builtin_amdgcn_s_barrier();
    }

#pragma unroll
    for (int mi = 0; mi < 4; ++mi) {
        int gmc = m0 + wm * 64 + mi * 16 + lk * 4;
#pragma unroll
        for (int ni = 0; ni < 4; ++ni) {
            int gn = n0 + wn * 64 + ni * 16 + lr;
            float bsv = (EPI == 1 || EPI == 3 || EPI == 4) ? bias[gn] : 0.0f;
            float sc = (EPI == 5) ? bias[gn]  : 0.0f;
            float sh = (EPI == 5) ? bias2[gn] : 0.0f;
#pragma unroll
            for (int e = 0; e < 4; ++e) {
                int rm = gmc + e, grow;
                if (clvl >= 0) { int j = rm >> 5; if (j > cnt - 1) j = cnt - 1; grow = (rm & 31) * S + d_sets.idx[clvl][j]; }
                else grow = rm;
                float v = acc[mi][ni][e] + bsv;
                if (EPI == 3) v = 0.5f * v * (1.0f + erff(v * 0.70710678118654752f));
                if (EPI == 5) { v = v * sc + sh; v = v > 0.0f ? v : (expf(v) - 1.0f); }
                if (EPI == 6) {
                    v += peT[(size_t)(grow % L) * D + gn];
                    Cout2[(size_t)grow * Nd + gn] = f2bf(v);
                } else if (EPI <= 1) {
                    ((float*)Cout)[(size_t)grow * Nd + gn] = v;
                } else {
                    ((short*)Cout)[(size_t)grow * Nd + gn] = f2bf(v);
                }
            }
        }
    }
}

// ---------------------------------------------------------------------------
// up-projection GEMM with INLINE concat gather (r21)
// ---------------------------------------------------------------------------
__launch_bounds__(256, 4)
__global__ void mfma_gemm_up(const short* __restrict__ cs1, const short* __restrict__ cs2,
                             const short* __restrict__ cs3, const short* __restrict__ Bt,
                             const float* __restrict__ bias, float* __restrict__ Cout) {
    __shared__ short As[2][128 * 32];
    __shared__ short Bs[2][128 * 32];
    int tid = threadIdx.x;
    int nwg  = gridDim.x * gridDim.y;
    int orig = blockIdx.y * gridDim.x + blockIdx.x;
    int qq = nwg >> 3, rr = nwg & 7;
    int xcd = orig & 7, idx = orig >> 3;
    int wgid = (xcd < rr ? xcd * (qq + 1) : rr * (qq + 1) + (xcd - rr) * qq) + idx;
    int m0 = (wgid / gridDim.x) * 128, n0 = (wgid % gridDim.x) * 128;
    const int Kd = DBOT, Nd = D;

    int lane = tid & 63, wid = tid >> 6;
    int wm = wid >> 1, wn = wid & 1;
    int lr = lane & 15, lk = lane >> 4;

    const short* aad[2];
    size_t bbase[2];
#pragma unroll
    for (int r = 0; r < 2; ++r) {
        int u = r * 256 + tid;
        int row = ((u >> 3) << 1) | ((u >> 2) & 1);
        int kg  = (u & 3) ^ ((u >> 3) & 3);
        int rm = m0 + row;
        const short* base;
        if (rm < BB * LC) {
            int b = rm / LC, t = rm % LC;
            if (t < L1)           base = cs1 + (size_t)(b * L1 + t) * DBOT;
            else if (t < L1 + L2) base = cs2 + (size_t)(b * L2 + (t - L1)) * DBOT;
            else                  base = cs3 + (size_t)(b * L3 + (t - L1 - L2)) * DBOT;
        } else {
            base = cs1;   // pad row: garbage computed, never read
        }
        aad[r] = base + kg * 8;
        bbase[r] = (size_t)(n0 + row) * Kd + kg * 8;
    }
    auto stage = [&](int buf, int k0) {
#pragma unroll
        for (int r = 0; r < 2; ++r) {
            short* la = As[buf] + (size_t)(r * 256 + wid * 64) * 8;
            short* lb = Bs[buf] + (size_t)(r * 256 + wid * 64) * 8;
            gload_lds16(aad[r] + k0, la);
            gload_lds16(Bt + bbase[r] + k0, lb);
        }
    };
    auto rd_off = [&](int row_) {
        int rh = row_ >> 1;
        int s  = lk ^ (rh & 3);
        return (size_t)(rh * 8 + (row_ & 1) * 4 + s) * 8;
    };

    float4v acc[4][4];
#pragma unroll
    for (int i = 0; i < 4; ++i)
#pragma unroll
        for (int j = 0; j < 4; ++j) acc[i][j] = 0;

    const int nt = Kd >> 5;   // 4
    stage(0, 0);
    for (int t = 0; t < nt; ++t) {
        int cur = t & 1;
        if (t + 1 < nt) {
            stage(cur ^ 1, (t + 1) * 32);
            asm volatile("s_waitcnt vmcnt(4)" ::: "memory");
        } else {
            asm volatile("s_waitcnt vmcnt(0)" ::: "memory");
        }
        __builtin_amdgcn_s_barrier();
        short8 af[4], bfv[4];
#pragma unroll
        for (int mi = 0; mi < 4; ++mi)
            af[mi] = *(const short8*)(As[cur] + rd_off(wm * 64 + mi * 16 + lr));
#pragma unroll
        for (int ni = 0; ni < 4; ++ni)
            bfv[ni] = *(const short8*)(Bs[cur] + rd_off(wn * 64 + ni * 16 + lr));
        __builtin_amdgcn_s_setprio(1);
#pragma unroll
        for (int mi = 0; mi < 4; ++mi)
#pragma unroll
            for (int ni = 0; ni < 4; ++ni)
                acc[mi][ni] = __builtin_amdgcn_mfma_f32_16x16x32_bf16(
                    af[mi], bfv[ni], acc[mi][ni], 0, 0, 0);
        __builtin_amdgcn_s_setprio(0);
        __builtin_amdgcn_s_barrier();
    }

#pragma unroll
    for (int mi = 0; mi < 4; ++mi) {
        int gmc = m0 + wm * 64 + mi * 16 + lk * 4;
#pragma unroll
        for (int ni = 0; ni < 4; ++ni) {
            int gn = n0 + wn * 64 + ni * 16 + lr;
            float bsv = bias[gn];
#pragma unroll
            for (int e = 0; e < 4; ++e)
                Cout[(size_t)(gmc + e) * Nd + gn] = acc[mi][ni][e] + bsv;
        }
    }
}

// ---------------------------------------------------------------------------
// SPLIT-K variant: gridDim.z = KS slices; writes f32 partial part[kz][Mpad][Nd].
// ---------------------------------------------------------------------------
__launch_bounds__(256, 4)
__global__ void mfma_gemm_sk(const short* __restrict__ A, const short* __restrict__ Bt,
                             float* __restrict__ part, int Kd, int Nd,
                             int alvl, int cnt) {
    __shared__ short As[2][128 * 32];
    __shared__ short Bs[2][128 * 32];
    int tid = threadIdx.x;
    int nwg  = gridDim.x * gridDim.y;
    int orig = blockIdx.y * gridDim.x + blockIdx.x;
    int qq = nwg >> 3, rr = nwg & 7;
    int xcd = orig & 7, idx = orig >> 3;
    int wgid = (xcd < rr ? xcd * (qq + 1) : rr * (qq + 1) + (xcd - rr) * qq) + idx;
    int m0 = (wgid / gridDim.x) * 128, n0 = (wgid % gridDim.x) * 128;
    int Mpad = gridDim.y * 128;
    int kz = blockIdx.z;
    int kb = Kd / gridDim.z;          // slice length (multiple of 32)
    int kbase = kz * kb;

    int lane = tid & 63, wid = tid >> 6;
    int wm = wid >> 1, wn = wid & 1;
    int lr = lane & 15, lk = lane >> 4;

    size_t abase[2], bbase[2];
#pragma unroll
    for (int r = 0; r < 2; ++r) {
        int u = r * 256 + tid;
        int row = ((u >> 3) << 1) | ((u >> 2) & 1);
        int kg  = (u & 3) ^ ((u >> 3) & 3);
        int rm = m0 + row, ga;
        if (alvl >= 0) { int j = rm >> 5; if (j > cnt - 1) j = cnt - 1; ga = (rm & 31) * S + d_sets.idx[alvl][j]; }
        else ga = rm;
        abase[r] = (size_t)ga * Kd + kbase + kg * 8;
        bbase[r] = (size_t)(n0 + row) * Kd + kbase + kg * 8;
    }
    auto stage = [&](int buf, int k0) {
#pragma unroll
        for (int r = 0; r < 2; ++r) {
            short* la = As[buf] + (size_t)(r * 256 + wid * 64) * 8;
            short* lb = Bs[buf] + (size_t)(r * 256 + wid * 64) * 8;
            gload_lds16(A + abase[r] + k0, la);
            gload_lds16(Bt + bbase[r] + k0, lb);
        }
    };
    auto rd_off = [&](int row_) {
        int rh = row_ >> 1;
        int s  = lk ^ (rh & 3);
        return (size_t)(rh * 8 + (row_ & 1) * 4 + s) * 8;
    };

    float4v acc[4][4];
#pragma unroll
    for (int i = 0; i < 4; ++i)
#pragma unroll
        for (int j = 0; j < 4; ++j) acc[i][j] = 0;

    const int nt = kb >> 5;
    stage(0, 0);
    for (int t = 0; t < nt; ++t) {
        int cur = t & 1;
        if (t + 1 < nt) {
            stage(cur ^ 1, (t + 1) * 32);
            asm volatile("s_waitcnt vmcnt(4)" ::: "memory");
        } else {
            asm volatile("s_waitcnt vmcnt(0)" ::: "memory");
        }
        __builtin_amdgcn_s_barrier();
        short8 af[4], bfv[4];
#pragma unroll
        for (int mi = 0; mi < 4; ++mi)
            af[mi] = *(const short8*)(As[cur] + rd_off(wm * 64 + mi * 16 + lr));
#pragma unroll
        for (int ni = 0; ni < 4; ++ni)
            bfv[ni] = *(const short8*)(Bs[cur] + rd_off(wn * 64 + ni * 16 + lr));
        __builtin_amdgcn_s_setprio(1);
#pragma unroll
        for (int mi = 0; mi < 4; ++mi)
#pragma unroll
            for (int ni = 0; ni < 4; ++ni)
                acc[mi][ni] = __builtin_amdgcn_mfma_f32_16x16x32_bf16(
                    af[mi], bfv[ni], acc[mi][ni], 0, 0, 0);
        __builtin_amdgcn_s_setprio(0);
        __builtin_amdgcn_s_barrier();
    }

#pragma unroll
    for (int mi = 0; mi < 4; ++mi) {
        int gmc = m0 + wm * 64 + mi * 16 + lk * 4;
#pragma unroll
        for (int ni = 0; ni < 4; ++ni) {
            int gn = n0 + wn * 64 + ni * 16 + lr;
#pragma unroll
            for (int e = 0; e < 4; ++e)
                part[((size_t)kz * Mpad + gmc + e) * Nd + gn] = acc[mi][ni][e];
        }
    }
}

// sum KS partials + epilogue -> bf16 compact output
// EPI: 3 +bias+gelu; 4 +bias; 5 *bias+bias2 then ELU (conv BN fold)
template<int EPI>
__launch_bounds__(256)
__global__ void reduce_sk(const float* __restrict__ part, const float* __restrict__ bias,
                          const float* __restrict__ bias2, short* __restrict__ Cout,
                          int Mpad, int Nd, int KS) {
    int idx = blockIdx.x * 256 + threadIdx.x;
    if (idx >= Mpad * Nd) return;
    float s = 0.0f;
    for (int k = 0; k < KS; ++k)
        s += part[(size_t)k * Mpad * Nd + idx];
    int n = idx % Nd;
    if (EPI == 3 || EPI == 4) s += bias[n];
    if (EPI == 3) s = 0.5f * s * (1.0f + erff(s * 0.70710678118654752f));
    if (EPI == 5) { s = s * bias[n] + bias2[n]; s = s > 0.0f ? s : (expf(s) - 1.0f); }
    Cout[idx] = f2bf(s);
}

// ---------------------------------------------------------------------------
// weight transpose tile helper
// ---------------------------------------------------------------------------
__device__ inline void wtrans_tile(const float* __restrict__ W, short* __restrict__ Wt,
                                   int Kd, int Nd, int n0, int k0, int tid) {
    __shared__ float tile[32][33];
    int tx = tid & 31, ty = tid >> 5; // ty 0..7
#pragma unroll
    for (int r = 0; r < 32; r += 8)
        tile[ty + r][tx] = W[(size_t)(k0 + ty + r) * Nd + n0 + tx];
    __syncthreads();
#pragma unroll
    for (int r = 0; r < 32; r += 8)
        Wt[(size_t)(n0 + ty + r) * Kd + k0 + tx] = f2bf(tile[tx][ty + r]);
}

// ---------------------------------------------------------------------------
// ONE fused prep kernel: all weight transposes + small prep + pe/wE/xim.
// ---------------------------------------------------------------------------
constexpr int PE_N  = L * D;           // 172032
constexpr int WE_N  = D * 32;          // 16384
constexpr int XIM_N = BB * L * 32;     // 344064
constexpr int MISC_N = PE_N + WE_N + XIM_N;
constexpr int PREP_BLKS = 3072 + 6144 + 640 + (MISC_N + 255) / 256;

__launch_bounds__(256)
__global__ void prep_all(const float* __restrict__ wq, const float* __restrict__ wk,
                         const float* __restrict__ wv, const float* __restrict__ wo,
                         short* __restrict__ wqkvT, short* __restrict__ woT,
                         const float* __restrict__ w1, const float* __restrict__ w2,
                         short* __restrict__ w1T, short* __restrict__ w2T,
                         const float* __restrict__ down_w, short* __restrict__ downT,
                         const float* __restrict__ up_w, short* __restrict__ upT,
                         const float* __restrict__ cw, const float* __restrict__ cb,
                         const float* __restrict__ bg, const float* __restrict__ bb,
                         short* __restrict__ cscmT, float* __restrict__ sc,
                         float* __restrict__ sh,
                         const float* __restrict__ x_enc, const float* __restrict__ x_mark,
                         const float* __restrict__ cew, const float* __restrict__ tw,
                         const float* __restrict__ tb, float* __restrict__ pe,
                         short* __restrict__ wE, short* __restrict__ xim) {
    int blk = blockIdx.x;
    int tid = threadIdx.x;
    if (blk < 3072) {
        int z = blk >> 8, rem = blk & 255;
        int l = z >> 2, part = z & 3;
        const float* src = (part == 0 ? wq : part == 1 ? wk : part == 2 ? wv : wo)
                           + (size_t)l * D * D;
        short* dst = (part < 3) ? wqkvT + (size_t)l * 3 * D * D + (size_t)part * D * D
                                : woT + (size_t)l * D * D;
        wtrans_tile(src, dst, D, D, (rem & 15) * 32, (rem >> 4) * 32, tid);
        return;
    }
    blk -= 3072;
    if (blk < 6144) {
        int z = blk >> 10, rem = blk & 1023;
        int l = z >> 1, part = z & 1;
        int bx = rem & 63, by = rem >> 6;
        int nt = part ? by : bx;
        int kt = part ? bx : by;
        if (part == 0)
            wtrans_tile(w1 + (size_t)l * D * DFF, w1T + (size_t)l * DFF * D,
                        D, DFF, nt * 32, kt * 32, tid);
        else
            wtrans_tile(w2 + (size_t)l * DFF * D, w2T + (size_t)l * D * DFF,
                        DFF, D, nt * 32, kt * 32, tid);
        return;
    }
    blk -= 6144;
    if (blk < 640) {
        if (blk < 64) {
            wtrans_tile(down_w, downT, D, DBOT, (blk & 3) * 32, (blk >> 2) * 32, tid);
        } else if (blk < 128) {
            int b2 = blk - 64;
            wtrans_tile(up_w, upT, DBOT, D, (b2 & 15) * 32, (b2 >> 4) * 32, tid);
        } else {
            int idx = (blk - 128) * 256 + tid;
            if (idx < 2 * DBOT * 512) {
                int l = idx >> 16;
                int rem = idx & 65535;
                int oc = rem >> 9, j = rem & 511;
                int r = j >> 7, c = j & 127;
                cscmT[idx] = f2bf(cw[(((size_t)l * DBOT + oc) * DBOT + c) * 4 + r]);
            }
            if (idx < 3 * DBOT) {
                sc[idx] = bg[idx];
                sh[idx] = cb[idx] * bg[idx] + bb[idx];
            }
        }
        return;
    }
    blk -= 640;
    {
        int idx = blk * 256 + tid;
        if (idx < PE_N) {
            int d = idx % D, t = idx / D;
            int e = d & ~1;
            float div = expf(-(float)e * (logf(10000.0f) / (float)D));
            float arg = (float)t * div;
            pe[idx] = (d & 1) ? cosf(arg) : sinf(arg);
            return;
        }
        int i2 = idx - PE_N;
        if (i2 < WE_N) {
            int k = i2 & 31, d = i2 >> 5;
            float v = 0.0f;
            if (k < 21) {
                int w = k / 7, i = k % 7;
                v = cew[(size_t)d * (CIN * 3) + i * 3 + w];
            } else if (k < 25) {
                v = tw[(size_t)(k - 21) * D + d];
            } else if (k == 25) {
                v = tb[d];
            }
            wE[i2] = f2bf(v);
            return;
        }
        int i3 = i2 - WE_N;
        if (i3 < XIM_N) {
            int k = i3 & 31, m = i3 >> 5;
            int t = m % L, b = m / L;
            float v = 0.0f;
            if (k < 21) {
                int w = k / 7, i = k % 7;
                int s = t + w - 1;
                if (s < 0) s = L - 1;
                if (s >= L) s = 0;
                v = x_enc[((size_t)b * L + s) * CIN + i];
            } else if (k < 25) {
                v = x_mark[(size_t)m * MARK + (k - 21)];
            } else if (k == 25) {
                v = 1.0f;
            }
            xim[i3] = f2bf(v);
        }
    }
}

// ---------------------------------------------------------------------------
// CSCM conv level 3 (tiny)
// ---------------------------------------------------------------------------
__launch_bounds__(128)
__global__ void cscm_conv_bf16(const short* __restrict__ in, int inRowsPerB,
                               short* __restrict__ outp, const float* __restrict__ w,
                               const float* __restrict__ cb, const float* __restrict__ bng,
                               const float* __restrict__ bnb, int Lout) {
    int bid = blockIdx.x;
    int to = bid % Lout, b = bid / Lout;
    __shared__ float insh[4 * DBOT];
    int tid = threadIdx.x;
#pragma unroll
    for (int r = 0; r < 4; ++r)
        insh[r * DBOT + tid] = bf2f(in[((size_t)(b * inRowsPerB + to * 4 + r)) * DBOT + tid]);
    __syncthreads();
    float acc = cb[tid];
    const float* wr = w + (size_t)tid * (DBOT * 4);
    for (int c = 0; c < DBOT; ++c) {
#pragma unroll
        for (int r = 0; r < 4; ++r)
            acc += insh[r * DBOT + c] * wr[c * 4 + r];
    }
    acc = acc * bng[tid] + bnb[tid];
    outp[((size_t)(b * Lout + to)) * DBOT + tid] = f2bf(acc > 0.0f ? acc : (expf(acc) - 1.0f));
}

// ---------------------------------------------------------------------------
// sparse attention over active level (compact Ob)
// ---------------------------------------------------------------------------
__launch_bounds__(256)
__global__ void attn_sparse_kernel(const short* __restrict__ QKV, short* __restrict__ Ob,
                                   int lvl, int cnt) {
    int wid  = blockIdx.x * 4 + (threadIdx.x >> 6);
    if (wid >= cnt * 32) return;
    int lane = threadIdx.x & 63;
    int b = wid & 31, j = wid >> 5;
    int i = d_sets.idx[lvl][j];
    const short8 qv = *(const short8*)(QKV + (size_t)(b * S + i) * 1536 + lane * 8);
    float qf[8];
#pragma unroll
    for (int e = 0; e < 8; ++e) qf[e] = bf2f(qv[e]);
    int nb[NMAX];
#pragma unroll
    for (int jj = 0; jj < NMAX; ++jj) nb[jj] = d_sets.nbr[i][jj];
    float sc[NMAX];
#pragma unroll
    for (int jj = 0; jj < NMAX; ++jj) {
        float s = -1e30f;
        if (nb[jj] >= 0) {
            const short8 kv = *(const short8*)(QKV + (size_t)(b * S + nb[jj]) * 1536 + 512 + lane * 8);
            s = 0.0f;
#pragma unroll
            for (int e = 0; e < 8; ++e) s += qf[e] * bf2f(kv[e]);
            s += __shfl_xor(s, 1); s += __shfl_xor(s, 2); s += __shfl_xor(s, 4);
            s *= 0.125f;
        }
        sc[jj] = s;
    }
    float mx = sc[0];
#pragma unroll
    for (int jj = 1; jj < NMAX; ++jj) mx = fmaxf(mx, sc[jj]);
    float sum = 0.0f;
    float accv[8] = {};
#pragma unroll
    for (int jj = 0; jj < NMAX; ++jj) {
        float p = expf(sc[jj] - mx);
        sum += p;
        if (nb[jj] >= 0) {
            const short8 vv = *(const short8*)(QKV + (size_t)(b * S + nb[jj]) * 1536 + 1024 + lane * 8);
#pragma unroll
            for (int e = 0; e < 8; ++e) accv[e] += p * bf2f(vv[e]);
        }
    }
    float inv = 1.0f / sum;
    short8 ov;
#pragma unroll
    for (int e = 0; e < 8; ++e) ov[e] = f2bf(accv[e] * inv);
    *(short8*)(Ob + (size_t)wid * D + lane * 8) = ov;
}

// ---------------------------------------------------------------------------
// wave-shuffle block reduction over 4 waves (256 thr)
// ---------------------------------------------------------------------------
__device__ inline float blk_reduce(float v, float* ws4, int tid) {
#pragma unroll
    for (int o = 32; o; o >>= 1) v += __shfl_xor(v, o);
    if ((tid & 63) == 0) ws4[tid >> 6] = v;
    __syncthreads();
    return ws4[0] + ws4[1] + ws4[2] + ws4[3];
}

// ---------------------------------------------------------------------------
// concat(emb_bf, coarse) + LayerNorm at A_0 rows only
// ---------------------------------------------------------------------------
__launch_bounds__(256)
__global__ void concat_ln_idx(const short* __restrict__ emb_bf, const float* __restrict__ coarse,
                              const float* __restrict__ g, const float* __restrict__ bta,
                              float* __restrict__ seq, short* __restrict__ seq_bf) {
    int row = blockIdx.x;
    int b = row & 31, j = row >> 5;
    int s = d_sets.idx[0][j];
    int orig = b * S + s;
    __shared__ float wsA[4];
    __shared__ float wsB[4];
    int tid = threadIdx.x;
    float x0, x1;
    if (s < L) {
        const short* src = emb_bf + ((size_t)b * L + s) * D;
        x0 = bf2f(src[tid]); x1 = bf2f(src[tid + 256]);
    } else {
        const float* src = coarse + ((size_t)b * LC + (s - L)) * D;
        x0 = src[tid]; x1 = src[tid + 256];
    }
    float mu = blk_reduce(x0 + x1, wsA, tid) * (1.0f / D);
    float d0 = x0 - mu, d1 = x1 - mu;
    float var = blk_reduce(d0 * d0 + d1 * d1, wsB, tid) * (1.0f / D);
    float rstd = rsqrtf(var + 1e-5f);
    float v0 = d0 * rstd * g[tid]       + bta[tid];
    float v1 = d1 * rstd * g[tid + 256] + bta[tid + 256];
    float* dst = seq + (size_t)orig * D;
    dst[tid] = v0; dst[tid + 256] = v1;
    short* dbf = seq_bf + (size_t)orig * D;
    dbf[tid] = f2bf(v0); dbf[tid + 256] = f2bf(v1);
}

// ---------------------------------------------------------------------------
// fused split-K reduce + residual LN
// ---------------------------------------------------------------------------
__launch_bounds__(256)
__global__ void add_ln_sk(float* __restrict__ seq, const float* __restrict__ part,
                          const float* __restrict__ bias, const float* __restrict__ g,
                          const float* __restrict__ bta, short* __restrict__ seq_bf,
                          int lvl, int Mpad, int KS) {
    int row = blockIdx.x;
    int b = row & 31, j = row >> 5;
    int orig = b * S + d_sets.idx[lvl][j];
    __shared__ float wsA[4];
    __shared__ float wsB[4];
    int tid = threadIdx.x;
    float a0 = 0.0f, a1 = 0.0f;
    for (int k = 0; k < KS; ++k) {
        const float* pr = part + ((size_t)k * Mpad + row) * D;
        a0 += pr[tid];
        a1 += pr[tid + 256];
    }
    if (bias) { a0 += bias[tid]; a1 += bias[tid + 256]; }
    float* srow = seq + (size_t)orig * D;
    float x0 = srow[tid] + a0;
    float x1 = srow[tid + 256] + a1;
    float mu = blk_reduce(x0 + x1, wsA, tid) * (1.0f / D);
    float d0 = x0 - mu, d1 = x1 - mu;
    float var = blk_reduce(d0 * d0 + d1 * d1, wsB, tid) * (1.0f / D);
    float rstd = rsqrtf(var + 1e-5f);
    float v0 = d0 * rstd * g[tid]       + bta[tid];
    float v1 = d1 * rstd * g[tid + 256] + bta[tid + 256];
    srow[tid] = v0; srow[tid + 256] = v1;
    short* dbf = seq_bf + (size_t)orig * D;
    dbf[tid] = f2bf(v0); dbf[tid + 256] = f2bf(v1);
}

// ---------------------------------------------------------------------------
// prediction head, split-K with fused gather (r22 form — r25 fusion regressed)
// ---------------------------------------------------------------------------
__launch_bounds__(256)
__global__ void pred_kernel(const float* __restrict__ seq, const float* __restrict__ w,
                            float* __restrict__ part) {
    __shared__ float es[32][257];
    __shared__ float wsm[256][8];
    int tid = threadIdx.x;
    int n0 = blockIdx.x * 8;
    int ks = blockIdx.y;
    int k0 = ks * 256;
    const int pos[4] = {335, 419, 440, 445};
    int seg = ks >> 1;
    int dbase = (ks & 1) * 256;
#pragma unroll 8
    for (int r = 0; r < 32; ++r)
        es[r][tid] = seq[((size_t)r * S + pos[seg]) * D + dbase + tid];
#pragma unroll
    for (int e = 0; e < 8; ++e)
        wsm[tid][e] = w[(size_t)(k0 + tid) * PRED_N + n0 + e];
    __syncthreads();
    int b = tid >> 3, nn = tid & 7;
    float acc = 0.0f;
#pragma unroll 8
    for (int kk = 0; kk < 256; ++kk)
        acc += es[b][kk] * wsm[kk][nn];
    part[(size_t)ks * (BB * PRED_N) + (size_t)b * PRED_N + n0 + nn] = acc;
}

__launch_bounds__(256)
__global__ void pred_reduce_kernel(const float* __restrict__ part, float* __restrict__ out) {
    int idx = blockIdx.x * 256 + threadIdx.x;
    if (idx >= BB * PRED_N) return;
    float s = 0.0f;
#pragma unroll
    for (int k = 0; k < 8; ++k) s += part[(size_t)k * (BB * PRED_N) + idx];
    out[idx] = s;
}

// ---------------------------------------------------------------------------
extern "C" void kernel_launch(void* const* d_in, const int* in_sizes, int n_in,
                              void* d_out, int out_size, void* d_ws, size_t ws_size,
                              hipStream_t stream) {
    const float* x_enc      = (const float*)d_in[0];
    const float* x_mark_enc = (const float*)d_in[1];
    const float* conv_embed_w = (const float*)d_in[4];
    const float* time_w  = (const float*)d_in[5];
    const float* time_b  = (const float*)d_in[6];
    const float* down_w  = (const float*)d_in[7];
    const float* down_b  = (const float*)d_in[8];
    const float* cscm_w  = (const float*)d_in[9];
    const float* cscm_b  = (const float*)d_in[10];
    const float* bn_g    = (const float*)d_in[11];
    const float* bn_b    = (const float*)d_in[12];
    const float* up_w    = (const float*)d_in[13];
    const float* up_b    = (const float*)d_in[14];
    const float* cln_g   = (const float*)d_in[15];
    const float* cln_b   = (const float*)d_in[16];
    const float* wq      = (const float*)d_in[17];
    const float* wk      = (const float*)d_in[18];
    const float* wv      = (const float*)d_in[19];
    const float* wo      = (const float*)d_in[20];
    const float* ln1_g   = (const float*)d_in[21];
    const float* ln1_b   = (const float*)d_in[22];
    const float* ffn_w1  = (const float*)d_in[23];
    const float* ffn_b1  = (const float*)d_in[24];
    const float* ffn_w2  = (const float*)d_in[25];
    const float* ffn_b2  = (const float*)d_in[26];
    const float* ln2_g   = (const float*)d_in[27];
    const float* ln2_b   = (const float*)d_in[28];
    const float* pred_w  = (const float*)d_in[29];
    float* out = (float*)d_out;

    // ---- workspace layout (bytes, 256-aligned) ----
    char* w8 = (char*)d_ws;
    size_t off = 0;
    auto alloc = [&](size_t bytes) {
        void* p = w8 + off;
        off = (off + bytes + 255) & ~(size_t)255;
        return p;
    };
    short* emb_bf = (short*)alloc((size_t)BB * L * D * 2);
    float* pe     = (float*)alloc((size_t)L * D * 4);
    short* xim    = (short*)alloc((size_t)BB * L * 32 * 2);
    short* wE     = (short*)alloc((size_t)D * 32 * 2);
    short* xd_bf  = (short*)alloc((size_t)BB * L * DBOT * 2);
    short* cs1_bf = (short*)alloc((size_t)MCONV2P * 512 * 2);
    short* cs2_bf = (short*)alloc((size_t)MCONV2P * DBOT * 2);
    short* cs3_bf = (short*)alloc((size_t)BB * L3 * DBOT * 2);
    float* coarse = (float*)alloc((size_t)MCAT * D * 4);
    float* seq    = (float*)alloc((size_t)BB * S * D * 4);
    float* part   = (float*)alloc((size_t)8 * BB * PRED_N * 4);
    float* partsk = (float*)alloc(psk_elems() * 4);   // split-K partials (exact)
    short* seq_bf = (short*)alloc((size_t)MP * D * 2);
    short* QKV    = (short*)alloc((size_t)MP * 3 * D * 2);  // + Ob contiguous
    short* Ob     = (short*)alloc((size_t)MP * D * 2);
    short* hidden = QKV;
    short* wqkvT  = (short*)alloc((size_t)NLAYER * 3 * D * D * 2);
    short* woT    = (short*)alloc((size_t)NLAYER * D * D * 2);
    short* w1T    = (short*)alloc((size_t)NLAYER * DFF * D * 2);
    short* w2T    = (short*)alloc((size_t)NLAYER * D * DFF * 2);
    short* downT  = (short*)alloc((size_t)DBOT * D * 2);
    short* upT    = (short*)alloc((size_t)D * DBOT * 2);
    short* cscmT  = (short*)alloc((size_t)2 * DBOT * 512 * 2);
    float* csc_sc = (float*)alloc((size_t)3 * DBOT * 4);
    float* csc_sh = (float*)alloc((size_t)3 * DBOT * 4);
    (void)ws_size; (void)in_sizes; (void)n_in; (void)out_size;

    const int rowsL = BB * L;   // 10752 = 84*128
    dim3 blk(256);

    // 0. ONE fused prep kernel
    prep_all<<<dim3(PREP_BLKS), blk, 0, stream>>>(
        wq, wk, wv, wo, wqkvT, woT,
        ffn_w1, ffn_w2, w1T, w2T,
        down_w, downT, up_w, upT,
        cscm_w, cscm_b, bn_g, bn_b, cscmT, csc_sc, csc_sh,
        x_enc, x_mark_enc, conv_embed_w, time_w, time_b, pe, wE, xim);
    // 1. embedding as GEMM + pe epilogue, bf16 out
    mfma_gemm<6><<<dim3(D / 128, rowsL / 128), blk, 0, stream>>>(
        xim, wE, nullptr, nullptr, nullptr, 32, D, -1, -1, 0, pe, emb_bf);
    // 2. down projection -> bf16 (split-K)
    mfma_gemm_sk<<<dim3(1, rowsL / 128, 4), blk, 0, stream>>>(
        emb_bf, downT, partsk, D, DBOT, -1, 0);
    reduce_sk<4><<<dim3((rowsL * DBOT + 255) / 256), blk, 0, stream>>>(
        partsk, down_b, nullptr, xd_bf, rowsL, DBOT, 4);
    // 3. CSCM pyramid (conv1/conv2 split-K)
    mfma_gemm_sk<<<dim3(1, MCONV1 / 128, 4), blk, 0, stream>>>(
        xd_bf, cscmT, partsk, 512, DBOT, -1, 0);
    reduce_sk<5><<<dim3((MCONV1 * DBOT + 255) / 256), blk, 0, stream>>>(
        partsk, csc_sc, csc_sh, cs1_bf, MCONV1, DBOT, 4);
    mfma_gemm_sk<<<dim3(1, MCONV2P / 128, 4), blk, 0, stream>>>(
        cs1_bf, cscmT + (size_t)DBOT * 512, partsk, 512, DBOT, -1, 0);
    reduce_sk<5><<<dim3((MCONV2P * DBOT + 255) / 256), blk, 0, stream>>>(
        partsk, csc_sc + DBOT, csc_sh + DBOT, cs2_bf, MCONV2P, DBOT, 4);
    cscm_conv_bf16<<<dim3(BB * L3), dim3(DBOT), 0, stream>>>(
        cs2_bf, L2, cs3_bf, cscm_w + 2 * DBOT * DBOT * 4,
        cscm_b + 2 * DBOT, bn_g + 2 * DBOT, bn_b + 2 * DBOT, L3);
    // 4. up projection with inline concat gather
    mfma_gemm_up<<<dim3(D / 128, MCAT / 128), blk, 0, stream>>>(
        cs1_bf, cs2_bf, cs3_bf, upT, up_b, coarse);
    // 5. concat + LN (A_0 rows only)
    concat_ln_idx<<<dim3(HS.cnt[0] * 32), blk, 0, stream>>>(
        emb_bf, coarse, cln_g, cln_b, seq, seq_bf);

    // 6. encoder layers (sparse active sets; split-K everywhere it pays)
    for (int l = 0; l < NLAYER; ++l) {
        const int inLvl = l, outLvl = l + 1;
        const int inCnt  = HS.cnt[l];
        const int outCnt = HS.cnt[l + 1];
        const int Mc   = outCnt * 32;
        const int Mpad = ((Mc + 127) / 128) * 128;
        mfma_gemm<2><<<dim3(3 * D / 128, (inCnt * 32 + 127) / 128), blk, 0, stream>>>(
            seq_bf, wqkvT + (size_t)l * 3 * D * D, nullptr, nullptr, QKV, D, 3 * D,
            inLvl, inLvl, inCnt, nullptr, nullptr);
        attn_sparse_kernel<<<dim3(outCnt * 8), blk, 0, stream>>>(
            QKV, Ob, outLvl, outCnt);
        // O-projection + LN1: ALWAYS split-K + fused reduce/LN
        // (r26: KS=8 for small Mc -> 2 K-steps/block, more parallelism)
        {
            int KSW = (Mc <= 512) ? 8 : 4;
            mfma_gemm_sk<<<dim3(D / 128, Mpad / 128, KSW), blk, 0, stream>>>(
                Ob, woT + (size_t)l * D * D, partsk, D, D, -1, 0);
            add_ln_sk<<<dim3(Mc), blk, 0, stream>>>(
                seq, partsk, nullptr, ln1_g + (size_t)l * D, ln1_b + (size_t)l * D,
                seq_bf, outLvl, Mpad, KSW);
        }
        // FFN1: split-K for Mc<=512 (covers l1, l2)
        if (Mc <= 512) {
            mfma_gemm_sk<<<dim3(DFF / 128, Mpad / 128, 4), blk, 0, stream>>>(
                seq_bf, w1T + (size_t)l * DFF * D, partsk, D, DFF, outLvl, outCnt);
            reduce_sk<3><<<dim3((Mpad * DFF + 255) / 256), blk, 0, stream>>>(
                partsk, ffn_b1 + (size_t)l * DFF, nullptr, hidden, Mpad, DFF, 4);
        } else {
            mfma_gemm<3><<<dim3(DFF / 128, Mpad / 128), blk, 0, stream>>>(
                seq_bf, w1T + (size_t)l * DFF * D, ffn_b1 + (size_t)l * DFF, nullptr,
                hidden, D, DFF, outLvl, -1, outCnt, nullptr, nullptr);
        }
        // FFN2 + LN2: split-K, reduce fused into LN
        {
            int KS = (Mc <= 512) ? 8 : 4;
            mfma_gemm_sk<<<dim3(D / 128, Mpad / 128, KS), blk, 0, stream>>>(
                hidden, w2T + (size_t)l * D * DFF, partsk, DFF, D, -1, 0);
            add_ln_sk<<<dim3(Mc), blk, 0, stream>>>(
                seq, partsk, ffn_b2 + (size_t)l * D, ln2_g + (size_t)l * D,
                ln2_b + (size_t)l * D, seq_bf, outLvl, Mpad, KS);
        }
    }

    // 7. prediction head (split-K, gather fused) + reduce
    pred_kernel<<<dim3(PRED_N / 8, 8), blk, 0, stream>>>(seq, pred_w, part);
    pred_reduce_kernel<<<dim3((BB * PRED_N + 255) / 256), blk, 0, stream>>>(part, out);
}

// Round 27
// 328.309 us; speedup vs baseline: 3.6326x; 1.0076x over previous
//
#include <hip/hip_runtime.h>
#include <math.h>

// ---- problem constants ----
constexpr int BB   = 32;    // batch
constexpr int L    = 336;   // seq_len
constexpr int CIN  = 7;
constexpr int MARK = 4;
constexpr int D    = 512;   // d_model
constexpr int DFF  = 2048;
constexpr int S    = 446;   // 336+84+21+5
constexpr int DBOT = 128;
constexpr int L1 = 84, L2 = 21, L3 = 5;
constexpr int LC = 110;     // 84+21+5
constexpr int NLAYER = 3;
constexpr int PRED_N = 672; // 96*7
constexpr int MP   = 14336; // BB*S padded
constexpr int NMAX = 12;    // max sparse neighbors (real max 10)
constexpr int MCONV1 = BB * L1;          // 2688 = 21*128 (exact)
constexpr int MCONV2P = 768;             // BB*L2=672 padded to 6*128
constexpr int MCAT  = 3584;              // BB*LC=3520 padded to 28*128

using short8  = __attribute__((ext_vector_type(8))) short;
using float4v = __attribute__((ext_vector_type(4))) float;

// ---------------------------------------------------------------------------
// COMPILE-TIME pyramid structure: neighbor lists + active sets.
// ---------------------------------------------------------------------------
struct SetsData {
    int nbr[S][NMAX];
    int idx[4][S];
    int cnt[4];
};

constexpr SetsData compute_sets() {
    SetsData sd{};
    constexpr int sizes[4]  = {336, 84, 21, 5};
    constexpr int starts[4] = {0, 336, 420, 441};
    for (int i = 0; i < S; ++i) {
        int li = 0, pi = i;
        if (i < 336)      { li = 0; pi = i; }
        else if (i < 420) { li = 1; pi = i - 336; }
        else if (i < 441) { li = 2; pi = i - 420; }
        else              { li = 3; pi = i - 441; }
        int cnt = 0;
        for (int d = -2; d <= 2; ++d) {
            int q = pi + d;
            if (q >= 0 && q < sizes[li]) sd.nbr[i][cnt++] = starts[li] + q;
        }
        if (li > 0) {
            int lo = pi * 4;
            int hi = (pi == sizes[li] - 1) ? sizes[li - 1] : (pi + 1) * 4;
            for (int c = lo; c < hi; ++c) sd.nbr[i][cnt++] = starts[li - 1] + c;
        }
        if (li < 3) {
            int q = pi >> 2;
            if (q > sizes[li + 1] - 1) q = sizes[li + 1] - 1;
            sd.nbr[i][cnt++] = starts[li + 1] + q;
        }
        for (int j = cnt; j < NMAX; ++j) sd.nbr[i][j] = -1;
    }
    sd.cnt[3] = 4;
    sd.idx[3][0] = 335; sd.idx[3][1] = 419; sd.idx[3][2] = 440; sd.idx[3][3] = 445;
    for (int lvl = 3; lvl >= 1; --lvl) {
        bool mk[S] = {};
        for (int k = 0; k < sd.cnt[lvl]; ++k) {
            int i = sd.idx[lvl][k];
            for (int t = 0; t < NMAX; ++t) {
                int v = sd.nbr[i][t];
                if (v >= 0) mk[v] = true;
            }
        }
        int nc = 0;
        for (int i = 0; i < S; ++i)
            if (mk[i]) sd.idx[lvl - 1][nc++] = i;
        sd.cnt[lvl - 1] = nc;
    }
    return sd;
}

constexpr SetsData HS = compute_sets();         // host: grid sizing
__constant__ SetsData d_sets = compute_sets();  // device: row maps + nbr

// exact split-K partial buffer size (elements), from compile-time counts
// (r22 thresholds: wo always split-K KS=4; ffn1 split-K for Mc<=512)
constexpr size_t psk_elems() {
    size_t mx = 4 * (size_t)BB * L * DBOT;      // down-proj split-K (5.5M)
    {
        size_t v = 4 * (size_t)MCONV1 * DBOT; if (v > mx) mx = v;   // conv1
        v = 4 * (size_t)MCONV2P * DBOT;       if (v > mx) mx = v;   // conv2
    }
    for (int l = 0; l < NLAYER; ++l) {
        size_t Mc = (size_t)HS.cnt[l + 1] * 32;
        size_t Mpad = ((Mc + 127) / 128) * 128;
        { size_t v = 4 * Mpad * 512;  if (v > mx) mx = v; }                  // wo (always)
        if (Mc <= 512) { size_t v = 4 * Mpad * 2048; if (v > mx) mx = v; }   // ffn1
        size_t ks = (Mc <= 512) ? 8 : 4;
        size_t v = ks * Mpad * 512; if (v > mx) mx = v;                      // ffn2
    }
    return mx;
}

__device__ inline short f2bf(float f) {
    union { float f; unsigned u; } v; v.f = f;
    unsigned r = v.u + 0x7fffu + ((v.u >> 16) & 1u);
    return (short)(r >> 16);
}
__device__ inline float bf2f(short h) {
    union { unsigned u; float f; } v; v.u = ((unsigned)(unsigned short)h) << 16;
    return v.f;
}

// async global->LDS, 16B per lane, wave-uniform LDS base + lane*16
__device__ inline void gload_lds16(const void* g, void* l) {
    __builtin_amdgcn_global_load_lds(
        (const __attribute__((address_space(1))) void*)g,
        (__attribute__((address_space(3))) void*)l, 16, 0, 0);
}

// Staging map: conflict-free + coalesced (verified r11: 0 bank conflicts).
// Sparse rows: alvl/clvl >= 0 select d_sets.idx[lvl] (pos-major compact:
// compact m -> b=m&31, j=m>>5 clamped to cnt-1, orig row b*S+idx[j]).

// ---------------------------------------------------------------------------
// 128x128 bf16 MFMA GEMM, BK=32, double-buffered, counted vmcnt(4) pipeline.
// EPI: 0 f32; 1 f32+bias; 2 bf16; 3 bf16+bias+gelu; 4 bf16+bias;
//      5 bf16, v = acc*bias[gn]+bias2[gn] then ELU;
//      6 v = acc + peT[(row%L)*D+gn] -> bf16 Cout2 only (embed)
// ---------------------------------------------------------------------------
template<int EPI>
__launch_bounds__(256, 4)
__global__ void mfma_gemm(const short* __restrict__ A, const short* __restrict__ Bt,
                          const float* __restrict__ bias, const float* __restrict__ bias2,
                          void* __restrict__ Cout, int Kd, int Nd,
                          int alvl, int clvl, int cnt,
                          const float* __restrict__ peT, short* __restrict__ Cout2) {
    __shared__ short As[2][128 * 32];
    __shared__ short Bs[2][128 * 32];
    int tid = threadIdx.x;
    int nwg  = gridDim.x * gridDim.y;
    int orig = blockIdx.y * gridDim.x + blockIdx.x;
    int qq = nwg >> 3, rr = nwg & 7;
    int xcd = orig & 7, idx = orig >> 3;
    int wgid = (xcd < rr ? xcd * (qq + 1) : rr * (qq + 1) + (xcd - rr) * qq) + idx;
    int m0 = (wgid / gridDim.x) * 128, n0 = (wgid % gridDim.x) * 128;

    int lane = tid & 63, wid = tid >> 6;
    int wm = wid >> 1, wn = wid & 1;
    int lr = lane & 15, lk = lane >> 4;

    size_t abase[2], bbase[2];
#pragma unroll
    for (int r = 0; r < 2; ++r) {
        int u = r * 256 + tid;
        int row = ((u >> 3) << 1) | ((u >> 2) & 1);
        int kg  = (u & 3) ^ ((u >> 3) & 3);
        int rm = m0 + row, ga;
        if (alvl >= 0) { int j = rm >> 5; if (j > cnt - 1) j = cnt - 1; ga = (rm & 31) * S + d_sets.idx[alvl][j]; }
        else ga = rm;
        abase[r] = (size_t)ga * Kd + kg * 8;
        bbase[r] = (size_t)(n0 + row) * Kd + kg * 8;
    }
    auto stage = [&](int buf, int k0) {
#pragma unroll
        for (int r = 0; r < 2; ++r) {
            short* la = As[buf] + (size_t)(r * 256 + wid * 64) * 8;
            short* lb = Bs[buf] + (size_t)(r * 256 + wid * 64) * 8;
            gload_lds16(A + abase[r] + k0, la);
            gload_lds16(Bt + bbase[r] + k0, lb);
        }
    };
    auto rd_off = [&](int row_) {
        int rh = row_ >> 1;
        int s  = lk ^ (rh & 3);
        return (size_t)(rh * 8 + (row_ & 1) * 4 + s) * 8;
    };

    float4v acc[4][4];
#pragma unroll
    for (int i = 0; i < 4; ++i)
#pragma unroll
        for (int j = 0; j < 4; ++j) acc[i][j] = 0;

    const int nt = Kd >> 5;
    stage(0, 0);
    for (int t = 0; t < nt; ++t) {
        int cur = t & 1;
        if (t + 1 < nt) {
            stage(cur ^ 1, (t + 1) * 32);
            asm volatile("s_waitcnt vmcnt(4)" ::: "memory");
        } else {
            asm volatile("s_waitcnt vmcnt(0)" ::: "memory");
        }
        __builtin_amdgcn_s_barrier();
        short8 af[4], bfv[4];
#pragma unroll
        for (int mi = 0; mi < 4; ++mi)
            af[mi] = *(const short8*)(As[cur] + rd_off(wm * 64 + mi * 16 + lr));
#pragma unroll
        for (int ni = 0; ni < 4; ++ni)
            bfv[ni] = *(const short8*)(Bs[cur] + rd_off(wn * 64 + ni * 16 + lr));
        __builtin_amdgcn_s_setprio(1);
#pragma unroll
        for (int mi = 0; mi < 4; ++mi)
#pragma unroll
            for (int ni = 0; ni < 4; ++ni)
                acc[mi][ni] = __builtin_amdgcn_mfma_f32_16x16x32_bf16(
                    af[mi], bfv[ni], acc[mi][ni], 0, 0, 0);
        __builtin_amdgcn_s_setprio(0);
        __builtin_amdgcn_s_barrier();
    }

#pragma unroll
    for (int mi = 0; mi < 4; ++mi) {
        int gmc = m0 + wm * 64 + mi * 16 + lk * 4;
#pragma unroll
        for (int ni = 0; ni < 4; ++ni) {
            int gn = n0 + wn * 64 + ni * 16 + lr;
            float bsv = (EPI == 1 || EPI == 3 || EPI == 4) ? bias[gn] : 0.0f;
            float sc = (EPI == 5) ? bias[gn]  : 0.0f;
            float sh = (EPI == 5) ? bias2[gn] : 0.0f;
#pragma unroll
            for (int e = 0; e < 4; ++e) {
                int rm = gmc + e, grow;
                if (clvl >= 0) { int j = rm >> 5; if (j > cnt - 1) j = cnt - 1; grow = (rm & 31) * S + d_sets.idx[clvl][j]; }
                else grow = rm;
                float v = acc[mi][ni][e] + bsv;
                if (EPI == 3) v = 0.5f * v * (1.0f + erff(v * 0.70710678118654752f));
                if (EPI == 5) { v = v * sc + sh; v = v > 0.0f ? v : (expf(v) - 1.0f); }
                if (EPI == 6) {
                    v += peT[(size_t)(grow % L) * D + gn];
                    Cout2[(size_t)grow * Nd + gn] = f2bf(v);
                } else if (EPI <= 1) {
                    ((float*)Cout)[(size_t)grow * Nd + gn] = v;
                } else {
                    ((short*)Cout)[(size_t)grow * Nd + gn] = f2bf(v);
                }
            }
        }
    }
}

// ---------------------------------------------------------------------------
// up-projection GEMM with INLINE concat gather (r21)
// ---------------------------------------------------------------------------
__launch_bounds__(256, 4)
__global__ void mfma_gemm_up(const short* __restrict__ cs1, const short* __restrict__ cs2,
                             const short* __restrict__ cs3, const short* __restrict__ Bt,
                             const float* __restrict__ bias, float* __restrict__ Cout) {
    __shared__ short As[2][128 * 32];
    __shared__ short Bs[2][128 * 32];
    int tid = threadIdx.x;
    int nwg  = gridDim.x * gridDim.y;
    int orig = blockIdx.y * gridDim.x + blockIdx.x;
    int qq = nwg >> 3, rr = nwg & 7;
    int xcd = orig & 7, idx = orig >> 3;
    int wgid = (xcd < rr ? xcd * (qq + 1) : rr * (qq + 1) + (xcd - rr) * qq) + idx;
    int m0 = (wgid / gridDim.x) * 128, n0 = (wgid % gridDim.x) * 128;
    const int Kd = DBOT, Nd = D;

    int lane = tid & 63, wid = tid >> 6;
    int wm = wid >> 1, wn = wid & 1;
    int lr = lane & 15, lk = lane >> 4;

    const short* aad[2];
    size_t bbase[2];
#pragma unroll
    for (int r = 0; r < 2; ++r) {
        int u = r * 256 + tid;
        int row = ((u >> 3) << 1) | ((u >> 2) & 1);
        int kg  = (u & 3) ^ ((u >> 3) & 3);
        int rm = m0 + row;
        const short* base;
        if (rm < BB * LC) {
            int b = rm / LC, t = rm % LC;
            if (t < L1)           base = cs1 + (size_t)(b * L1 + t) * DBOT;
            else if (t < L1 + L2) base = cs2 + (size_t)(b * L2 + (t - L1)) * DBOT;
            else                  base = cs3 + (size_t)(b * L3 + (t - L1 - L2)) * DBOT;
        } else {
            base = cs1;   // pad row: garbage computed, never read
        }
        aad[r] = base + kg * 8;
        bbase[r] = (size_t)(n0 + row) * Kd + kg * 8;
    }
    auto stage = [&](int buf, int k0) {
#pragma unroll
        for (int r = 0; r < 2; ++r) {
            short* la = As[buf] + (size_t)(r * 256 + wid * 64) * 8;
            short* lb = Bs[buf] + (size_t)(r * 256 + wid * 64) * 8;
            gload_lds16(aad[r] + k0, la);
            gload_lds16(Bt + bbase[r] + k0, lb);
        }
    };
    auto rd_off = [&](int row_) {
        int rh = row_ >> 1;
        int s  = lk ^ (rh & 3);
        return (size_t)(rh * 8 + (row_ & 1) * 4 + s) * 8;
    };

    float4v acc[4][4];
#pragma unroll
    for (int i = 0; i < 4; ++i)
#pragma unroll
        for (int j = 0; j < 4; ++j) acc[i][j] = 0;

    const int nt = Kd >> 5;   // 4
    stage(0, 0);
    for (int t = 0; t < nt; ++t) {
        int cur = t & 1;
        if (t + 1 < nt) {
            stage(cur ^ 1, (t + 1) * 32);
            asm volatile("s_waitcnt vmcnt(4)" ::: "memory");
        } else {
            asm volatile("s_waitcnt vmcnt(0)" ::: "memory");
        }
        __builtin_amdgcn_s_barrier();
        short8 af[4], bfv[4];
#pragma unroll
        for (int mi = 0; mi < 4; ++mi)
            af[mi] = *(const short8*)(As[cur] + rd_off(wm * 64 + mi * 16 + lr));
#pragma unroll
        for (int ni = 0; ni < 4; ++ni)
            bfv[ni] = *(const short8*)(Bs[cur] + rd_off(wn * 64 + ni * 16 + lr));
        __builtin_amdgcn_s_setprio(1);
#pragma unroll
        for (int mi = 0; mi < 4; ++mi)
#pragma unroll
            for (int ni = 0; ni < 4; ++ni)
                acc[mi][ni] = __builtin_amdgcn_mfma_f32_16x16x32_bf16(
                    af[mi], bfv[ni], acc[mi][ni], 0, 0, 0);
        __builtin_amdgcn_s_setprio(0);
        __builtin_amdgcn_s_barrier();
    }

#pragma unroll
    for (int mi = 0; mi < 4; ++mi) {
        int gmc = m0 + wm * 64 + mi * 16 + lk * 4;
#pragma unroll
        for (int ni = 0; ni < 4; ++ni) {
            int gn = n0 + wn * 64 + ni * 16 + lr;
            float bsv = bias[gn];
#pragma unroll
            for (int e = 0; e < 4; ++e)
                Cout[(size_t)(gmc + e) * Nd + gn] = acc[mi][ni][e] + bsv;
        }
    }
}

// ---------------------------------------------------------------------------
// SPLIT-K variant: gridDim.z = KS slices; writes f32 partial part[kz][Mpad][Nd].
// ---------------------------------------------------------------------------
__launch_bounds__(256, 4)
__global__ void mfma_gemm_sk(const short* __restrict__ A, const short* __restrict__ Bt,
                             float* __restrict__ part, int Kd, int Nd,
                             int alvl, int cnt) {
    __shared__ short As[2][128 * 32];
    __shared__ short Bs[2][128 * 32];
    int tid = threadIdx.x;
    int nwg  = gridDim.x * gridDim.y;
    int orig = blockIdx.y * gridDim.x + blockIdx.x;
    int qq = nwg >> 3, rr = nwg & 7;
    int xcd = orig & 7, idx = orig >> 3;
    int wgid = (xcd < rr ? xcd * (qq + 1) : rr * (qq + 1) + (xcd - rr) * qq) + idx;
    int m0 = (wgid / gridDim.x) * 128, n0 = (wgid % gridDim.x) * 128;
    int Mpad = gridDim.y * 128;
    int kz = blockIdx.z;
    int kb = Kd / gridDim.z;          // slice length (multiple of 32)
    int kbase = kz * kb;

    int lane = tid & 63, wid = tid >> 6;
    int wm = wid >> 1, wn = wid & 1;
    int lr = lane & 15, lk = lane >> 4;

    size_t abase[2], bbase[2];
#pragma unroll
    for (int r = 0; r < 2; ++r) {
        int u = r * 256 + tid;
        int row = ((u >> 3) << 1) | ((u >> 2) & 1);
        int kg  = (u & 3) ^ ((u >> 3) & 3);
        int rm = m0 + row, ga;
        if (alvl >= 0) { int j = rm >> 5; if (j > cnt - 1) j = cnt - 1; ga = (rm & 31) * S + d_sets.idx[alvl][j]; }
        else ga = rm;
        abase[r] = (size_t)ga * Kd + kbase + kg * 8;
        bbase[r] = (size_t)(n0 + row) * Kd + kbase + kg * 8;
    }
    auto stage = [&](int buf, int k0) {
#pragma unroll
        for (int r = 0; r < 2; ++r) {
            short* la = As[buf] + (size_t)(r * 256 + wid * 64) * 8;
            short* lb = Bs[buf] + (size_t)(r * 256 + wid * 64) * 8;
            gload_lds16(A + abase[r] + k0, la);
            gload_lds16(Bt + bbase[r] + k0, lb);
        }
    };
    auto rd_off = [&](int row_) {
        int rh = row_ >> 1;
        int s  = lk ^ (rh & 3);
        return (size_t)(rh * 8 + (row_ & 1) * 4 + s) * 8;
    };

    float4v acc[4][4];
#pragma unroll
    for (int i = 0; i < 4; ++i)
#pragma unroll
        for (int j = 0; j < 4; ++j) acc[i][j] = 0;

    const int nt = kb >> 5;
    stage(0, 0);
    for (int t = 0; t < nt; ++t) {
        int cur = t & 1;
        if (t + 1 < nt) {
            stage(cur ^ 1, (t + 1) * 32);
            asm volatile("s_waitcnt vmcnt(4)" ::: "memory");
        } else {
            asm volatile("s_waitcnt vmcnt(0)" ::: "memory");
        }
        __builtin_amdgcn_s_barrier();
        short8 af[4], bfv[4];
#pragma unroll
        for (int mi = 0; mi < 4; ++mi)
            af[mi] = *(const short8*)(As[cur] + rd_off(wm * 64 + mi * 16 + lr));
#pragma unroll
        for (int ni = 0; ni < 4; ++ni)
            bfv[ni] = *(const short8*)(Bs[cur] + rd_off(wn * 64 + ni * 16 + lr));
        __builtin_amdgcn_s_setprio(1);
#pragma unroll
        for (int mi = 0; mi < 4; ++mi)
#pragma unroll
            for (int ni = 0; ni < 4; ++ni)
                acc[mi][ni] = __builtin_amdgcn_mfma_f32_16x16x32_bf16(
                    af[mi], bfv[ni], acc[mi][ni], 0, 0, 0);
        __builtin_amdgcn_s_setprio(0);
        __builtin_amdgcn_s_barrier();
    }

#pragma unroll
    for (int mi = 0; mi < 4; ++mi) {
        int gmc = m0 + wm * 64 + mi * 16 + lk * 4;
#pragma unroll
        for (int ni = 0; ni < 4; ++ni) {
            int gn = n0 + wn * 64 + ni * 16 + lr;
#pragma unroll
            for (int e = 0; e < 4; ++e)
                part[((size_t)kz * Mpad + gmc + e) * Nd + gn] = acc[mi][ni][e];
        }
    }
}

// sum KS partials + epilogue -> bf16 compact output
// EPI: 3 +bias+gelu; 4 +bias; 5 *bias+bias2 then ELU (conv BN fold)
template<int EPI>
__launch_bounds__(256)
__global__ void reduce_sk(const float* __restrict__ part, const float* __restrict__ bias,
                          const float* __restrict__ bias2, short* __restrict__ Cout,
                          int Mpad, int Nd, int KS) {
    int idx = blockIdx.x * 256 + threadIdx.x;
    if (idx >= Mpad * Nd) return;
    float s = 0.0f;
    for (int k = 0; k < KS; ++k)
        s += part[(size_t)k * Mpad * Nd + idx];
    int n = idx % Nd;
    if (EPI == 3 || EPI == 4) s += bias[n];
    if (EPI == 3) s = 0.5f * s * (1.0f + erff(s * 0.70710678118654752f));
    if (EPI == 5) { s = s * bias[n] + bias2[n]; s = s > 0.0f ? s : (expf(s) - 1.0f); }
    Cout[idx] = f2bf(s);
}

// ---------------------------------------------------------------------------
// weight transpose tile helper
// ---------------------------------------------------------------------------
__device__ inline void wtrans_tile(const float* __restrict__ W, short* __restrict__ Wt,
                                   int Kd, int Nd, int n0, int k0, int tid) {
    __shared__ float tile[32][33];
    int tx = tid & 31, ty = tid >> 5; // ty 0..7
#pragma unroll
    for (int r = 0; r < 32; r += 8)
        tile[ty + r][tx] = W[(size_t)(k0 + ty + r) * Nd + n0 + tx];
    __syncthreads();
#pragma unroll
    for (int r = 0; r < 32; r += 8)
        Wt[(size_t)(n0 + ty + r) * Kd + k0 + tx] = f2bf(tile[tx][ty + r]);
}

// ---------------------------------------------------------------------------
// ONE fused prep kernel: all weight transposes + small prep + pe/wE/xim.
// ---------------------------------------------------------------------------
constexpr int PE_N  = L * D;           // 172032
constexpr int WE_N  = D * 32;          // 16384
constexpr int XIM_N = BB * L * 32;     // 344064
constexpr int MISC_N = PE_N + WE_N + XIM_N;
constexpr int PREP_BLKS = 3072 + 6144 + 640 + (MISC_N + 255) / 256;

__launch_bounds__(256)
__global__ void prep_all(const float* __restrict__ wq, const float* __restrict__ wk,
                         const float* __restrict__ wv, const float* __restrict__ wo,
                         short* __restrict__ wqkvT, short* __restrict__ woT,
                         const float* __restrict__ w1, const float* __restrict__ w2,
                         short* __restrict__ w1T, short* __restrict__ w2T,
                         const float* __restrict__ down_w, short* __restrict__ downT,
                         const float* __restrict__ up_w, short* __restrict__ upT,
                         const float* __restrict__ cw, const float* __restrict__ cb,
                         const float* __restrict__ bg, const float* __restrict__ bb,
                         short* __restrict__ cscmT, float* __restrict__ sc,
                         float* __restrict__ sh,
                         const float* __restrict__ x_enc, const float* __restrict__ x_mark,
                         const float* __restrict__ cew, const float* __restrict__ tw,
                         const float* __restrict__ tb, float* __restrict__ pe,
                         short* __restrict__ wE, short* __restrict__ xim) {
    int blk = blockIdx.x;
    int tid = threadIdx.x;
    if (blk < 3072) {
        int z = blk >> 8, rem = blk & 255;
        int l = z >> 2, part = z & 3;
        const float* src = (part == 0 ? wq : part == 1 ? wk : part == 2 ? wv : wo)
                           + (size_t)l * D * D;
        short* dst = (part < 3) ? wqkvT + (size_t)l * 3 * D * D + (size_t)part * D * D
                                : woT + (size_t)l * D * D;
        wtrans_tile(src, dst, D, D, (rem & 15) * 32, (rem >> 4) * 32, tid);
        return;
    }
    blk -= 3072;
    if (blk < 6144) {
        int z = blk >> 10, rem = blk & 1023;
        int l = z >> 1, part = z & 1;
        int bx = rem & 63, by = rem >> 6;
        int nt = part ? by : bx;
        int kt = part ? bx : by;
        if (part == 0)
            wtrans_tile(w1 + (size_t)l * D * DFF, w1T + (size_t)l * DFF * D,
                        D, DFF, nt * 32, kt * 32, tid);
        else
            wtrans_tile(w2 + (size_t)l * DFF * D, w2T + (size_t)l * D * DFF,
                        DFF, D, nt * 32, kt * 32, tid);
        return;
    }
    blk -= 6144;
    if (blk < 640) {
        if (blk < 64) {
            wtrans_tile(down_w, downT, D, DBOT, (blk & 3) * 32, (blk >> 2) * 32, tid);
        } else if (blk < 128) {
            int b2 = blk - 64;
            wtrans_tile(up_w, upT, DBOT, D, (b2 & 15) * 32, (b2 >> 4) * 32, tid);
        } else {
            int idx = (blk - 128) * 256 + tid;
            if (idx < 2 * DBOT * 512) {
                int l = idx >> 16;
                int rem = idx & 65535;
                int oc = rem >> 9, j = rem & 511;
                int r = j >> 7, c = j & 127;
                cscmT[idx] = f2bf(cw[(((size_t)l * DBOT + oc) * DBOT + c) * 4 + r]);
            }
            if (idx < 3 * DBOT) {
                sc[idx] = bg[idx];
                sh[idx] = cb[idx] * bg[idx] + bb[idx];
            }
        }
        return;
    }
    blk -= 640;
    {
        int idx = blk * 256 + tid;
        if (idx < PE_N) {
            int d = idx % D, t = idx / D;
            int e = d & ~1;
            float div = expf(-(float)e * (logf(10000.0f) / (float)D));
            float arg = (float)t * div;
            pe[idx] = (d & 1) ? cosf(arg) : sinf(arg);
            return;
        }
        int i2 = idx - PE_N;
        if (i2 < WE_N) {
            int k = i2 & 31, d = i2 >> 5;
            float v = 0.0f;
            if (k < 21) {
                int w = k / 7, i = k % 7;
                v = cew[(size_t)d * (CIN * 3) + i * 3 + w];
            } else if (k < 25) {
                v = tw[(size_t)(k - 21) * D + d];
            } else if (k == 25) {
                v = tb[d];
            }
            wE[i2] = f2bf(v);
            return;
        }
        int i3 = i2 - WE_N;
        if (i3 < XIM_N) {
            int k = i3 & 31, m = i3 >> 5;
            int t = m % L, b = m / L;
            float v = 0.0f;
            if (k < 21) {
                int w = k / 7, i = k % 7;
                int s = t + w - 1;
                if (s < 0) s = L - 1;
                if (s >= L) s = 0;
                v = x_enc[((size_t)b * L + s) * CIN + i];
            } else if (k < 25) {
                v = x_mark[(size_t)m * MARK + (k - 21)];
            } else if (k == 25) {
                v = 1.0f;
            }
            xim[i3] = f2bf(v);
        }
    }
}

// ---------------------------------------------------------------------------
// CSCM conv level 3 (tiny)
// ---------------------------------------------------------------------------
__launch_bounds__(128)
__global__ void cscm_conv_bf16(const short* __restrict__ in, int inRowsPerB,
                               short* __restrict__ outp, const float* __restrict__ w,
                               const float* __restrict__ cb, const float* __restrict__ bng,
                               const float* __restrict__ bnb, int Lout) {
    int bid = blockIdx.x;
    int to = bid % Lout, b = bid / Lout;
    __shared__ float insh[4 * DBOT];
    int tid = threadIdx.x;
#pragma unroll
    for (int r = 0; r < 4; ++r)
        insh[r * DBOT + tid] = bf2f(in[((size_t)(b * inRowsPerB + to * 4 + r)) * DBOT + tid]);
    __syncthreads();
    float acc = cb[tid];
    const float* wr = w + (size_t)tid * (DBOT * 4);
    for (int c = 0; c < DBOT; ++c) {
#pragma unroll
        for (int r = 0; r < 4; ++r)
            acc += insh[r * DBOT + c] * wr[c * 4 + r];
    }
    acc = acc * bng[tid] + bnb[tid];
    outp[((size_t)(b * Lout + to)) * DBOT + tid] = f2bf(acc > 0.0f ? acc : (expf(acc) - 1.0f));
}

// ---------------------------------------------------------------------------
// sparse attention over active level (compact Ob)
// ---------------------------------------------------------------------------
__launch_bounds__(256)
__global__ void attn_sparse_kernel(const short* __restrict__ QKV, short* __restrict__ Ob,
                                   int lvl, int cnt) {
    int wid  = blockIdx.x * 4 + (threadIdx.x >> 6);
    if (wid >= cnt * 32) return;
    int lane = threadIdx.x & 63;
    int b = wid & 31, j = wid >> 5;
    int i = d_sets.idx[lvl][j];
    const short8 qv = *(const short8*)(QKV + (size_t)(b * S + i) * 1536 + lane * 8);
    float qf[8];
#pragma unroll
    for (int e = 0; e < 8; ++e) qf[e] = bf2f(qv[e]);
    int nb[NMAX];
#pragma unroll
    for (int jj = 0; jj < NMAX; ++jj) nb[jj] = d_sets.nbr[i][jj];
    float sc[NMAX];
#pragma unroll
    for (int jj = 0; jj < NMAX; ++jj) {
        float s = -1e30f;
        if (nb[jj] >= 0) {
            const short8 kv = *(const short8*)(QKV + (size_t)(b * S + nb[jj]) * 1536 + 512 + lane * 8);
            s = 0.0f;
#pragma unroll
            for (int e = 0; e < 8; ++e) s += qf[e] * bf2f(kv[e]);
            s += __shfl_xor(s, 1); s += __shfl_xor(s, 2); s += __shfl_xor(s, 4);
            s *= 0.125f;
        }
        sc[jj] = s;
    }
    float mx = sc[0];
#pragma unroll
    for (int jj = 1; jj < NMAX; ++jj) mx = fmaxf(mx, sc[jj]);
    float sum = 0.0f;
    float accv[8] = {};
#pragma unroll
    for (int jj = 0; jj < NMAX; ++jj) {
        float p = expf(sc[jj] - mx);
        sum += p;
        if (nb[jj] >= 0) {
            const short8 vv = *(const short8*)(QKV + (size_t)(b * S + nb[jj]) * 1536 + 1024 + lane * 8);
#pragma unroll
            for (int e = 0; e < 8; ++e) accv[e] += p * bf2f(vv[e]);
        }
    }
    float inv = 1.0f / sum;
    short8 ov;
#pragma unroll
    for (int e = 0; e < 8; ++e) ov[e] = f2bf(accv[e] * inv);
    *(short8*)(Ob + (size_t)wid * D + lane * 8) = ov;
}

// ---------------------------------------------------------------------------
// wave-shuffle block reduction over 4 waves (256 thr)
// ---------------------------------------------------------------------------
__device__ inline float blk_reduce(float v, float* ws4, int tid) {
#pragma unroll
    for (int o = 32; o; o >>= 1) v += __shfl_xor(v, o);
    if ((tid & 63) == 0) ws4[tid >> 6] = v;
    __syncthreads();
    return ws4[0] + ws4[1] + ws4[2] + ws4[3];
}

// ---------------------------------------------------------------------------
// concat(emb_bf, coarse) + LayerNorm at A_0 rows only
// ---------------------------------------------------------------------------
__launch_bounds__(256)
__global__ void concat_ln_idx(const short* __restrict__ emb_bf, const float* __restrict__ coarse,
                              const float* __restrict__ g, const float* __restrict__ bta,
                              float* __restrict__ seq, short* __restrict__ seq_bf) {
    int row = blockIdx.x;
    int b = row & 31, j = row >> 5;
    int s = d_sets.idx[0][j];
    int orig = b * S + s;
    __shared__ float wsA[4];
    __shared__ float wsB[4];
    int tid = threadIdx.x;
    float x0, x1;
    if (s < L) {
        const short* src = emb_bf + ((size_t)b * L + s) * D;
        x0 = bf2f(src[tid]); x1 = bf2f(src[tid + 256]);
    } else {
        const float* src = coarse + ((size_t)b * LC + (s - L)) * D;
        x0 = src[tid]; x1 = src[tid + 256];
    }
    float mu = blk_reduce(x0 + x1, wsA, tid) * (1.0f / D);
    float d0 = x0 - mu, d1 = x1 - mu;
    float var = blk_reduce(d0 * d0 + d1 * d1, wsB, tid) * (1.0f / D);
    float rstd = rsqrtf(var + 1e-5f);
    float v0 = d0 * rstd * g[tid]       + bta[tid];
    float v1 = d1 * rstd * g[tid + 256] + bta[tid + 256];
    float* dst = seq + (size_t)orig * D;
    dst[tid] = v0; dst[tid + 256] = v1;
    short* dbf = seq_bf + (size_t)orig * D;
    dbf[tid] = f2bf(v0); dbf[tid + 256] = f2bf(v1);
}

// ---------------------------------------------------------------------------
// fused split-K reduce + residual LN
// ---------------------------------------------------------------------------
__launch_bounds__(256)
__global__ void add_ln_sk(float* __restrict__ seq, const float* __restrict__ part,
                          const float* __restrict__ bias, const float* __restrict__ g,
                          const float* __restrict__ bta, short* __restrict__ seq_bf,
                          int lvl, int Mpad, int KS) {
    int row = blockIdx.x;
    int b = row & 31, j = row >> 5;
    int orig = b * S + d_sets.idx[lvl][j];
    __shared__ float wsA[4];
    __shared__ float wsB[4];
    int tid = threadIdx.x;
    float a0 = 0.0f, a1 = 0.0f;
    for (int k = 0; k < KS; ++k) {
        const float* pr = part + ((size_t)k * Mpad + row) * D;
        a0 += pr[tid];
        a1 += pr[tid + 256];
    }
    if (bias) { a0 += bias[tid]; a1 += bias[tid + 256]; }
    float* srow = seq + (size_t)orig * D;
    float x0 = srow[tid] + a0;
    float x1 = srow[tid + 256] + a1;
    float mu = blk_reduce(x0 + x1, wsA, tid) * (1.0f / D);
    float d0 = x0 - mu, d1 = x1 - mu;
    float var = blk_reduce(d0 * d0 + d1 * d1, wsB, tid) * (1.0f / D);
    float rstd = rsqrtf(var + 1e-5f);
    float v0 = d0 * rstd * g[tid]       + bta[tid];
    float v1 = d1 * rstd * g[tid + 256] + bta[tid + 256];
    srow[tid] = v0; srow[tid + 256] = v1;
    short* dbf = seq_bf + (size_t)orig * D;
    dbf[tid] = f2bf(v0); dbf[tid + 256] = f2bf(v1);
}

// ---------------------------------------------------------------------------
// prediction head, split-K with fused gather
// ---------------------------------------------------------------------------
__launch_bounds__(256)
__global__ void pred_kernel(const float* __restrict__ seq, const float* __restrict__ w,
                            float* __restrict__ part) {
    __shared__ float es[32][257];
    __shared__ float wsm[256][8];
    int tid = threadIdx.x;
    int n0 = blockIdx.x * 8;
    int ks = blockIdx.y;
    int k0 = ks * 256;
    const int pos[4] = {335, 419, 440, 445};
    int seg = ks >> 1;
    int dbase = (ks & 1) * 256;
#pragma unroll 8
    for (int r = 0; r < 32; ++r)
        es[r][tid] = seq[((size_t)r * S + pos[seg]) * D + dbase + tid];
#pragma unroll
    for (int e = 0; e < 8; ++e)
        wsm[tid][e] = w[(size_t)(k0 + tid) * PRED_N + n0 + e];
    __syncthreads();
    int b = tid >> 3, nn = tid & 7;
    float acc = 0.0f;
#pragma unroll 8
    for (int kk = 0; kk < 256; ++kk)
        acc += es[b][kk] * wsm[kk][nn];
    part[(size_t)ks * (BB * PRED_N) + (size_t)b * PRED_N + n0 + nn] = acc;
}

__launch_bounds__(256)
__global__ void pred_reduce_kernel(const float* __restrict__ part, float* __restrict__ out) {
    int idx = blockIdx.x * 256 + threadIdx.x;
    if (idx >= BB * PRED_N) return;
    float s = 0.0f;
#pragma unroll
    for (int k = 0; k < 8; ++k) s += part[(size_t)k * (BB * PRED_N) + idx];
    out[idx] = s;
}

// ---------------------------------------------------------------------------
extern "C" void kernel_launch(void* const* d_in, const int* in_sizes, int n_in,
                              void* d_out, int out_size, void* d_ws, size_t ws_size,
                              hipStream_t stream) {
    const float* x_enc      = (const float*)d_in[0];
    const float* x_mark_enc = (const float*)d_in[1];
    const float* conv_embed_w = (const float*)d_in[4];
    const float* time_w  = (const float*)d_in[5];
    const float* time_b  = (const float*)d_in[6];
    const float* down_w  = (const float*)d_in[7];
    const float* down_b  = (const float*)d_in[8];
    const float* cscm_w  = (const float*)d_in[9];
    const float* cscm_b  = (const float*)d_in[10];
    const float* bn_g    = (const float*)d_in[11];
    const float* bn_b    = (const float*)d_in[12];
    const float* up_w    = (const float*)d_in[13];
    const float* up_b    = (const float*)d_in[14];
    const float* cln_g   = (const float*)d_in[15];
    const float* cln_b   = (const float*)d_in[16];
    const float* wq      = (const float*)d_in[17];
    const float* wk      = (const float*)d_in[18];
    const float* wv      = (const float*)d_in[19];
    const float* wo      = (const float*)d_in[20];
    const float* ln1_g   = (const float*)d_in[21];
    const float* ln1_b   = (const float*)d_in[22];
    const float* ffn_w1  = (const float*)d_in[23];
    const float* ffn_b1  = (const float*)d_in[24];
    const float* ffn_w2  = (const float*)d_in[25];
    const float* ffn_b2  = (const float*)d_in[26];
    const float* ln2_g   = (const float*)d_in[27];
    const float* ln2_b   = (const float*)d_in[28];
    const float* pred_w  = (const float*)d_in[29];
    float* out = (float*)d_out;

    // ---- workspace layout (bytes, 256-aligned) ----
    char* w8 = (char*)d_ws;
    size_t off = 0;
    auto alloc = [&](size_t bytes) {
        void* p = w8 + off;
        off = (off + bytes + 255) & ~(size_t)255;
        return p;
    };
    short* emb_bf = (short*)alloc((size_t)BB * L * D * 2);
    float* pe     = (float*)alloc((size_t)L * D * 4);
    short* xim    = (short*)alloc((size_t)BB * L * 32 * 2);
    short* wE     = (short*)alloc((size_t)D * 32 * 2);
    short* xd_bf  = (short*)alloc((size_t)BB * L * DBOT * 2);
    short* cs1_bf = (short*)alloc((size_t)MCONV2P * 512 * 2);
    short* cs2_bf = (short*)alloc((size_t)MCONV2P * DBOT * 2);
    short* cs3_bf = (short*)alloc((size_t)BB * L3 * DBOT * 2);
    float* coarse = (float*)alloc((size_t)MCAT * D * 4);
    float* seq    = (float*)alloc((size_t)BB * S * D * 4);
    float* part   = (float*)alloc((size_t)8 * BB * PRED_N * 4);
    float* partsk = (float*)alloc(psk_elems() * 4);   // split-K partials (exact)
    short* seq_bf = (short*)alloc((size_t)MP * D * 2);
    short* QKV    = (short*)alloc((size_t)MP * 3 * D * 2);  // + Ob contiguous
    short* Ob     = (short*)alloc((size_t)MP * D * 2);
    short* hidden = QKV;
    short* wqkvT  = (short*)alloc((size_t)NLAYER * 3 * D * D * 2);
    short* woT    = (short*)alloc((size_t)NLAYER * D * D * 2);
    short* w1T    = (short*)alloc((size_t)NLAYER * DFF * D * 2);
    short* w2T    = (short*)alloc((size_t)NLAYER * D * DFF * 2);
    short* downT  = (short*)alloc((size_t)DBOT * D * 2);
    short* upT    = (short*)alloc((size_t)D * DBOT * 2);
    short* cscmT  = (short*)alloc((size_t)2 * DBOT * 512 * 2);
    float* csc_sc = (float*)alloc((size_t)3 * DBOT * 4);
    float* csc_sh = (float*)alloc((size_t)3 * DBOT * 4);
    (void)ws_size; (void)in_sizes; (void)n_in; (void)out_size;

    const int rowsL = BB * L;   // 10752 = 84*128
    dim3 blk(256);

    // 0. ONE fused prep kernel
    prep_all<<<dim3(PREP_BLKS), blk, 0, stream>>>(
        wq, wk, wv, wo, wqkvT, woT,
        ffn_w1, ffn_w2, w1T, w2T,
        down_w, downT, up_w, upT,
        cscm_w, cscm_b, bn_g, bn_b, cscmT, csc_sc, csc_sh,
        x_enc, x_mark_enc, conv_embed_w, time_w, time_b, pe, wE, xim);
    // 1. embedding as GEMM + pe epilogue, bf16 out
    mfma_gemm<6><<<dim3(D / 128, rowsL / 128), blk, 0, stream>>>(
        xim, wE, nullptr, nullptr, nullptr, 32, D, -1, -1, 0, pe, emb_bf);
    // 2. down projection -> bf16 (split-K)
    mfma_gemm_sk<<<dim3(1, rowsL / 128, 4), blk, 0, stream>>>(
        emb_bf, downT, partsk, D, DBOT, -1, 0);
    reduce_sk<4><<<dim3((rowsL * DBOT + 255) / 256), blk, 0, stream>>>(
        partsk, down_b, nullptr, xd_bf, rowsL, DBOT, 4);
    // 3. CSCM pyramid (conv1/conv2 split-K)
    mfma_gemm_sk<<<dim3(1, MCONV1 / 128, 4), blk, 0, stream>>>(
        xd_bf, cscmT, partsk, 512, DBOT, -1, 0);
    reduce_sk<5><<<dim3((MCONV1 * DBOT + 255) / 256), blk, 0, stream>>>(
        partsk, csc_sc, csc_sh, cs1_bf, MCONV1, DBOT, 4);
    mfma_gemm_sk<<<dim3(1, MCONV2P / 128, 4), blk, 0, stream>>>(
        cs1_bf, cscmT + (size_t)DBOT * 512, partsk, 512, DBOT, -1, 0);
    reduce_sk<5><<<dim3((MCONV2P * DBOT + 255) / 256), blk, 0, stream>>>(
        partsk, csc_sc + DBOT, csc_sh + DBOT, cs2_bf, MCONV2P, DBOT, 4);
    cscm_conv_bf16<<<dim3(BB * L3), dim3(DBOT), 0, stream>>>(
        cs2_bf, L2, cs3_bf, cscm_w + 2 * DBOT * DBOT * 4,
        cscm_b + 2 * DBOT, bn_g + 2 * DBOT, bn_b + 2 * DBOT, L3);
    // 4. up projection with inline concat gather
    mfma_gemm_up<<<dim3(D / 128, MCAT / 128), blk, 0, stream>>>(
        cs1_bf, cs2_bf, cs3_bf, upT, up_b, coarse);
    // 5. concat + LN (A_0 rows only)
    concat_ln_idx<<<dim3(HS.cnt[0] * 32), blk, 0, stream>>>(
        emb_bf, coarse, cln_g, cln_b, seq, seq_bf);

    // 6. encoder layers (sparse active sets; split-K everywhere it pays)
    for (int l = 0; l < NLAYER; ++l) {
        const int inLvl = l, outLvl = l + 1;
        const int inCnt  = HS.cnt[l];
        const int outCnt = HS.cnt[l + 1];
        const int Mc   = outCnt * 32;
        const int Mpad = ((Mc + 127) / 128) * 128;
        mfma_gemm<2><<<dim3(3 * D / 128, (inCnt * 32 + 127) / 128), blk, 0, stream>>>(
            seq_bf, wqkvT + (size_t)l * 3 * D * D, nullptr, nullptr, QKV, D, 3 * D,
            inLvl, inLvl, inCnt, nullptr, nullptr);
        attn_sparse_kernel<<<dim3(outCnt * 8), blk, 0, stream>>>(
            QKV, Ob, outLvl, outCnt);
        // O-projection + LN1: ALWAYS split-K (KS=4, the r22 optimum) + fused LN
        mfma_gemm_sk<<<dim3(D / 128, Mpad / 128, 4), blk, 0, stream>>>(
            Ob, woT + (size_t)l * D * D, partsk, D, D, -1, 0);
        add_ln_sk<<<dim3(Mc), blk, 0, stream>>>(
            seq, partsk, nullptr, ln1_g + (size_t)l * D, ln1_b + (size_t)l * D,
            seq_bf, outLvl, Mpad, 4);
        // FFN1: split-K for Mc<=512 (covers l1, l2)
        if (Mc <= 512) {
            mfma_gemm_sk<<<dim3(DFF / 128, Mpad / 128, 4), blk, 0, stream>>>(
                seq_bf, w1T + (size_t)l * DFF * D, partsk, D, DFF, outLvl, outCnt);
            reduce_sk<3><<<dim3((Mpad * DFF + 255) / 256), blk, 0, stream>>>(
                partsk, ffn_b1 + (size_t)l * DFF, nullptr, hidden, Mpad, DFF, 4);
        } else {
            mfma_gemm<3><<<dim3(DFF / 128, Mpad / 128), blk, 0, stream>>>(
                seq_bf, w1T + (size_t)l * DFF * D, ffn_b1 + (size_t)l * DFF, nullptr,
                hidden, D, DFF, outLvl, -1, outCnt, nullptr, nullptr);
        }
        // FFN2 + LN2: split-K, reduce fused into LN
        {
            int KS = (Mc <= 512) ? 8 : 4;
            mfma_gemm_sk<<<dim3(D / 128, Mpad / 128, KS), blk, 0, stream>>>(
                hidden, w2T + (size_t)l * D * DFF, partsk, DFF, D, -1, 0);
            add_ln_sk<<<dim3(Mc), blk, 0, stream>>>(
                seq, partsk, ffn_b2 + (size_t)l * D, ln2_g + (size_t)l * D,
                ln2_b + (size_t)l * D, seq_bf, outLvl, Mpad, KS);
        }
    }

    // 7. prediction head (split-K, gather fused) + reduce
    pred_kernel<<<dim3(PRED_N / 8, 8), blk, 0, stream>>>(seq, pred_w, part);
    pred_reduce_kernel<<<dim3((BB * PRED_N + 255) / 256), blk, 0, stream>>>(part, out);
}